// Round 1
// baseline (7756.445 us; speedup 1.0000x reference)
//
#include <hip/hip_runtime.h>

#define NW    10000
#define INDIM 300
#define SZ    256
#define BB    16
#define LL    128
#define NLEM  3000
#define FH    1024   // 4*SZ

__device__ __forceinline__ float sigf(float x){ return 1.f/(1.f+__expf(-x)); }
__device__ __forceinline__ float tanhf_(float x){ return 2.f/(1.f+__expf(-2.f*x)) - 1.f; }

// ---------------- we = relu(emb @ Wp + bp) : [10000,300]@[300,256] ----------
__global__ void k_we(const float* __restrict__ emb, const float* __restrict__ Wp,
                     const float* __restrict__ bp, float* __restrict__ we){
  __shared__ __align__(16) float As[16][INDIM];
  int r0 = blockIdx.x*16, tid = threadIdx.x;
  for(int i=tid;i<16*INDIM;i+=256){int lr=i/INDIM,d=i-lr*INDIM;
    As[lr][d]=emb[(long)(r0+lr)*INDIM+d];}
  __syncthreads();
  int cl=tid&63, rg=tid>>6;
  float acc[4][4];
  #pragma unroll
  for(int i=0;i<4;i++){acc[i][0]=acc[i][1]=acc[i][2]=acc[i][3]=0.f;}
  for(int k=0;k<INDIM;k+=4){
    float4 a4[4];
    #pragma unroll
    for(int i=0;i<4;i++) a4[i]=*(const float4*)&As[rg*4+i][k];
    #pragma unroll
    for(int j=0;j<4;j++){
      const float* wr=Wp+(long)(k+j)*SZ+cl;
      float w0=wr[0],w1=wr[64],w2=wr[128],w3=wr[192];
      #pragma unroll
      for(int i=0;i<4;i++){
        float a=(j==0)?a4[i].x:(j==1)?a4[i].y:(j==2)?a4[i].z:a4[i].w;
        acc[i][0]=fmaf(a,w0,acc[i][0]);acc[i][1]=fmaf(a,w1,acc[i][1]);
        acc[i][2]=fmaf(a,w2,acc[i][2]);acc[i][3]=fmaf(a,w3,acc[i][3]);
      }
    }
  }
  #pragma unroll
  for(int i=0;i<4;i++){
    int r=r0+rg*4+i;
    #pragma unroll
    for(int cc=0;cc<4;cc++){int col=cl+cc*64;
      we[(long)r*SZ+col]=fmaxf(acc[i][cc]+bp[col],0.f);}
  }
}

// ------------- xwi[dir,t,b,:] = x_row @ Wi[:256] + Wi[256+iseq] + bvec ------
// rows r = ((dir*128 + t)*16 + b); bwd rows gather the length-reversed token.
__global__ void k_xwi(const int* __restrict__ seq, const int* __restrict__ len,
                      const float* __restrict__ src, long bstride,
                      const float* __restrict__ Wi_f, const float* __restrict__ bvf,
                      const float* __restrict__ Wi_b, const float* __restrict__ bvb,
                      int iseq, float* __restrict__ xwi){
  __shared__ __align__(16) float As[64][SZ];
  __shared__ const float* rowp[64];
  int r0=blockIdx.x*64, cb=blockIdx.y, tid=threadIdx.x;
  int dir=r0>>11;
  if(tid<64){
    int grow=r0+tid;
    int t=(grow>>4)&(LL-1), b=grow&(BB-1);
    int lb=len[b];
    int tt=(dir==0)? t : ((t<lb)? (lb-1-t) : t);
    int tok=seq[b*LL+tt];
    rowp[tid]=src + (long)b*bstride + (long)tok*SZ;
  }
  __syncthreads();
  for(int i=tid;i<64*SZ;i+=256){int lr=i>>8,j=i&(SZ-1);As[lr][j]=rowp[lr][j];}
  __syncthreads();
  const float* __restrict__ Wi = dir? Wi_b : Wi_f;
  const float* __restrict__ bv = dir? bvb : bvf;
  int cl=tid&63, rg=tid>>6, c0=cb*256+cl;
  float acc[16][4];
  #pragma unroll
  for(int i=0;i<16;i++){acc[i][0]=acc[i][1]=acc[i][2]=acc[i][3]=0.f;}
  for(int k=0;k<SZ;k+=4){
    float4 a4[16];
    #pragma unroll
    for(int i=0;i<16;i++) a4[i]=*(const float4*)&As[rg*16+i][k];
    #pragma unroll
    for(int j=0;j<4;j++){
      const float* wr=Wi+(long)(k+j)*FH+c0;
      float w0=wr[0],w1=wr[64],w2=wr[128],w3=wr[192];
      #pragma unroll
      for(int i=0;i<16;i++){
        float a=(j==0)?a4[i].x:(j==1)?a4[i].y:(j==2)?a4[i].z:a4[i].w;
        acc[i][0]=fmaf(a,w0,acc[i][0]);acc[i][1]=fmaf(a,w1,acc[i][1]);
        acc[i][2]=fmaf(a,w2,acc[i][2]);acc[i][3]=fmaf(a,w3,acc[i][3]);
      }
    }
  }
  #pragma unroll
  for(int cc=0;cc<4;cc++){
    int cx=c0+cc*64;
    float be=Wi[(long)(SZ+iseq)*FH+cx]+bv[cx];
    #pragma unroll
    for(int i=0;i<16;i++){
      int grow=r0+rg*16+i;
      xwi[(long)grow*FH+cx]=acc[i][cc]+be;
    }
  }
}

// --------- persistent-register LSTM: one block per (dir,b), Wh in VGPRs -----
__global__ __launch_bounds__(1024,1) void k_lstm(const float* __restrict__ Wh_f,
    const float* __restrict__ Wh_b, const float* __restrict__ xwi,
    float* __restrict__ hglob){
  int blk=blockIdx.x, dir=blk>>4, b=blk&15;
  const float* __restrict__ Wh = dir? Wh_b : Wh_f;
  int n=threadIdx.x;
  float w[SZ];
  #pragma unroll
  for(int k=0;k<SZ;k++) w[k]=Wh[(long)k*FH+n];
  __shared__ __align__(16) float hl[SZ];
  __shared__ float zl[FH];
  float c=0.f;
  if(n<SZ) hl[n]=0.f;
  __syncthreads();
  const float* __restrict__ xbase = xwi + ((long)dir*LL*BB + b)*FH;
  for(int t=0;t<LL;t++){
    float a0=0.f,a1=0.f,a2=0.f,a3=0.f;
    #pragma unroll
    for(int k4=0;k4<SZ/4;k4++){
      float4 h4=*(const float4*)&hl[k4*4];
      a0=fmaf(h4.x,w[4*k4+0],a0);
      a1=fmaf(h4.y,w[4*k4+1],a1);
      a2=fmaf(h4.z,w[4*k4+2],a2);
      a3=fmaf(h4.w,w[4*k4+3],a3);
    }
    float acc = xbase[(long)t*BB*FH + n] + ((a0+a1)+(a2+a3));
    zl[n]=acc;
    __syncthreads();
    if(n<SZ){
      float zi=zl[n], zf=zl[n+SZ], zg=zl[n+2*SZ], zo=zl[n+3*SZ];
      c = sigf(zf)*c + sigf(zi)*tanhf_(zg);
      float h = sigf(zo)*tanhf_(c);
      hl[n]=h;
      hglob[((long)(dir*LL+t)*BB+b)*SZ+n]=h;
    }
    __syncthreads();
  }
}

// ---- enc = [hf|hb] @ Wenc + benc, relu(max) scatter into lembuf + flags ----
__global__ void k_enc(const int* __restrict__ seq, const int* __restrict__ len,
                      const int* __restrict__ u2l, const float* __restrict__ hglob,
                      const float* __restrict__ Wenc, const float* __restrict__ benc,
                      unsigned int* __restrict__ lembuf, unsigned int* __restrict__ flags){
  __shared__ __align__(16) float As[16][2*SZ];
  __shared__ const float* pf16[16]; __shared__ const float* pb16[16];
  __shared__ int lem_s[16], val_s[16], b_s[16];
  int r0=blockIdx.x*16, tid=threadIdx.x;
  if(tid<16){
    int r=r0+tid, b=r>>7, t=r&127, lb=len[b];
    int v=(t<lb); val_s[tid]=v; b_s[tid]=b;
    int lem=u2l[seq[r]];
    lem_s[tid]=lem;
    pf16[tid]=hglob+((long)t*BB+b)*SZ;
    int tr=v? (lb-1-t) : t;
    pb16[tid]=hglob+((long)(LL+tr)*BB+b)*SZ;
    if(v) flags[(long)b*NLEM+lem]=1u;
  }
  __syncthreads();
  for(int i=tid;i<16*SZ;i+=256){int lr=i>>8,j=i&(SZ-1);
    As[lr][j]=pf16[lr][j]; As[lr][SZ+j]=pb16[lr][j];}
  __syncthreads();
  int cl=tid&63, rg=tid>>6;
  float acc[4][4];
  #pragma unroll
  for(int i=0;i<4;i++){acc[i][0]=acc[i][1]=acc[i][2]=acc[i][3]=0.f;}
  for(int k=0;k<2*SZ;k+=4){
    float4 a4[4];
    #pragma unroll
    for(int i=0;i<4;i++) a4[i]=*(const float4*)&As[rg*4+i][k];
    #pragma unroll
    for(int j=0;j<4;j++){
      const float* wr=Wenc+(long)(k+j)*SZ+cl;
      float w0=wr[0],w1=wr[64],w2=wr[128],w3=wr[192];
      #pragma unroll
      for(int i=0;i<4;i++){
        float a=(j==0)?a4[i].x:(j==1)?a4[i].y:(j==2)?a4[i].z:a4[i].w;
        acc[i][0]=fmaf(a,w0,acc[i][0]);acc[i][1]=fmaf(a,w1,acc[i][1]);
        acc[i][2]=fmaf(a,w2,acc[i][2]);acc[i][3]=fmaf(a,w3,acc[i][3]);
      }
    }
  }
  #pragma unroll
  for(int i=0;i<4;i++){
    int lr=rg*4+i;
    if(val_s[lr]){
      long base=((long)b_s[lr]*NLEM+lem_s[lr])*SZ;
      #pragma unroll
      for(int cc=0;cc<4;cc++){
        int col=cl+cc*64;
        float e=fmaxf(acc[i][cc]+benc[col],0.f);
        atomicMax(&lembuf[base+col], __float_as_uint(e));
      }
    }
  }
}

// ------------ generic C[r] = A[r] @ W  (K=256), optional touched-flags ------
__global__ void k_rowgemm(const float* __restrict__ A, const float* __restrict__ W,
                          float* __restrict__ C, const unsigned int* __restrict__ flags){
  __shared__ __align__(16) float As[16][SZ];
  __shared__ int any_s;
  int r0=blockIdx.x*16, tid=threadIdx.x;
  if(tid==0){
    int a = flags? 0 : 1;
    if(flags){ for(int i=0;i<16;i++) a |= (int)flags[r0+i]; }
    any_s=a;
  }
  __syncthreads();
  if(!any_s) return;
  for(int i=tid;i<16*SZ;i+=256){int lr=i>>8,j=i&(SZ-1);As[lr][j]=A[(long)(r0+lr)*SZ+j];}
  __syncthreads();
  int cl=tid&63, rg=tid>>6;
  float acc[4][4];
  #pragma unroll
  for(int i=0;i<4;i++){acc[i][0]=acc[i][1]=acc[i][2]=acc[i][3]=0.f;}
  for(int k=0;k<SZ;k+=4){
    float4 a4[4];
    #pragma unroll
    for(int i=0;i<4;i++) a4[i]=*(const float4*)&As[rg*4+i][k];
    #pragma unroll
    for(int j=0;j<4;j++){
      const float* wr=W+(long)(k+j)*SZ+cl;
      float w0=wr[0],w1=wr[64],w2=wr[128],w3=wr[192];
      #pragma unroll
      for(int i=0;i<4;i++){
        float a=(j==0)?a4[i].x:(j==1)?a4[i].y:(j==2)?a4[i].z:a4[i].w;
        acc[i][0]=fmaf(a,w0,acc[i][0]);acc[i][1]=fmaf(a,w1,acc[i][1]);
        acc[i][2]=fmaf(a,w2,acc[i][2]);acc[i][3]=fmaf(a,w3,acc[i][3]);
      }
    }
  }
  #pragma unroll
  for(int i=0;i<4;i++){
    int r=r0+rg*4+i;
    #pragma unroll
    for(int cc=0;cc<4;cc++) C[(long)r*SZ+cl+cc*64]=acc[i][cc];
  }
}

// ------- iter-0 gate: ctxt==tile(we) -> pure elementwise from P0/Q ----------
__global__ void k_gate0(const float* __restrict__ we, const float* __restrict__ P0,
                        const float* __restrict__ Q, const float* __restrict__ lembuf,
                        const int* __restrict__ u2l, const unsigned int* __restrict__ flags,
                        const float* __restrict__ bg, float* __restrict__ out){
  long idx=(long)blockIdx.x*256+threadIdx.x;      // one float4 each
  const long TOTAL4=(long)BB*NW*SZ/4;
  if(idx>=TOTAL4) return;
  long row=idx>>6; int k4=(int)(idx&63);
  int r32=(int)row;
  int b=r32/NW, w=r32-b*NW;
  int lem=u2l[w];
  long qb=((long)b*NLEM+lem)*SZ;
  unsigned int fl=flags[(long)b*NLEM+lem];
  float4 p =((const float4*)(P0+(long)w*SZ))[k4];
  float4 wv=((const float4*)(we+(long)w*SZ))[k4];
  float4 bgv=((const float4*)bg)[k4];
  float4 q, nw;
  if(fl){ q=((const float4*)(Q+qb))[k4]; nw=((const float4*)(lembuf+qb))[k4]; }
  else  { q=make_float4(0.f,0.f,0.f,0.f); nw=q; }
  float4 o;
  { float g=sigf(p.x+q.x+bgv.x); o.x=wv.x*g+(1.f-g)*nw.x; }
  { float g=sigf(p.y+q.y+bgv.y); o.y=wv.y*g+(1.f-g)*nw.y; }
  { float g=sigf(p.z+q.z+bgv.z); o.z=wv.z*g+(1.f-g)*nw.z; }
  { float g=sigf(p.w+q.w+bgv.w); o.w=wv.w*g+(1.f-g)*nw.w; }
  ((float4*)out)[idx]=o;
}

// ------- iter-1 gate: fused ctxt@Wg1 GEMM + gate + in-place update ----------
__global__ void k_gate1(const float* __restrict__ ctxt, const float* __restrict__ Wg,
                        const float* __restrict__ Q, const float* __restrict__ lembuf,
                        const int* __restrict__ u2l, const unsigned int* __restrict__ flags,
                        const float* __restrict__ bg, float* __restrict__ out){
  __shared__ __align__(16) float As[64][SZ];   // 64 KB
  __shared__ __align__(16) float Ws[64][SZ];   // 64 KB
  __shared__ int lem_s[64];
  int r0=blockIdx.x*64, tid=threadIdx.x;
  for(int i=tid;i<64*SZ;i+=256){int lr=i>>8,j=i&(SZ-1);
    As[lr][j]=ctxt[(long)(r0+lr)*SZ+j];}
  if(tid<64){int r=r0+tid; lem_s[tid]=u2l[r%NW];}
  int cl=tid&63, rg=tid>>6;
  float acc[16][4];
  #pragma unroll
  for(int i=0;i<16;i++){acc[i][0]=acc[i][1]=acc[i][2]=acc[i][3]=0.f;}
  for(int kb=0;kb<4;kb++){
    __syncthreads();
    for(int i=tid;i<64*SZ;i+=256){int lr=i>>8,j=i&(SZ-1);
      Ws[lr][j]=Wg[(long)(kb*64+lr)*SZ+j];}
    __syncthreads();
    for(int k=0;k<64;k+=4){
      float4 a4[16];
      #pragma unroll
      for(int i=0;i<16;i++) a4[i]=*(const float4*)&As[rg*16+i][kb*64+k];
      #pragma unroll
      for(int j=0;j<4;j++){
        float w0=Ws[k+j][cl],w1=Ws[k+j][cl+64],w2=Ws[k+j][cl+128],w3=Ws[k+j][cl+192];
        #pragma unroll
        for(int i=0;i<16;i++){
          float a=(j==0)?a4[i].x:(j==1)?a4[i].y:(j==2)?a4[i].z:a4[i].w;
          acc[i][0]=fmaf(a,w0,acc[i][0]);acc[i][1]=fmaf(a,w1,acc[i][1]);
          acc[i][2]=fmaf(a,w2,acc[i][2]);acc[i][3]=fmaf(a,w3,acc[i][3]);
        }
      }
    }
  }
  #pragma unroll
  for(int i=0;i<16;i++){
    int lr=rg*16+i, r=r0+lr, b=r/NW;
    long base=((long)b*NLEM+lem_s[lr])*SZ;
    unsigned int fl=flags[(long)b*NLEM+lem_s[lr]];
    #pragma unroll
    for(int cc=0;cc<4;cc++){
      int col=cl+cc*64;
      float qv=0.f, nw=0.f;
      if(fl){ qv=Q[base+col]; nw=lembuf[base+col]; }
      float g=sigf(acc[i][cc]+qv+bg[col]);
      out[(long)r*SZ+col]=As[lr][col]*g+(1.f-g)*nw;
    }
  }
}

extern "C" void kernel_launch(void* const* d_in, const int* in_sizes, int n_in,
                              void* d_out, int out_size, void* d_ws, size_t ws_size,
                              hipStream_t stream){
  const float* emb  =(const float*)d_in[0];
  const float* Wp   =(const float*)d_in[1];
  const float* bp   =(const float*)d_in[2];
  const float* Wi_f =(const float*)d_in[3];
  const float* Wh_f =(const float*)d_in[4];
  const float* b_f  =(const float*)d_in[5];
  const float* Wi_b =(const float*)d_in[6];
  const float* Wh_b =(const float*)d_in[7];
  const float* b_b  =(const float*)d_in[8];
  const float* Wenc =(const float*)d_in[9];
  const float* benc =(const float*)d_in[10];
  const float* Wg   =(const float*)d_in[11];
  const float* bg   =(const float*)d_in[12];
  const int*   seq0 =(const int*)d_in[13];
  const int*   seq1 =(const int*)d_in[14];
  const int*   len0 =(const int*)d_in[15];
  const int*   len1 =(const int*)d_in[16];
  const int*   u2l  =(const int*)d_in[17];

  float* ws    = (float*)d_ws;
  float* we    = ws;                       // 2,560,000
  float* xwi   = we    + 2560000;          // 4,194,304
  float* hglob = xwi   + 4194304;          // 1,048,576
  float* lembuf= hglob + 1048576;          // 12,288,000
  float* flags = lembuf+ 12288000;         // 48,000 (uint)
  float* Q     = flags + 48000;            // 12,288,000
  float* P0    = Q     + 12288000;         // 2,560,000
  float* out   = (float*)d_out;

  k_we<<<NW/16,256,0,stream>>>(emb,Wp,bp,we);
  k_rowgemm<<<NW/16,256,0,stream>>>(we,Wg,P0,nullptr);            // P0 = we@Wg1

  const int* seqs[2]={seq0,seq1};
  const int* lens[2]={len0,len1};
  for(int i=0;i<2;i++){
    hipMemsetAsync(lembuf,0,(size_t)(12288000+48000)*4,stream);   // lembuf + flags
    const float* src = (i==0)? we : out;
    long bstride     = (i==0)? 0L : (long)NW*SZ;
    dim3 gx(64,4);
    k_xwi<<<gx,256,0,stream>>>(seqs[i],lens[i],src,bstride,Wi_f,b_f,Wi_b,b_b,i,xwi);
    k_lstm<<<32,1024,0,stream>>>(Wh_f,Wh_b,xwi,hglob);
    k_enc<<<BB*LL/16,256,0,stream>>>(seqs[i],lens[i],u2l,hglob,Wenc,benc,
                                     (unsigned int*)lembuf,(unsigned int*)flags);
    k_rowgemm<<<BB*NLEM/16,256,0,stream>>>(lembuf,Wg+(long)SZ*SZ,Q,
                                           (const unsigned int*)flags); // Q = nw@Wg2
    if(i==0){
      long nb=((long)BB*NW*SZ/4+255)/256;
      k_gate0<<<(int)nb,256,0,stream>>>(we,P0,Q,lembuf,u2l,
                                        (const unsigned int*)flags,bg,out);
    }else{
      k_gate1<<<BB*NW/64,256,0,stream>>>(out,Wg,Q,lembuf,u2l,
                                         (const unsigned int*)flags,bg,out);
    }
  }
}

// Round 2
// 5499.831 us; speedup vs baseline: 1.4103x; 1.4103x over previous
//
#include <hip/hip_runtime.h>

#define NW    10000
#define INDIM 300
#define SZ    256
#define BB    16
#define LL    128
#define NLEM  3000
#define FH    1024   // 4*SZ

typedef float f32x16 __attribute__((ext_vector_type(16)));

__device__ __forceinline__ float sigf(float x){ return 1.f/(1.f+__expf(-x)); }
__device__ __forceinline__ float tanhf_(float x){ return 2.f/(1.f+__expf(-2.f*x)) - 1.f; }

// ---------------- we = relu(emb @ Wp + bp) : [10000,300]@[300,256] ----------
__global__ void k_we(const float* __restrict__ emb, const float* __restrict__ Wp,
                     const float* __restrict__ bp, float* __restrict__ we){
  __shared__ __align__(16) float As[16][INDIM];
  int r0 = blockIdx.x*16, tid = threadIdx.x;
  for(int i=tid;i<16*INDIM;i+=256){int lr=i/INDIM,d=i-lr*INDIM;
    As[lr][d]=emb[(long)(r0+lr)*INDIM+d];}
  __syncthreads();
  int cl=tid&63, rg=tid>>6;
  float acc[4][4];
  #pragma unroll
  for(int i=0;i<4;i++){acc[i][0]=acc[i][1]=acc[i][2]=acc[i][3]=0.f;}
  for(int k=0;k<INDIM;k+=4){
    float4 a4[4];
    #pragma unroll
    for(int i=0;i<4;i++) a4[i]=*(const float4*)&As[rg*4+i][k];
    #pragma unroll
    for(int j=0;j<4;j++){
      const float* wr=Wp+(long)(k+j)*SZ+cl;
      float w0=wr[0],w1=wr[64],w2=wr[128],w3=wr[192];
      #pragma unroll
      for(int i=0;i<4;i++){
        float a=(j==0)?a4[i].x:(j==1)?a4[i].y:(j==2)?a4[i].z:a4[i].w;
        acc[i][0]=fmaf(a,w0,acc[i][0]);acc[i][1]=fmaf(a,w1,acc[i][1]);
        acc[i][2]=fmaf(a,w2,acc[i][2]);acc[i][3]=fmaf(a,w3,acc[i][3]);
      }
    }
  }
  #pragma unroll
  for(int i=0;i<4;i++){
    int r=r0+rg*4+i;
    #pragma unroll
    for(int cc=0;cc<4;cc++){int col=cl+cc*64;
      we[(long)r*SZ+col]=fmaxf(acc[i][cc]+bp[col],0.f);}
  }
}

// ------------- xwi[dir,t,b,:] = x_row @ Wi[:256] + Wi[256+iseq] + bvec ------
__global__ void k_xwi(const int* __restrict__ seq, const int* __restrict__ len,
                      const float* __restrict__ src, long bstride,
                      const float* __restrict__ Wi_f, const float* __restrict__ bvf,
                      const float* __restrict__ Wi_b, const float* __restrict__ bvb,
                      int iseq, float* __restrict__ xwi){
  __shared__ __align__(16) float As[64][SZ];
  __shared__ const float* rowp[64];
  int r0=blockIdx.x*64, cb=blockIdx.y, tid=threadIdx.x;
  int dir=r0>>11;
  if(tid<64){
    int grow=r0+tid;
    int t=(grow>>4)&(LL-1), b=grow&(BB-1);
    int lb=len[b];
    int tt=(dir==0)? t : ((t<lb)? (lb-1-t) : t);
    int tok=seq[b*LL+tt];
    rowp[tid]=src + (long)b*bstride + (long)tok*SZ;
  }
  __syncthreads();
  for(int i=tid;i<64*SZ;i+=256){int lr=i>>8,j=i&(SZ-1);As[lr][j]=rowp[lr][j];}
  __syncthreads();
  const float* __restrict__ Wi = dir? Wi_b : Wi_f;
  const float* __restrict__ bv = dir? bvb : bvf;
  int cl=tid&63, rg=tid>>6, c0=cb*256+cl;
  float acc[16][4];
  #pragma unroll
  for(int i=0;i<16;i++){acc[i][0]=acc[i][1]=acc[i][2]=acc[i][3]=0.f;}
  for(int k=0;k<SZ;k+=4){
    float4 a4[16];
    #pragma unroll
    for(int i=0;i<16;i++) a4[i]=*(const float4*)&As[rg*16+i][k];
    #pragma unroll
    for(int j=0;j<4;j++){
      const float* wr=Wi+(long)(k+j)*FH+c0;
      float w0=wr[0],w1=wr[64],w2=wr[128],w3=wr[192];
      #pragma unroll
      for(int i=0;i<16;i++){
        float a=(j==0)?a4[i].x:(j==1)?a4[i].y:(j==2)?a4[i].z:a4[i].w;
        acc[i][0]=fmaf(a,w0,acc[i][0]);acc[i][1]=fmaf(a,w1,acc[i][1]);
        acc[i][2]=fmaf(a,w2,acc[i][2]);acc[i][3]=fmaf(a,w3,acc[i][3]);
      }
    }
  }
  #pragma unroll
  for(int cc=0;cc<4;cc++){
    int cx=c0+cc*64;
    float be=Wi[(long)(SZ+iseq)*FH+cx]+bv[cx];
    #pragma unroll
    for(int i=0;i<16;i++){
      int grow=r0+rg*16+i;
      xwi[(long)grow*FH+cx]=acc[i][cc]+be;
    }
  }
}

// --------- persistent-register LSTM: one block per (dir,b) ------------------
// 256 recurrent weights per thread live in 16 NAMED f32x16 vars (VGPRs).
__global__ __launch_bounds__(1024,1) void k_lstm(const float* __restrict__ Wh_f,
    const float* __restrict__ Wh_b, const float* __restrict__ xwi,
    float* __restrict__ hglob){
  int blk=blockIdx.x, dir=blk>>4, b=blk&15;
  const float* __restrict__ Wh = dir? Wh_b : Wh_f;
  int n=threadIdx.x;

  f32x16 W0,W1,W2,W3,W4,W5,W6,W7,W8,W9,W10,W11,W12,W13,W14,W15;
#define LOADW(I) { f32x16 t; _Pragma("unroll") \
  for(int j=0;j<16;j++) t[j]=Wh[(long)((I)*16+j)*FH+n]; W##I=t; }
  LOADW(0) LOADW(1) LOADW(2) LOADW(3) LOADW(4) LOADW(5) LOADW(6) LOADW(7)
  LOADW(8) LOADW(9) LOADW(10) LOADW(11) LOADW(12) LOADW(13) LOADW(14) LOADW(15)
#undef LOADW

  __shared__ __align__(16) float hl[SZ];
  __shared__ float sl[FH];
  float c=0.f;
  if(n<SZ) hl[n]=0.f;
  __syncthreads();
  const float* __restrict__ xbase = xwi + ((long)dir*LL*BB + b)*FH + n;
  int zone = n>>8;
  for(int t=0;t<LL;t++){
    float xv = xbase[(long)t*BB*FH];          // independent of h: hidden under DOTs
    float a0=0.f,a1=0.f,a2=0.f,a3=0.f;
#define DOT(I) { _Pragma("unroll") for(int j=0;j<16;j+=4){ \
    float4 h4=*(const float4*)&hl[(I)*16+j]; \
    a0=fmaf(h4.x,W##I[j+0],a0); a1=fmaf(h4.y,W##I[j+1],a1); \
    a2=fmaf(h4.z,W##I[j+2],a2); a3=fmaf(h4.w,W##I[j+3],a3); } }
    DOT(0) DOT(1) DOT(2) DOT(3) DOT(4) DOT(5) DOT(6) DOT(7)
    DOT(8) DOT(9) DOT(10) DOT(11) DOT(12) DOT(13) DOT(14) DOT(15)
#undef DOT
    float z = xv + ((a0+a1)+(a2+a3));
    float s = (zone==2)? tanhf_(z) : sigf(z); // all 1024 lanes do their transcendental
    sl[n]=s;
    __syncthreads();
    if(n<SZ){
      c = sl[n+SZ]*c + sl[n]*sl[n+2*SZ];
      float h = sl[n+3*SZ]*tanhf_(c);
      hl[n]=h;
      hglob[((long)(dir*LL+t)*BB+b)*SZ+n]=h;
    }
    __syncthreads();
  }
}

// ---- enc = [hf|hb] @ Wenc + benc, relu(max) scatter into lembuf + flags ----
__global__ void k_enc(const int* __restrict__ seq, const int* __restrict__ len,
                      const int* __restrict__ u2l, const float* __restrict__ hglob,
                      const float* __restrict__ Wenc, const float* __restrict__ benc,
                      unsigned int* __restrict__ lembuf, unsigned int* __restrict__ flags){
  __shared__ __align__(16) float As[16][2*SZ];
  __shared__ const float* pf16[16]; __shared__ const float* pb16[16];
  __shared__ int lem_s[16], val_s[16], b_s[16];
  int r0=blockIdx.x*16, tid=threadIdx.x;
  if(tid<16){
    int r=r0+tid, b=r>>7, t=r&127, lb=len[b];
    int v=(t<lb); val_s[tid]=v; b_s[tid]=b;
    int lem=u2l[seq[r]];
    lem_s[tid]=lem;
    pf16[tid]=hglob+((long)t*BB+b)*SZ;
    int tr=v? (lb-1-t) : t;
    pb16[tid]=hglob+((long)(LL+tr)*BB+b)*SZ;
    if(v) flags[(long)b*NLEM+lem]=1u;
  }
  __syncthreads();
  for(int i=tid;i<16*SZ;i+=256){int lr=i>>8,j=i&(SZ-1);
    As[lr][j]=pf16[lr][j]; As[lr][SZ+j]=pb16[lr][j];}
  __syncthreads();
  int cl=tid&63, rg=tid>>6;
  float acc[4][4];
  #pragma unroll
  for(int i=0;i<4;i++){acc[i][0]=acc[i][1]=acc[i][2]=acc[i][3]=0.f;}
  for(int k=0;k<2*SZ;k+=4){
    float4 a4[4];
    #pragma unroll
    for(int i=0;i<4;i++) a4[i]=*(const float4*)&As[rg*4+i][k];
    #pragma unroll
    for(int j=0;j<4;j++){
      const float* wr=Wenc+(long)(k+j)*SZ+cl;
      float w0=wr[0],w1=wr[64],w2=wr[128],w3=wr[192];
      #pragma unroll
      for(int i=0;i<4;i++){
        float a=(j==0)?a4[i].x:(j==1)?a4[i].y:(j==2)?a4[i].z:a4[i].w;
        acc[i][0]=fmaf(a,w0,acc[i][0]);acc[i][1]=fmaf(a,w1,acc[i][1]);
        acc[i][2]=fmaf(a,w2,acc[i][2]);acc[i][3]=fmaf(a,w3,acc[i][3]);
      }
    }
  }
  #pragma unroll
  for(int i=0;i<4;i++){
    int lr=rg*4+i;
    if(val_s[lr]){
      long base=((long)b_s[lr]*NLEM+lem_s[lr])*SZ;
      #pragma unroll
      for(int cc=0;cc<4;cc++){
        int col=cl+cc*64;
        float e=fmaxf(acc[i][cc]+benc[col],0.f);
        atomicMax(&lembuf[base+col], __float_as_uint(e));
      }
    }
  }
}

// ------------ generic C[r] = A[r] @ W  (K=256), optional touched-flags ------
__global__ void k_rowgemm(const float* __restrict__ A, const float* __restrict__ W,
                          float* __restrict__ C, const unsigned int* __restrict__ flags){
  __shared__ __align__(16) float As[16][SZ];
  __shared__ int any_s;
  int r0=blockIdx.x*16, tid=threadIdx.x;
  if(tid==0){
    int a = flags? 0 : 1;
    if(flags){ for(int i=0;i<16;i++) a |= (int)flags[r0+i]; }
    any_s=a;
  }
  __syncthreads();
  if(!any_s) return;
  for(int i=tid;i<16*SZ;i+=256){int lr=i>>8,j=i&(SZ-1);As[lr][j]=A[(long)(r0+lr)*SZ+j];}
  __syncthreads();
  int cl=tid&63, rg=tid>>6;
  float acc[4][4];
  #pragma unroll
  for(int i=0;i<4;i++){acc[i][0]=acc[i][1]=acc[i][2]=acc[i][3]=0.f;}
  for(int k=0;k<SZ;k+=4){
    float4 a4[4];
    #pragma unroll
    for(int i=0;i<4;i++) a4[i]=*(const float4*)&As[rg*4+i][k];
    #pragma unroll
    for(int j=0;j<4;j++){
      const float* wr=W+(long)(k+j)*SZ+cl;
      float w0=wr[0],w1=wr[64],w2=wr[128],w3=wr[192];
      #pragma unroll
      for(int i=0;i<4;i++){
        float a=(j==0)?a4[i].x:(j==1)?a4[i].y:(j==2)?a4[i].z:a4[i].w;
        acc[i][0]=fmaf(a,w0,acc[i][0]);acc[i][1]=fmaf(a,w1,acc[i][1]);
        acc[i][2]=fmaf(a,w2,acc[i][2]);acc[i][3]=fmaf(a,w3,acc[i][3]);
      }
    }
  }
  #pragma unroll
  for(int i=0;i<4;i++){
    int r=r0+rg*4+i;
    #pragma unroll
    for(int cc=0;cc<4;cc++) C[(long)r*SZ+cl+cc*64]=acc[i][cc];
  }
}

// ------- iter-0 gate: ctxt==tile(we) -> pure elementwise from P0/Q ----------
__global__ void k_gate0(const float* __restrict__ we, const float* __restrict__ P0,
                        const float* __restrict__ Q, const float* __restrict__ lembuf,
                        const int* __restrict__ u2l, const unsigned int* __restrict__ flags,
                        const float* __restrict__ bg, float* __restrict__ out){
  long idx=(long)blockIdx.x*256+threadIdx.x;      // one float4 each
  const long TOTAL4=(long)BB*NW*SZ/4;
  if(idx>=TOTAL4) return;
  long row=idx>>6; int k4=(int)(idx&63);
  int r32=(int)row;
  int b=r32/NW, w=r32-b*NW;
  int lem=u2l[w];
  long qb=((long)b*NLEM+lem)*SZ;
  unsigned int fl=flags[(long)b*NLEM+lem];
  float4 p =((const float4*)(P0+(long)w*SZ))[k4];
  float4 wv=((const float4*)(we+(long)w*SZ))[k4];
  float4 bgv=((const float4*)bg)[k4];
  float4 q, nw;
  if(fl){ q=((const float4*)(Q+qb))[k4]; nw=((const float4*)(lembuf+qb))[k4]; }
  else  { q=make_float4(0.f,0.f,0.f,0.f); nw=q; }
  float4 o;
  { float g=sigf(p.x+q.x+bgv.x); o.x=wv.x*g+(1.f-g)*nw.x; }
  { float g=sigf(p.y+q.y+bgv.y); o.y=wv.y*g+(1.f-g)*nw.y; }
  { float g=sigf(p.z+q.z+bgv.z); o.z=wv.z*g+(1.f-g)*nw.z; }
  { float g=sigf(p.w+q.w+bgv.w); o.w=wv.w*g+(1.f-g)*nw.w; }
  ((float4*)out)[idx]=o;
}

// ------- iter-1 gate: fused ctxt@Wg1 GEMM + gate + in-place update ----------
__global__ void k_gate1(const float* __restrict__ ctxt, const float* __restrict__ Wg,
                        const float* __restrict__ Q, const float* __restrict__ lembuf,
                        const int* __restrict__ u2l, const unsigned int* __restrict__ flags,
                        const float* __restrict__ bg, float* __restrict__ out){
  __shared__ __align__(16) float As[64][SZ];   // 64 KB
  __shared__ __align__(16) float Ws[64][SZ];   // 64 KB
  __shared__ int lem_s[64];
  int r0=blockIdx.x*64, tid=threadIdx.x;
  for(int i=tid;i<64*SZ;i+=256){int lr=i>>8,j=i&(SZ-1);
    As[lr][j]=ctxt[(long)(r0+lr)*SZ+j];}
  if(tid<64){int r=r0+tid; lem_s[tid]=u2l[r%NW];}
  int cl=tid&63, rg=tid>>6;
  float acc[16][4];
  #pragma unroll
  for(int i=0;i<16;i++){acc[i][0]=acc[i][1]=acc[i][2]=acc[i][3]=0.f;}
  for(int kb=0;kb<4;kb++){
    __syncthreads();
    for(int i=tid;i<64*SZ;i+=256){int lr=i>>8,j=i&(SZ-1);
      Ws[lr][j]=Wg[(long)(kb*64+lr)*SZ+j];}
    __syncthreads();
    for(int k=0;k<64;k+=4){
      float4 a4[16];
      #pragma unroll
      for(int i=0;i<16;i++) a4[i]=*(const float4*)&As[rg*16+i][kb*64+k];
      #pragma unroll
      for(int j=0;j<4;j++){
        float w0=Ws[k+j][cl],w1=Ws[k+j][cl+64],w2=Ws[k+j][cl+128],w3=Ws[k+j][cl+192];
        #pragma unroll
        for(int i=0;i<16;i++){
          float a=(j==0)?a4[i].x:(j==1)?a4[i].y:(j==2)?a4[i].z:a4[i].w;
          acc[i][0]=fmaf(a,w0,acc[i][0]);acc[i][1]=fmaf(a,w1,acc[i][1]);
          acc[i][2]=fmaf(a,w2,acc[i][2]);acc[i][3]=fmaf(a,w3,acc[i][3]);
        }
      }
    }
  }
  #pragma unroll
  for(int i=0;i<16;i++){
    int lr=rg*16+i, r=r0+lr, b=r/NW;
    long base=((long)b*NLEM+lem_s[lr])*SZ;
    unsigned int fl=flags[(long)b*NLEM+lem_s[lr]];
    #pragma unroll
    for(int cc=0;cc<4;cc++){
      int col=cl+cc*64;
      float qv=0.f, nw=0.f;
      if(fl){ qv=Q[base+col]; nw=lembuf[base+col]; }
      float g=sigf(acc[i][cc]+qv+bg[col]);
      out[(long)r*SZ+col]=As[lr][col]*g+(1.f-g)*nw;
    }
  }
}

extern "C" void kernel_launch(void* const* d_in, const int* in_sizes, int n_in,
                              void* d_out, int out_size, void* d_ws, size_t ws_size,
                              hipStream_t stream){
  const float* emb  =(const float*)d_in[0];
  const float* Wp   =(const float*)d_in[1];
  const float* bp   =(const float*)d_in[2];
  const float* Wi_f =(const float*)d_in[3];
  const float* Wh_f =(const float*)d_in[4];
  const float* b_f  =(const float*)d_in[5];
  const float* Wi_b =(const float*)d_in[6];
  const float* Wh_b =(const float*)d_in[7];
  const float* b_b  =(const float*)d_in[8];
  const float* Wenc =(const float*)d_in[9];
  const float* benc =(const float*)d_in[10];
  const float* Wg   =(const float*)d_in[11];
  const float* bg   =(const float*)d_in[12];
  const int*   seq0 =(const int*)d_in[13];
  const int*   seq1 =(const int*)d_in[14];
  const int*   len0 =(const int*)d_in[15];
  const int*   len1 =(const int*)d_in[16];
  const int*   u2l  =(const int*)d_in[17];

  float* ws    = (float*)d_ws;
  float* we    = ws;                       // 2,560,000
  float* xwi   = we    + 2560000;          // 4,194,304
  float* hglob = xwi   + 4194304;          // 1,048,576
  float* lembuf= hglob + 1048576;          // 12,288,000
  float* flags = lembuf+ 12288000;         // 48,000 (uint)
  float* Q     = flags + 48000;            // 12,288,000
  float* P0    = Q     + 12288000;         // 2,560,000
  float* out   = (float*)d_out;

  k_we<<<NW/16,256,0,stream>>>(emb,Wp,bp,we);
  k_rowgemm<<<NW/16,256,0,stream>>>(we,Wg,P0,nullptr);            // P0 = we@Wg1

  const int* seqs[2]={seq0,seq1};
  const int* lens[2]={len0,len1};
  for(int i=0;i<2;i++){
    hipMemsetAsync(lembuf,0,(size_t)(12288000+48000)*4,stream);   // lembuf + flags
    const float* src = (i==0)? we : out;
    long bstride     = (i==0)? 0L : (long)NW*SZ;
    dim3 gx(64,4);
    k_xwi<<<gx,256,0,stream>>>(seqs[i],lens[i],src,bstride,Wi_f,b_f,Wi_b,b_b,i,xwi);
    k_lstm<<<32,1024,0,stream>>>(Wh_f,Wh_b,xwi,hglob);
    k_enc<<<BB*LL/16,256,0,stream>>>(seqs[i],lens[i],u2l,hglob,Wenc,benc,
                                     (unsigned int*)lembuf,(unsigned int*)flags);
    k_rowgemm<<<BB*NLEM/16,256,0,stream>>>(lembuf,Wg+(long)SZ*SZ,Q,
                                           (const unsigned int*)flags); // Q = nw@Wg2
    if(i==0){
      long nb=((long)BB*NW*SZ/4+255)/256;
      k_gate0<<<(int)nb,256,0,stream>>>(we,P0,Q,lembuf,u2l,
                                        (const unsigned int*)flags,bg,out);
    }else{
      k_gate1<<<BB*NW/64,256,0,stream>>>(out,Wg,Q,lembuf,u2l,
                                         (const unsigned int*)flags,bg,out);
    }
  }
}

// Round 3
// 3397.280 us; speedup vs baseline: 2.2831x; 1.6189x over previous
//
#include <hip/hip_runtime.h>

#define NW    10000
#define INDIM 300
#define SZ    256
#define BB    16
#define LL    128
#define NLEM  3000
#define FH    1024   // 4*SZ

typedef short  bf16x8 __attribute__((ext_vector_type(8)));
typedef float  f32x4  __attribute__((ext_vector_type(4)));

__device__ __forceinline__ float sigf(float x){ return 1.f/(1.f+__expf(-x)); }
__device__ __forceinline__ float tanhf_(float x){ return 2.f/(1.f+__expf(-2.f*x)) - 1.f; }
__device__ __forceinline__ short f2b(float f){
  unsigned u=__float_as_uint(f); u += 0x7FFFu + ((u>>16)&1u); return (short)(u>>16);
}

// ---------------- we = relu(emb @ Wp + bp) : [10000,300]@[300,256] ----------
__global__ void k_we(const float* __restrict__ emb, const float* __restrict__ Wp,
                     const float* __restrict__ bp, float* __restrict__ we){
  __shared__ __align__(16) float As[16][INDIM];
  int r0 = blockIdx.x*16, tid = threadIdx.x;
  for(int i=tid;i<16*INDIM;i+=256){int lr=i/INDIM,d=i-lr*INDIM;
    As[lr][d]=emb[(long)(r0+lr)*INDIM+d];}
  __syncthreads();
  int cl=tid&63, rg=tid>>6;
  float acc[4][4];
  #pragma unroll
  for(int i=0;i<4;i++){acc[i][0]=acc[i][1]=acc[i][2]=acc[i][3]=0.f;}
  for(int k=0;k<INDIM;k+=4){
    float4 a4[4];
    #pragma unroll
    for(int i=0;i<4;i++) a4[i]=*(const float4*)&As[rg*4+i][k];
    #pragma unroll
    for(int j=0;j<4;j++){
      const float* wr=Wp+(long)(k+j)*SZ+cl;
      float w0=wr[0],w1=wr[64],w2=wr[128],w3=wr[192];
      #pragma unroll
      for(int i=0;i<4;i++){
        float a=(j==0)?a4[i].x:(j==1)?a4[i].y:(j==2)?a4[i].z:a4[i].w;
        acc[i][0]=fmaf(a,w0,acc[i][0]);acc[i][1]=fmaf(a,w1,acc[i][1]);
        acc[i][2]=fmaf(a,w2,acc[i][2]);acc[i][3]=fmaf(a,w3,acc[i][3]);
      }
    }
  }
  #pragma unroll
  for(int i=0;i<4;i++){
    int r=r0+rg*4+i;
    #pragma unroll
    for(int cc=0;cc<4;cc++){int col=cl+cc*64;
      we[(long)r*SZ+col]=fmaxf(acc[i][cc]+bp[col],0.f);}
  }
}

// ---- xwi (fragment-layout output): value = x_row @ Wi[:256] + Wi[256+iseq] + b
// layout: xwi3[(((dir*128+t)*4+w)*64 + l)*64 + nt*4 + r]
//   col = g*256 + w*64 + ug*16 + nl ; nt = ug*4+g ; l=(b>>2)*16+nl ; r=b&3
__global__ void k_xwi(const int* __restrict__ seq, const int* __restrict__ len,
                      const float* __restrict__ src, long bstride,
                      const float* __restrict__ Wi_f, const float* __restrict__ bvf,
                      const float* __restrict__ Wi_b, const float* __restrict__ bvb,
                      int iseq, float* __restrict__ xwi){
  __shared__ __align__(16) float As[64][SZ];
  __shared__ const float* rowp[64];
  int r0=blockIdx.x*64, cb=blockIdx.y, tid=threadIdx.x;
  int dir=r0>>11;
  if(tid<64){
    int grow=r0+tid;
    int t=(grow>>4)&(LL-1), b=grow&(BB-1);
    int lb=len[b];
    int tt=(dir==0)? t : ((t<lb)? (lb-1-t) : t);
    int tok=seq[b*LL+tt];
    rowp[tid]=src + (long)b*bstride + (long)tok*SZ;
  }
  __syncthreads();
  for(int i=tid;i<64*SZ;i+=256){int lr=i>>8,j=i&(SZ-1);As[lr][j]=rowp[lr][j];}
  __syncthreads();
  const float* __restrict__ Wi = dir? Wi_b : Wi_f;
  const float* __restrict__ bv = dir? bvb : bvf;
  int cl=tid&63, rg=tid>>6, c0=cb*256+cl;
  float acc[16][4];
  #pragma unroll
  for(int i=0;i<16;i++){acc[i][0]=acc[i][1]=acc[i][2]=acc[i][3]=0.f;}
  for(int k=0;k<SZ;k+=4){
    float4 a4[16];
    #pragma unroll
    for(int i=0;i<16;i++) a4[i]=*(const float4*)&As[rg*16+i][k];
    #pragma unroll
    for(int j=0;j<4;j++){
      const float* wr=Wi+(long)(k+j)*FH+c0;
      float w0=wr[0],w1=wr[64],w2=wr[128],w3=wr[192];
      #pragma unroll
      for(int i=0;i<16;i++){
        float a=(j==0)?a4[i].x:(j==1)?a4[i].y:(j==2)?a4[i].z:a4[i].w;
        acc[i][0]=fmaf(a,w0,acc[i][0]);acc[i][1]=fmaf(a,w1,acc[i][1]);
        acc[i][2]=fmaf(a,w2,acc[i][2]);acc[i][3]=fmaf(a,w3,acc[i][3]);
      }
    }
  }
  #pragma unroll
  for(int cc=0;cc<4;cc++){
    int cx=c0+cc*64;
    float be=Wi[(long)(SZ+iseq)*FH+cx]+bv[cx];
    int g=cx>>8, rem=cx&255, w2=rem>>6, ug=(rem>>4)&3, nl=rem&15, nt=ug*4+g;
    #pragma unroll
    for(int i=0;i<16;i++){
      int grow=r0+rg*16+i;
      int b=grow&15, t=(grow>>4)&127, d2=grow>>11;
      long idx3=((((long)d2*128+t)*4+w2)*64 + (b>>2)*16+nl)*64 + nt*4 + (b&3);
      xwi[idx3]=acc[i][cc]+be;
    }
  }
}

// ---- prep: Wh -> bf16 MFMA B-fragments, gate-grouped column permutation ----
// frag[((dir*4+w)*128 + nt*8+ks)*64 + l] (bf16x8):
//   B[k][col], k=ks*32+8*(l>>4)+j, col=g*256+w*64+ug*16+(l&15), nt=ug*4+g
__global__ void k_prep(const float* __restrict__ Wh_f, const float* __restrict__ Wh_b,
                       short* __restrict__ frag){
  int tid = blockIdx.x*256 + threadIdx.x;   // 65536 total
  int l = tid&63, T=(tid>>6)&127, w=(tid>>13)&3, dir=tid>>15;
  const float* Wh = dir? Wh_b : Wh_f;
  int nt=T>>3, ks=T&7, ug=nt>>2, g=nt&3;
  int col = g*256 + w*64 + ug*16 + (l&15);
  int k0 = ks*32 + 8*(l>>4);
  short v[8];
  #pragma unroll
  for(int j=0;j<8;j++) v[j]=f2b(Wh[(long)(k0+j)*FH + col]);
  *(bf16x8*)(frag + (long)tid*8) = *(bf16x8*)v;
}

// --------- MFMA batched persistent LSTM: 1 block/dir, 256 thr, 512 VGPR -----
#define MF(a,b,c) __builtin_amdgcn_mfma_f32_16x16x32_bf16(a,b,c,0,0,0)
#define LDF(T)    (*(const bf16x8*)(fr + (long)(T)*512 + l*8))
#define LDL(nt,ks) (*(const bf16x8*)(bl + ((nt)-9)*4096 + (ks)*512 + l*8))
#define DECLR(nt) bf16x8 R##nt##_0=LDF(nt*8+0),R##nt##_1=LDF(nt*8+1),R##nt##_2=LDF(nt*8+2),R##nt##_3=LDF(nt*8+3),R##nt##_4=LDF(nt*8+4),R##nt##_5=LDF(nt*8+5),R##nt##_6=LDF(nt*8+6),R##nt##_7=LDF(nt*8+7);
#define DECLC(nt) f32x4 C##nt={0.f,0.f,0.f,0.f};
#define MMR(nt) { C##nt=MF(A0,R##nt##_0,C##nt); C##nt=MF(A1,R##nt##_1,C##nt); C##nt=MF(A2,R##nt##_2,C##nt); C##nt=MF(A3,R##nt##_3,C##nt); C##nt=MF(A4,R##nt##_4,C##nt); C##nt=MF(A5,R##nt##_5,C##nt); C##nt=MF(A6,R##nt##_6,C##nt); C##nt=MF(A7,R##nt##_7,C##nt); }
#define MML(nt) { C##nt=MF(A0,LDL(nt,0),C##nt); C##nt=MF(A1,LDL(nt,1),C##nt); C##nt=MF(A2,LDL(nt,2),C##nt); C##nt=MF(A3,LDL(nt,3),C##nt); C##nt=MF(A4,LDL(nt,4),C##nt); C##nt=MF(A5,LDL(nt,5),C##nt); C##nt=MF(A6,LDL(nt,6),C##nt); C##nt=MF(A7,LDL(nt,7),C##nt); }
#define MMS(nt) { C##nt=MF(A0,LDF(nt*8+0),C##nt); C##nt=MF(A1,LDF(nt*8+1),C##nt); C##nt=MF(A2,LDF(nt*8+2),C##nt); C##nt=MF(A3,LDF(nt*8+3),C##nt); C##nt=MF(A4,LDF(nt*8+4),C##nt); C##nt=MF(A5,LDF(nt*8+5),C##nt); C##nt=MF(A6,LDF(nt*8+6),C##nt); C##nt=MF(A7,LDF(nt*8+7),C##nt); }
#define XLD(ug,g) (*(const f32x4*)(xp + ((ug)*4+(g))*4))
#define GATE1(ug,r,CA,CB,CC,CD,X0,X1,X2,X3) { \
  float zi=CA[r]+X0[r], zf=CB[r]+X1[r], zg=CC[r]+X2[r], zo=CD[r]+X3[r]; \
  cst_##ug##_##r = sigf(zf)*cst_##ug##_##r + sigf(zi)*tanhf_(zg); \
  float hv = sigf(zo)*tanhf_(cst_##ug##_##r); \
  int b_=4*(l>>4)+(r); int u_=w*64+(ug)*16+(l&15); \
  hbn[b_*264+u_]=f2b(hv); \
  hg[((long)t*16+b_)*256+u_]=hv; }
#define GATES(ug,CA,CB,CC,CD,X0,X1,X2,X3) \
  GATE1(ug,0,CA,CB,CC,CD,X0,X1,X2,X3) GATE1(ug,1,CA,CB,CC,CD,X0,X1,X2,X3) \
  GATE1(ug,2,CA,CB,CC,CD,X0,X1,X2,X3) GATE1(ug,3,CA,CB,CC,CD,X0,X1,X2,X3)

extern __shared__ char smem_raw[];

__global__ __launch_bounds__(256,1) void k_lstm_mfma(
    const short* __restrict__ frag, const float* __restrict__ xwi3,
    float* __restrict__ hglob){
  const int dir = blockIdx.x;
  const int tid = threadIdx.x;
  const int w = tid>>6, l = tid&63;
  short* hb = (short*)smem_raw;                        // 2 x 16 x 264 shorts
  short* bl = (short*)(smem_raw + 16896) + w*16384;    // per-wave LDS B tiles
  const short* fr = frag + (long)(dir*4+w)*128*512;

  for(int i=tid;i<4224;i+=256) ((int*)smem_raw)[i]=0;  // zero both h buffers

  // stage LDS tiles nt 9..12 (T=72..103), 32 KB per wave
  #pragma unroll 4
  for(int c2=0;c2<32;c2++)
    *(f32x4*)(bl + c2*512 + l*8) = *(const f32x4*)(fr + 72*512 + c2*512 + l*8);

  DECLR(0) DECLR(1) DECLR(2) DECLR(3) DECLR(4) DECLR(5) DECLR(6) DECLR(7) DECLR(8)

  float cst_0_0=0,cst_0_1=0,cst_0_2=0,cst_0_3=0, cst_1_0=0,cst_1_1=0,cst_1_2=0,cst_1_3=0,
        cst_2_0=0,cst_2_1=0,cst_2_2=0,cst_2_3=0, cst_3_0=0,cst_3_1=0,cst_3_2=0,cst_3_3=0;
  __syncthreads();

  const float* xwb = xwi3 + (long)dir*2097152 + (long)(w*64+l)*64;
  float* hg = hglob + (long)dir*524288;

  for(int t=0;t<LL;t++){
    const int cur=t&1, nxt=cur^1;
    const short* hr = hb + cur*4224 + (l&15)*264 + (l>>4)*8;
    bf16x8 A0=*(const bf16x8*)(hr+0),   A1=*(const bf16x8*)(hr+32),
           A2=*(const bf16x8*)(hr+64),  A3=*(const bf16x8*)(hr+96),
           A4=*(const bf16x8*)(hr+128), A5=*(const bf16x8*)(hr+160),
           A6=*(const bf16x8*)(hr+192), A7=*(const bf16x8*)(hr+224);
    const float* xp = xwb + (long)t*16384;
    f32x4 xa0=XLD(0,0), xa1=XLD(0,1), xa2=XLD(0,2), xa3=XLD(0,3);
    DECLC(0) DECLC(1) DECLC(2) DECLC(3) DECLC(4) DECLC(5) DECLC(6) DECLC(7)
    DECLC(8) DECLC(9) DECLC(10) DECLC(11) DECLC(12) DECLC(13) DECLC(14) DECLC(15)
    MMR(0) MMR(1) MMR(2) MMR(3) MMR(4) MMR(5) MMR(6) MMR(7) MMR(8)
    MML(9) MML(10) MML(11) MML(12)
    MMS(13) MMS(14) MMS(15)
    short* hbn = hb + nxt*4224;
    f32x4 xb0=XLD(1,0), xb1=XLD(1,1), xb2=XLD(1,2), xb3=XLD(1,3);
    GATES(0, C0,C1,C2,C3,     xa0,xa1,xa2,xa3)
    f32x4 xc0=XLD(2,0), xc1=XLD(2,1), xc2=XLD(2,2), xc3=XLD(2,3);
    GATES(1, C4,C5,C6,C7,     xb0,xb1,xb2,xb3)
    f32x4 xd0=XLD(3,0), xd1=XLD(3,1), xd2=XLD(3,2), xd3=XLD(3,3);
    GATES(2, C8,C9,C10,C11,   xc0,xc1,xc2,xc3)
    GATES(3, C12,C13,C14,C15, xd0,xd1,xd2,xd3)
    __syncthreads();
  }
}

// ---- enc = [hf|hb] @ Wenc + benc, relu(max) scatter into lembuf + flags ----
__global__ void k_enc(const int* __restrict__ seq, const int* __restrict__ len,
                      const int* __restrict__ u2l, const float* __restrict__ hglob,
                      const float* __restrict__ Wenc, const float* __restrict__ benc,
                      unsigned int* __restrict__ lembuf, unsigned int* __restrict__ flags){
  __shared__ __align__(16) float As[16][2*SZ];
  __shared__ const float* pf16[16]; __shared__ const float* pb16[16];
  __shared__ int lem_s[16], val_s[16], b_s[16];
  int r0=blockIdx.x*16, tid=threadIdx.x;
  if(tid<16){
    int r=r0+tid, b=r>>7, t=r&127, lb=len[b];
    int v=(t<lb); val_s[tid]=v; b_s[tid]=b;
    int lem=u2l[seq[r]];
    lem_s[tid]=lem;
    pf16[tid]=hglob+((long)t*BB+b)*SZ;
    int tr=v? (lb-1-t) : t;
    pb16[tid]=hglob+((long)(LL+tr)*BB+b)*SZ;
    if(v) flags[(long)b*NLEM+lem]=1u;
  }
  __syncthreads();
  for(int i=tid;i<16*SZ;i+=256){int lr=i>>8,j=i&(SZ-1);
    As[lr][j]=pf16[lr][j]; As[lr][SZ+j]=pb16[lr][j];}
  __syncthreads();
  int cl=tid&63, rg=tid>>6;
  float acc[4][4];
  #pragma unroll
  for(int i=0;i<4;i++){acc[i][0]=acc[i][1]=acc[i][2]=acc[i][3]=0.f;}
  for(int k=0;k<2*SZ;k+=4){
    float4 a4[4];
    #pragma unroll
    for(int i=0;i<4;i++) a4[i]=*(const float4*)&As[rg*4+i][k];
    #pragma unroll
    for(int j=0;j<4;j++){
      const float* wr=Wenc+(long)(k+j)*SZ+cl;
      float w0=wr[0],w1=wr[64],w2=wr[128],w3=wr[192];
      #pragma unroll
      for(int i=0;i<4;i++){
        float a=(j==0)?a4[i].x:(j==1)?a4[i].y:(j==2)?a4[i].z:a4[i].w;
        acc[i][0]=fmaf(a,w0,acc[i][0]);acc[i][1]=fmaf(a,w1,acc[i][1]);
        acc[i][2]=fmaf(a,w2,acc[i][2]);acc[i][3]=fmaf(a,w3,acc[i][3]);
      }
    }
  }
  #pragma unroll
  for(int i=0;i<4;i++){
    int lr=rg*4+i;
    if(val_s[lr]){
      long base=((long)b_s[lr]*NLEM+lem_s[lr])*SZ;
      #pragma unroll
      for(int cc=0;cc<4;cc++){
        int col=cl+cc*64;
        float e=fmaxf(acc[i][cc]+benc[col],0.f);
        atomicMax(&lembuf[base+col], __float_as_uint(e));
      }
    }
  }
}

// ------------ generic C[r] = A[r] @ W  (K=256), optional touched-flags ------
__global__ void k_rowgemm(const float* __restrict__ A, const float* __restrict__ W,
                          float* __restrict__ C, const unsigned int* __restrict__ flags){
  __shared__ __align__(16) float As[16][SZ];
  __shared__ int any_s;
  int r0=blockIdx.x*16, tid=threadIdx.x;
  if(tid==0){
    int a = flags? 0 : 1;
    if(flags){ for(int i=0;i<16;i++) a |= (int)flags[r0+i]; }
    any_s=a;
  }
  __syncthreads();
  if(!any_s) return;
  for(int i=tid;i<16*SZ;i+=256){int lr=i>>8,j=i&(SZ-1);As[lr][j]=A[(long)(r0+lr)*SZ+j];}
  __syncthreads();
  int cl=tid&63, rg=tid>>6;
  float acc[4][4];
  #pragma unroll
  for(int i=0;i<4;i++){acc[i][0]=acc[i][1]=acc[i][2]=acc[i][3]=0.f;}
  for(int k=0;k<SZ;k+=4){
    float4 a4[4];
    #pragma unroll
    for(int i=0;i<4;i++) a4[i]=*(const float4*)&As[rg*4+i][k];
    #pragma unroll
    for(int j=0;j<4;j++){
      const float* wr=W+(long)(k+j)*SZ+cl;
      float w0=wr[0],w1=wr[64],w2=wr[128],w3=wr[192];
      #pragma unroll
      for(int i=0;i<4;i++){
        float a=(j==0)?a4[i].x:(j==1)?a4[i].y:(j==2)?a4[i].z:a4[i].w;
        acc[i][0]=fmaf(a,w0,acc[i][0]);acc[i][1]=fmaf(a,w1,acc[i][1]);
        acc[i][2]=fmaf(a,w2,acc[i][2]);acc[i][3]=fmaf(a,w3,acc[i][3]);
      }
    }
  }
  #pragma unroll
  for(int i=0;i<4;i++){
    int r=r0+rg*4+i;
    #pragma unroll
    for(int cc=0;cc<4;cc++) C[(long)r*SZ+cl+cc*64]=acc[i][cc];
  }
}

// ------- iter-0 gate: ctxt==tile(we) -> pure elementwise from P0/Q ----------
__global__ void k_gate0(const float* __restrict__ we, const float* __restrict__ P0,
                        const float* __restrict__ Q, const float* __restrict__ lembuf,
                        const int* __restrict__ u2l, const unsigned int* __restrict__ flags,
                        const float* __restrict__ bg, float* __restrict__ out){
  long idx=(long)blockIdx.x*256+threadIdx.x;      // one float4 each
  const long TOTAL4=(long)BB*NW*SZ/4;
  if(idx>=TOTAL4) return;
  long row=idx>>6; int k4=(int)(idx&63);
  int r32=(int)row;
  int b=r32/NW, w=r32-b*NW;
  int lem=u2l[w];
  long qb=((long)b*NLEM+lem)*SZ;
  unsigned int fl=flags[(long)b*NLEM+lem];
  float4 p =((const float4*)(P0+(long)w*SZ))[k4];
  float4 wv=((const float4*)(we+(long)w*SZ))[k4];
  float4 bgv=((const float4*)bg)[k4];
  float4 q, nw;
  if(fl){ q=((const float4*)(Q+qb))[k4]; nw=((const float4*)(lembuf+qb))[k4]; }
  else  { q=make_float4(0.f,0.f,0.f,0.f); nw=q; }
  float4 o;
  { float g=sigf(p.x+q.x+bgv.x); o.x=wv.x*g+(1.f-g)*nw.x; }
  { float g=sigf(p.y+q.y+bgv.y); o.y=wv.y*g+(1.f-g)*nw.y; }
  { float g=sigf(p.z+q.z+bgv.z); o.z=wv.z*g+(1.f-g)*nw.z; }
  { float g=sigf(p.w+q.w+bgv.w); o.w=wv.w*g+(1.f-g)*nw.w; }
  ((float4*)out)[idx]=o;
}

// ------- iter-1 gate: fused ctxt@Wg1 GEMM + gate + in-place update ----------
__global__ void k_gate1(const float* __restrict__ ctxt, const float* __restrict__ Wg,
                        const float* __restrict__ Q, const float* __restrict__ lembuf,
                        const int* __restrict__ u2l, const unsigned int* __restrict__ flags,
                        const float* __restrict__ bg, float* __restrict__ out){
  __shared__ __align__(16) float As[64][SZ];   // 64 KB
  __shared__ __align__(16) float Ws[64][SZ];   // 64 KB
  __shared__ int lem_s[64];
  int r0=blockIdx.x*64, tid=threadIdx.x;
  for(int i=tid;i<64*SZ;i+=256){int lr=i>>8,j=i&(SZ-1);
    As[lr][j]=ctxt[(long)(r0+lr)*SZ+j];}
  if(tid<64){int r=r0+tid; lem_s[tid]=u2l[r%NW];}
  int cl=tid&63, rg=tid>>6;
  float acc[16][4];
  #pragma unroll
  for(int i=0;i<16;i++){acc[i][0]=acc[i][1]=acc[i][2]=acc[i][3]=0.f;}
  for(int kb=0;kb<4;kb++){
    __syncthreads();
    for(int i=tid;i<64*SZ;i+=256){int lr=i>>8,j=i&(SZ-1);
      Ws[lr][j]=Wg[(long)(kb*64+lr)*SZ+j];}
    __syncthreads();
    for(int k=0;k<64;k+=4){
      float4 a4[16];
      #pragma unroll
      for(int i=0;i<16;i++) a4[i]=*(const float4*)&As[rg*16+i][kb*64+k];
      #pragma unroll
      for(int j=0;j<4;j++){
        float w0=Ws[k+j][cl],w1=Ws[k+j][cl+64],w2=Ws[k+j][cl+128],w3=Ws[k+j][cl+192];
        #pragma unroll
        for(int i=0;i<16;i++){
          float a=(j==0)?a4[i].x:(j==1)?a4[i].y:(j==2)?a4[i].z:a4[i].w;
          acc[i][0]=fmaf(a,w0,acc[i][0]);acc[i][1]=fmaf(a,w1,acc[i][1]);
          acc[i][2]=fmaf(a,w2,acc[i][2]);acc[i][3]=fmaf(a,w3,acc[i][3]);
        }
      }
    }
  }
  #pragma unroll
  for(int i=0;i<16;i++){
    int lr=rg*16+i, r=r0+lr, b=r/NW;
    long base=((long)b*NLEM+lem_s[lr])*SZ;
    unsigned int fl=flags[(long)b*NLEM+lem_s[lr]];
    #pragma unroll
    for(int cc=0;cc<4;cc++){
      int col=cl+cc*64;
      float qv=0.f, nw=0.f;
      if(fl){ qv=Q[base+col]; nw=lembuf[base+col]; }
      float g=sigf(acc[i][cc]+qv+bg[col]);
      out[(long)r*SZ+col]=As[lr][col]*g+(1.f-g)*nw;
    }
  }
}

extern "C" void kernel_launch(void* const* d_in, const int* in_sizes, int n_in,
                              void* d_out, int out_size, void* d_ws, size_t ws_size,
                              hipStream_t stream){
  const float* emb  =(const float*)d_in[0];
  const float* Wp   =(const float*)d_in[1];
  const float* bp   =(const float*)d_in[2];
  const float* Wi_f =(const float*)d_in[3];
  const float* Wh_f =(const float*)d_in[4];
  const float* b_f  =(const float*)d_in[5];
  const float* Wi_b =(const float*)d_in[6];
  const float* Wh_b =(const float*)d_in[7];
  const float* b_b  =(const float*)d_in[8];
  const float* Wenc =(const float*)d_in[9];
  const float* benc =(const float*)d_in[10];
  const float* Wg   =(const float*)d_in[11];
  const float* bg   =(const float*)d_in[12];
  const int*   seq0 =(const int*)d_in[13];
  const int*   seq1 =(const int*)d_in[14];
  const int*   len0 =(const int*)d_in[15];
  const int*   len1 =(const int*)d_in[16];
  const int*   u2l  =(const int*)d_in[17];

  float* ws    = (float*)d_ws;
  float* we    = ws;                       // 2,560,000
  float* xwi   = we    + 2560000;          // 4,194,304 (fragment layout)
  float* hglob = xwi   + 4194304;          // 1,048,576
  float* lembuf= hglob + 1048576;          // 12,288,000
  float* flags = lembuf+ 12288000;         // 48,000 (uint)
  float* Q     = flags + 48000;            // 12,288,000
  float* P0    = Q     + 12288000;         // 2,560,000
  short* whb   = (short*)(P0 + 2560000);   // 524,288 shorts (262,144 floats)
  float* out   = (float*)d_out;

  hipFuncSetAttribute((const void*)k_lstm_mfma,
                      hipFuncAttributeMaxDynamicSharedMemorySize, 147968);

  k_we<<<NW/16,256,0,stream>>>(emb,Wp,bp,we);
  k_rowgemm<<<NW/16,256,0,stream>>>(we,Wg,P0,nullptr);            // P0 = we@Wg1
  k_prep<<<256,256,0,stream>>>(Wh_f,Wh_b,whb);

  const int* seqs[2]={seq0,seq1};
  const int* lens[2]={len0,len1};
  for(int i=0;i<2;i++){
    hipMemsetAsync(lembuf,0,(size_t)(12288000+48000)*4,stream);   // lembuf + flags
    const float* src = (i==0)? we : out;
    long bstride     = (i==0)? 0L : (long)NW*SZ;
    dim3 gx(64,4);
    k_xwi<<<gx,256,0,stream>>>(seqs[i],lens[i],src,bstride,Wi_f,b_f,Wi_b,b_b,i,xwi);
    k_lstm_mfma<<<2,256,147968,stream>>>(whb,xwi,hglob);
    k_enc<<<BB*LL/16,256,0,stream>>>(seqs[i],lens[i],u2l,hglob,Wenc,benc,
                                     (unsigned int*)lembuf,(unsigned int*)flags);
    k_rowgemm<<<BB*NLEM/16,256,0,stream>>>(lembuf,Wg+(long)SZ*SZ,Q,
                                           (const unsigned int*)flags); // Q = nw@Wg2
    if(i==0){
      long nb=((long)BB*NW*SZ/4+255)/256;
      k_gate0<<<(int)nb,256,0,stream>>>(we,P0,Q,lembuf,u2l,
                                        (const unsigned int*)flags,bg,out);
    }else{
      k_gate1<<<BB*NW/64,256,0,stream>>>(out,Wg,Q,lembuf,u2l,
                                         (const unsigned int*)flags,bg,out);
    }
  }
}

// Round 4
// 2474.919 us; speedup vs baseline: 3.1340x; 1.3727x over previous
//
#include <hip/hip_runtime.h>

#define NW    10000
#define INDIM 300
#define SZ    256
#define BB    16
#define LL    128
#define NLEM  3000
#define FH    1024   // 4*SZ
#define NCAPMAX 32768

typedef short  bf16x8 __attribute__((ext_vector_type(8)));
typedef float  f32x4  __attribute__((ext_vector_type(4)));

__device__ __forceinline__ float sigf(float x){ return 1.f/(1.f+__expf(-x)); }
__device__ __forceinline__ float tanhf_(float x){ return 2.f/(1.f+__expf(-2.f*x)) - 1.f; }
__device__ __forceinline__ short f2b(float f){
  unsigned u=__float_as_uint(f); u += 0x7FFFu + ((u>>16)&1u); return (short)(u>>16);
}

// ---------------- we = relu(emb @ Wp + bp) : [10000,300]@[300,256] ----------
__global__ void k_we(const float* __restrict__ emb, const float* __restrict__ Wp,
                     const float* __restrict__ bp, float* __restrict__ we){
  __shared__ __align__(16) float As[16][INDIM];
  int r0 = blockIdx.x*16, tid = threadIdx.x;
  for(int i=tid;i<16*INDIM;i+=256){int lr=i/INDIM,d=i-lr*INDIM;
    As[lr][d]=emb[(long)(r0+lr)*INDIM+d];}
  __syncthreads();
  int cl=tid&63, rg=tid>>6;
  float acc[4][4];
  #pragma unroll
  for(int i=0;i<4;i++){acc[i][0]=acc[i][1]=acc[i][2]=acc[i][3]=0.f;}
  for(int k=0;k<INDIM;k+=4){
    float4 a4[4];
    #pragma unroll
    for(int i=0;i<4;i++) a4[i]=*(const float4*)&As[rg*4+i][k];
    #pragma unroll
    for(int j=0;j<4;j++){
      const float* wr=Wp+(long)(k+j)*SZ+cl;
      float w0=wr[0],w1=wr[64],w2=wr[128],w3=wr[192];
      #pragma unroll
      for(int i=0;i<4;i++){
        float a=(j==0)?a4[i].x:(j==1)?a4[i].y:(j==2)?a4[i].z:a4[i].w;
        acc[i][0]=fmaf(a,w0,acc[i][0]);acc[i][1]=fmaf(a,w1,acc[i][1]);
        acc[i][2]=fmaf(a,w2,acc[i][2]);acc[i][3]=fmaf(a,w3,acc[i][3]);
      }
    }
  }
  #pragma unroll
  for(int i=0;i<4;i++){
    int r=r0+rg*4+i;
    #pragma unroll
    for(int cc=0;cc<4;cc++){int col=cl+cc*64;
      we[(long)r*SZ+col]=fmaxf(acc[i][cc]+bp[col],0.f);}
  }
}

// ---- xwi (fragment-layout output): value = x_row @ Wi[:256] + Wi[256+iseq] + b
__global__ void k_xwi(const int* __restrict__ seq, const int* __restrict__ len,
                      const float* __restrict__ src, long bstride,
                      const float* __restrict__ Wi_f, const float* __restrict__ bvf,
                      const float* __restrict__ Wi_b, const float* __restrict__ bvb,
                      int iseq, float* __restrict__ xwi){
  __shared__ __align__(16) float As[64][SZ];
  __shared__ const float* rowp[64];
  int r0=blockIdx.x*64, cb=blockIdx.y, tid=threadIdx.x;
  int dir=r0>>11;
  if(tid<64){
    int grow=r0+tid;
    int t=(grow>>4)&(LL-1), b=grow&(BB-1);
    int lb=len[b];
    int tt=(dir==0)? t : ((t<lb)? (lb-1-t) : t);
    int tok=seq[b*LL+tt];
    rowp[tid]=src + (long)b*bstride + (long)tok*SZ;
  }
  __syncthreads();
  for(int i=tid;i<64*SZ;i+=256){int lr=i>>8,j=i&(SZ-1);As[lr][j]=rowp[lr][j];}
  __syncthreads();
  const float* __restrict__ Wi = dir? Wi_b : Wi_f;
  const float* __restrict__ bv = dir? bvb : bvf;
  int cl=tid&63, rg=tid>>6, c0=cb*256+cl;
  float acc[16][4];
  #pragma unroll
  for(int i=0;i<16;i++){acc[i][0]=acc[i][1]=acc[i][2]=acc[i][3]=0.f;}
  for(int k=0;k<SZ;k+=4){
    float4 a4[16];
    #pragma unroll
    for(int i=0;i<16;i++) a4[i]=*(const float4*)&As[rg*16+i][k];
    #pragma unroll
    for(int j=0;j<4;j++){
      const float* wr=Wi+(long)(k+j)*FH+c0;
      float w0=wr[0],w1=wr[64],w2=wr[128],w3=wr[192];
      #pragma unroll
      for(int i=0;i<16;i++){
        float a=(j==0)?a4[i].x:(j==1)?a4[i].y:(j==2)?a4[i].z:a4[i].w;
        acc[i][0]=fmaf(a,w0,acc[i][0]);acc[i][1]=fmaf(a,w1,acc[i][1]);
        acc[i][2]=fmaf(a,w2,acc[i][2]);acc[i][3]=fmaf(a,w3,acc[i][3]);
      }
    }
  }
  #pragma unroll
  for(int cc=0;cc<4;cc++){
    int cx=c0+cc*64;
    float be=Wi[(long)(SZ+iseq)*FH+cx]+bv[cx];
    int g=cx>>8, rem=cx&255, w2=rem>>6, ug=(rem>>4)&3, nl=rem&15, nt=ug*4+g;
    #pragma unroll
    for(int i=0;i<16;i++){
      int grow=r0+rg*16+i;
      int b=grow&15, t=(grow>>4)&127, d2=grow>>11;
      long idx3=((((long)d2*128+t)*4+w2)*64 + (b>>2)*16+nl)*64 + nt*4 + (b&3);
      xwi[idx3]=acc[i][cc]+be;
    }
  }
}

// ---- prep: Wh -> bf16 MFMA B-fragments, gate-grouped column permutation ----
__global__ void k_prep(const float* __restrict__ Wh_f, const float* __restrict__ Wh_b,
                       short* __restrict__ frag){
  int tid = blockIdx.x*256 + threadIdx.x;   // 65536 total
  int l = tid&63, T=(tid>>6)&127, w=(tid>>13)&3, dir=tid>>15;
  const float* Wh = dir? Wh_b : Wh_f;
  int nt=T>>3, ks=T&7, ug=nt>>2, g=nt&3;
  int col = g*256 + w*64 + ug*16 + (l&15);
  int k0 = ks*32 + 8*(l>>4);
  short v[8];
  #pragma unroll
  for(int j=0;j<8;j++) v[j]=f2b(Wh[(long)(k0+j)*FH + col]);
  *(bf16x8*)(frag + (long)tid*8) = *(bf16x8*)v;
}

// --------- MFMA batched persistent LSTM: 1 block/dir, 256 thr ---------------
#define MF(a,b,c) __builtin_amdgcn_mfma_f32_16x16x32_bf16(a,b,c,0,0,0)
#define LDF(T)    (*(const bf16x8*)(fr + (long)(T)*512 + l*8))
#define LDL(nt,ks) (*(const bf16x8*)(bl + ((nt)-9)*4096 + (ks)*512 + l*8))
#define DECLR(nt) bf16x8 R##nt##_0=LDF(nt*8+0),R##nt##_1=LDF(nt*8+1),R##nt##_2=LDF(nt*8+2),R##nt##_3=LDF(nt*8+3),R##nt##_4=LDF(nt*8+4),R##nt##_5=LDF(nt*8+5),R##nt##_6=LDF(nt*8+6),R##nt##_7=LDF(nt*8+7);
#define DECLC(nt) f32x4 C##nt={0.f,0.f,0.f,0.f};
#define MMR(nt) { C##nt=MF(A0,R##nt##_0,C##nt); C##nt=MF(A1,R##nt##_1,C##nt); C##nt=MF(A2,R##nt##_2,C##nt); C##nt=MF(A3,R##nt##_3,C##nt); C##nt=MF(A4,R##nt##_4,C##nt); C##nt=MF(A5,R##nt##_5,C##nt); C##nt=MF(A6,R##nt##_6,C##nt); C##nt=MF(A7,R##nt##_7,C##nt); }
#define MML(nt) { C##nt=MF(A0,LDL(nt,0),C##nt); C##nt=MF(A1,LDL(nt,1),C##nt); C##nt=MF(A2,LDL(nt,2),C##nt); C##nt=MF(A3,LDL(nt,3),C##nt); C##nt=MF(A4,LDL(nt,4),C##nt); C##nt=MF(A5,LDL(nt,5),C##nt); C##nt=MF(A6,LDL(nt,6),C##nt); C##nt=MF(A7,LDL(nt,7),C##nt); }
#define MMS(nt) { C##nt=MF(A0,LDF(nt*8+0),C##nt); C##nt=MF(A1,LDF(nt*8+1),C##nt); C##nt=MF(A2,LDF(nt*8+2),C##nt); C##nt=MF(A3,LDF(nt*8+3),C##nt); C##nt=MF(A4,LDF(nt*8+4),C##nt); C##nt=MF(A5,LDF(nt*8+5),C##nt); C##nt=MF(A6,LDF(nt*8+6),C##nt); C##nt=MF(A7,LDF(nt*8+7),C##nt); }
#define XLD(ug,g) (*(const f32x4*)(xp + ((ug)*4+(g))*4))
#define GATE1(ug,r,CA,CB,CC,CD,X0,X1,X2,X3) { \
  float zi=CA[r]+X0[r], zf=CB[r]+X1[r], zg=CC[r]+X2[r], zo=CD[r]+X3[r]; \
  cst_##ug##_##r = sigf(zf)*cst_##ug##_##r + sigf(zi)*tanhf_(zg); \
  float hv = sigf(zo)*tanhf_(cst_##ug##_##r); \
  int b_=4*(l>>4)+(r); int u_=w*64+(ug)*16+(l&15); \
  hbn[b_*264+u_]=f2b(hv); \
  hg[((long)t*16+b_)*256+u_]=hv; }
#define GATES(ug,CA,CB,CC,CD,X0,X1,X2,X3) \
  GATE1(ug,0,CA,CB,CC,CD,X0,X1,X2,X3) GATE1(ug,1,CA,CB,CC,CD,X0,X1,X2,X3) \
  GATE1(ug,2,CA,CB,CC,CD,X0,X1,X2,X3) GATE1(ug,3,CA,CB,CC,CD,X0,X1,X2,X3)

extern __shared__ char smem_raw[];

__global__ __launch_bounds__(256,1) void k_lstm_mfma(
    const short* __restrict__ frag, const float* __restrict__ xwi3,
    float* __restrict__ hglob){
  const int dir = blockIdx.x;
  const int tid = threadIdx.x;
  const int w = tid>>6, l = tid&63;
  short* hb = (short*)smem_raw;                        // 2 x 16 x 264 shorts
  short* bl = (short*)(smem_raw + 16896) + w*16384;    // per-wave LDS B tiles
  const short* fr = frag + (long)(dir*4+w)*128*512;

  for(int i=tid;i<4224;i+=256) ((int*)smem_raw)[i]=0;  // zero both h buffers

  #pragma unroll 4
  for(int c2=0;c2<32;c2++)
    *(f32x4*)(bl + c2*512 + l*8) = *(const f32x4*)(fr + 72*512 + c2*512 + l*8);

  DECLR(0) DECLR(1) DECLR(2) DECLR(3) DECLR(4) DECLR(5) DECLR(6) DECLR(7) DECLR(8)

  float cst_0_0=0,cst_0_1=0,cst_0_2=0,cst_0_3=0, cst_1_0=0,cst_1_1=0,cst_1_2=0,cst_1_3=0,
        cst_2_0=0,cst_2_1=0,cst_2_2=0,cst_2_3=0, cst_3_0=0,cst_3_1=0,cst_3_2=0,cst_3_3=0;
  __syncthreads();

  const float* xwb = xwi3 + (long)dir*2097152 + (long)(w*64+l)*64;
  float* hg = hglob + (long)dir*524288;

  for(int t=0;t<LL;t++){
    const int cur=t&1, nxt=cur^1;
    const short* hr = hb + cur*4224 + (l&15)*264 + (l>>4)*8;
    bf16x8 A0=*(const bf16x8*)(hr+0),   A1=*(const bf16x8*)(hr+32),
           A2=*(const bf16x8*)(hr+64),  A3=*(const bf16x8*)(hr+96),
           A4=*(const bf16x8*)(hr+128), A5=*(const bf16x8*)(hr+160),
           A6=*(const bf16x8*)(hr+192), A7=*(const bf16x8*)(hr+224);
    const float* xp = xwb + (long)t*16384;
    f32x4 xa0=XLD(0,0), xa1=XLD(0,1), xa2=XLD(0,2), xa3=XLD(0,3);
    DECLC(0) DECLC(1) DECLC(2) DECLC(3) DECLC(4) DECLC(5) DECLC(6) DECLC(7)
    DECLC(8) DECLC(9) DECLC(10) DECLC(11) DECLC(12) DECLC(13) DECLC(14) DECLC(15)
    MMR(0) MMR(1) MMR(2) MMR(3) MMR(4) MMR(5) MMR(6) MMR(7) MMR(8)
    MML(9) MML(10) MML(11) MML(12)
    MMS(13) MMS(14) MMS(15)
    short* hbn = hb + nxt*4224;
    f32x4 xb0=XLD(1,0), xb1=XLD(1,1), xb2=XLD(1,2), xb3=XLD(1,3);
    GATES(0, C0,C1,C2,C3,     xa0,xa1,xa2,xa3)
    f32x4 xc0=XLD(2,0), xc1=XLD(2,1), xc2=XLD(2,2), xc3=XLD(2,3);
    GATES(1, C4,C5,C6,C7,     xb0,xb1,xb2,xb3)
    f32x4 xd0=XLD(3,0), xd1=XLD(3,1), xd2=XLD(3,2), xd3=XLD(3,3);
    GATES(2, C8,C9,C10,C11,   xc0,xc1,xc2,xc3)
    GATES(3, C12,C13,C14,C15, xd0,xd1,xd2,xd3)
    __syncthreads();
  }
}

// ---- enc = [hf|hb] @ Wenc + benc, relu(max) scatter into lembuf + flags ----
__global__ void k_enc(const int* __restrict__ seq, const int* __restrict__ len,
                      const int* __restrict__ u2l, const float* __restrict__ hglob,
                      const float* __restrict__ Wenc, const float* __restrict__ benc,
                      unsigned int* __restrict__ lembuf, unsigned int* __restrict__ flags){
  __shared__ __align__(16) float As[16][2*SZ];
  __shared__ const float* pf16[16]; __shared__ const float* pb16[16];
  __shared__ int lem_s[16], val_s[16], b_s[16];
  int r0=blockIdx.x*16, tid=threadIdx.x;
  if(tid<16){
    int r=r0+tid, b=r>>7, t=r&127, lb=len[b];
    int v=(t<lb); val_s[tid]=v; b_s[tid]=b;
    int lem=u2l[seq[r]];
    lem_s[tid]=lem;
    pf16[tid]=hglob+((long)t*BB+b)*SZ;
    int tr=v? (lb-1-t) : t;
    pb16[tid]=hglob+((long)(LL+tr)*BB+b)*SZ;
    if(v) flags[(long)b*NLEM+lem]=1u;
  }
  __syncthreads();
  for(int i=tid;i<16*SZ;i+=256){int lr=i>>8,j=i&(SZ-1);
    As[lr][j]=pf16[lr][j]; As[lr][SZ+j]=pb16[lr][j];}
  __syncthreads();
  int cl=tid&63, rg=tid>>6;
  float acc[4][4];
  #pragma unroll
  for(int i=0;i<4;i++){acc[i][0]=acc[i][1]=acc[i][2]=acc[i][3]=0.f;}
  for(int k=0;k<2*SZ;k+=4){
    float4 a4[4];
    #pragma unroll
    for(int i=0;i<4;i++) a4[i]=*(const float4*)&As[rg*4+i][k];
    #pragma unroll
    for(int j=0;j<4;j++){
      const float* wr=Wenc+(long)(k+j)*SZ+cl;
      float w0=wr[0],w1=wr[64],w2=wr[128],w3=wr[192];
      #pragma unroll
      for(int i=0;i<4;i++){
        float a=(j==0)?a4[i].x:(j==1)?a4[i].y:(j==2)?a4[i].z:a4[i].w;
        acc[i][0]=fmaf(a,w0,acc[i][0]);acc[i][1]=fmaf(a,w1,acc[i][1]);
        acc[i][2]=fmaf(a,w2,acc[i][2]);acc[i][3]=fmaf(a,w3,acc[i][3]);
      }
    }
  }
  #pragma unroll
  for(int i=0;i<4;i++){
    int lr=rg*4+i;
    if(val_s[lr]){
      long base=((long)b_s[lr]*NLEM+lem_s[lr])*SZ;
      #pragma unroll
      for(int cc=0;cc<4;cc++){
        int col=cl+cc*64;
        float e=fmaxf(acc[i][cc]+benc[col],0.f);
        atomicMax(&lembuf[base+col], __float_as_uint(e));
      }
    }
  }
}

// ------------ generic C[r] = A[r] @ W  (K=256), optional touched-flags ------
__global__ void k_rowgemm(const float* __restrict__ A, const float* __restrict__ W,
                          float* __restrict__ C, const unsigned int* __restrict__ flags){
  __shared__ __align__(16) float As[16][SZ];
  __shared__ int any_s;
  int r0=blockIdx.x*16, tid=threadIdx.x;
  if(tid==0){
    int a = flags? 0 : 1;
    if(flags){ for(int i=0;i<16;i++) a |= (int)flags[r0+i]; }
    any_s=a;
  }
  __syncthreads();
  if(!any_s) return;
  for(int i=tid;i<16*SZ;i+=256){int lr=i>>8,j=i&(SZ-1);As[lr][j]=A[(long)(r0+lr)*SZ+j];}
  __syncthreads();
  int cl=tid&63, rg=tid>>6;
  float acc[4][4];
  #pragma unroll
  for(int i=0;i<4;i++){acc[i][0]=acc[i][1]=acc[i][2]=acc[i][3]=0.f;}
  for(int k=0;k<SZ;k+=4){
    float4 a4[4];
    #pragma unroll
    for(int i=0;i<4;i++) a4[i]=*(const float4*)&As[rg*4+i][k];
    #pragma unroll
    for(int j=0;j<4;j++){
      const float* wr=W+(long)(k+j)*SZ+cl;
      float w0=wr[0],w1=wr[64],w2=wr[128],w3=wr[192];
      #pragma unroll
      for(int i=0;i<4;i++){
        float a=(j==0)?a4[i].x:(j==1)?a4[i].y:(j==2)?a4[i].z:a4[i].w;
        acc[i][0]=fmaf(a,w0,acc[i][0]);acc[i][1]=fmaf(a,w1,acc[i][1]);
        acc[i][2]=fmaf(a,w2,acc[i][2]);acc[i][3]=fmaf(a,w3,acc[i][3]);
      }
    }
  }
  #pragma unroll
  for(int i=0;i<4;i++){
    int r=r0+rg*4+i;
    #pragma unroll
    for(int cc=0;cc<4;cc++) C[(long)r*SZ+cl+cc*64]=acc[i][cc];
  }
}

// ---- P1base: A=we*sig(P0+bg) staged on the fly; result overwrites P0 -------
__global__ void k_p1base(const float* __restrict__ we, float* __restrict__ P0,
                         const float* __restrict__ bg, const float* __restrict__ W){
  __shared__ __align__(16) float As[16][SZ];
  int r0=blockIdx.x*16, tid=threadIdx.x;
  for(int i=tid;i<16*SZ;i+=256){int lr=i>>8,j=i&(SZ-1);
    long off=(long)(r0+lr)*SZ+j;
    As[lr][j]=we[off]*sigf(P0[off]+bg[j]);}
  __syncthreads();
  int cl=tid&63, rg=tid>>6;
  float acc[4][4];
  #pragma unroll
  for(int i=0;i<4;i++){acc[i][0]=acc[i][1]=acc[i][2]=acc[i][3]=0.f;}
  for(int k=0;k<SZ;k+=4){
    float4 a4[4];
    #pragma unroll
    for(int i=0;i<4;i++) a4[i]=*(const float4*)&As[rg*4+i][k];
    #pragma unroll
    for(int j=0;j<4;j++){
      const float* wr=W+(long)(k+j)*SZ+cl;
      float w0=wr[0],w1=wr[64],w2=wr[128],w3=wr[192];
      #pragma unroll
      for(int i=0;i<4;i++){
        float a=(j==0)?a4[i].x:(j==1)?a4[i].y:(j==2)?a4[i].z:a4[i].w;
        acc[i][0]=fmaf(a,w0,acc[i][0]);acc[i][1]=fmaf(a,w1,acc[i][1]);
        acc[i][2]=fmaf(a,w2,acc[i][2]);acc[i][3]=fmaf(a,w3,acc[i][3]);
      }
    }
  }
  #pragma unroll
  for(int i=0;i<4;i++){
    int r=r0+rg*4+i;
    #pragma unroll
    for(int cc=0;cc<4;cc++) P0[(long)r*SZ+cl+cc*64]=acc[i][cc];
  }
}

// ---- compact list of rows whose lemma was touched in iter 0 ----------------
__global__ void k_compact(const int* __restrict__ u2l, const unsigned int* __restrict__ flags,
                          int* __restrict__ cnt, int* __restrict__ list,
                          int* __restrict__ idxmap, int ncap){
  int r = blockIdx.x*256+threadIdx.x;
  if(r>=BB*NW) return;
  int b=r/NW, w=r-b*NW;
  int im=-1;
  if(flags[(long)b*NLEM+u2l[w]]){
    int idx=atomicAdd(cnt,1);
    if(idx<ncap){ list[idx]=r; im=idx; }
  }
  idxmap[r]=im;
}

// ---- Ptouch[i] = out[list[i]] @ Wg1 over the compacted rows ----------------
__global__ void k_ptouch(const float* __restrict__ out, const float* __restrict__ W,
                         const int* __restrict__ cnt, const int* __restrict__ list,
                         float* __restrict__ Pt){
  __shared__ __align__(16) float As[16][SZ];
  __shared__ const float* rp[16];
  int n=*cnt;
  int r0=blockIdx.x*16, tid=threadIdx.x;
  if(r0>=n) return;
  if(tid<16){
    int idx=r0+tid;
    rp[tid]=(idx<n)? out+(long)list[idx]*SZ : nullptr;
  }
  __syncthreads();
  for(int i=tid;i<16*SZ;i+=256){int lr=i>>8,j=i&(SZ-1);
    As[lr][j]= rp[lr]? rp[lr][j] : 0.f;}
  __syncthreads();
  int cl=tid&63, rg=tid>>6;
  float acc[4][4];
  #pragma unroll
  for(int i=0;i<4;i++){acc[i][0]=acc[i][1]=acc[i][2]=acc[i][3]=0.f;}
  for(int k=0;k<SZ;k+=4){
    float4 a4[4];
    #pragma unroll
    for(int i=0;i<4;i++) a4[i]=*(const float4*)&As[rg*4+i][k];
    #pragma unroll
    for(int j=0;j<4;j++){
      const float* wr=W+(long)(k+j)*SZ+cl;
      float w0=wr[0],w1=wr[64],w2=wr[128],w3=wr[192];
      #pragma unroll
      for(int i=0;i<4;i++){
        float a=(j==0)?a4[i].x:(j==1)?a4[i].y:(j==2)?a4[i].z:a4[i].w;
        acc[i][0]=fmaf(a,w0,acc[i][0]);acc[i][1]=fmaf(a,w1,acc[i][1]);
        acc[i][2]=fmaf(a,w2,acc[i][2]);acc[i][3]=fmaf(a,w3,acc[i][3]);
      }
    }
  }
  #pragma unroll
  for(int i=0;i<4;i++){
    int idx=r0+rg*4+i;
    if(idx<n){
      #pragma unroll
      for(int cc=0;cc<4;cc++) Pt[(long)idx*SZ+cl+cc*64]=acc[i][cc];
    }
  }
}

// ------- iter-0 gate: ctxt==tile(we) -> pure elementwise from P0/Q ----------
__global__ void k_gate0(const float* __restrict__ we, const float* __restrict__ P0,
                        const float* __restrict__ Q, const float* __restrict__ lembuf,
                        const int* __restrict__ u2l, const unsigned int* __restrict__ flags,
                        const float* __restrict__ bg, float* __restrict__ out){
  long idx=(long)blockIdx.x*256+threadIdx.x;
  const long TOTAL4=(long)BB*NW*SZ/4;
  if(idx>=TOTAL4) return;
  long row=idx>>6; int k4=(int)(idx&63);
  int r32=(int)row;
  int b=r32/NW, w=r32-b*NW;
  int lem=u2l[w];
  long qb=((long)b*NLEM+lem)*SZ;
  unsigned int fl=flags[(long)b*NLEM+lem];
  float4 p =((const float4*)(P0+(long)w*SZ))[k4];
  float4 wv=((const float4*)(we+(long)w*SZ))[k4];
  float4 bgv=((const float4*)bg)[k4];
  float4 q, nw;
  if(fl){ q=((const float4*)(Q+qb))[k4]; nw=((const float4*)(lembuf+qb))[k4]; }
  else  { q=make_float4(0.f,0.f,0.f,0.f); nw=q; }
  float4 o;
  { float g=sigf(p.x+q.x+bgv.x); o.x=wv.x*g+(1.f-g)*nw.x; }
  { float g=sigf(p.y+q.y+bgv.y); o.y=wv.y*g+(1.f-g)*nw.y; }
  { float g=sigf(p.z+q.z+bgv.z); o.z=wv.z*g+(1.f-g)*nw.z; }
  { float g=sigf(p.w+q.w+bgv.w); o.w=wv.w*g+(1.f-g)*nw.w; }
  ((float4*)out)[idx]=o;
}

// ------- iter-1 gate, elementwise: P from Ptouch (touched0) or P1base -------
__global__ void k_gate1e(const float* __restrict__ P1base, const float* __restrict__ Pt,
                         const int* __restrict__ idxmap,
                         const float* __restrict__ Q, const float* __restrict__ lembuf,
                         const int* __restrict__ u2l, const unsigned int* __restrict__ flags,
                         const float* __restrict__ bg, float* __restrict__ out){
  long idx=(long)blockIdx.x*256+threadIdx.x;
  const long TOTAL4=(long)BB*NW*SZ/4;
  if(idx>=TOTAL4) return;
  long row=idx>>6; int k4=(int)(idx&63);
  int r32=(int)row;
  int b=r32/NW, w=r32-b*NW;
  int im=idxmap[r32];
  int lem=u2l[w];
  long qb=((long)b*NLEM+lem)*SZ;
  unsigned int fl=flags[(long)b*NLEM+lem];
  float4 p = (im>=0)? ((const float4*)(Pt+(long)im*SZ))[k4]
                    : ((const float4*)(P1base+(long)w*SZ))[k4];
  float4 cv=((const float4*)(out+(long)row*SZ))[k4];
  float4 bgv=((const float4*)bg)[k4];
  float4 q, nw;
  if(fl){ q=((const float4*)(Q+qb))[k4]; nw=((const float4*)(lembuf+qb))[k4]; }
  else  { q=make_float4(0.f,0.f,0.f,0.f); nw=q; }
  float4 o;
  { float g=sigf(p.x+q.x+bgv.x); o.x=cv.x*g+(1.f-g)*nw.x; }
  { float g=sigf(p.y+q.y+bgv.y); o.y=cv.y*g+(1.f-g)*nw.y; }
  { float g=sigf(p.z+q.z+bgv.z); o.z=cv.z*g+(1.f-g)*nw.z; }
  { float g=sigf(p.w+q.w+bgv.w); o.w=cv.w*g+(1.f-g)*nw.w; }
  ((float4*)out)[idx]=o;
}

// ------- legacy dense iter-1 gate (fallback if ws too small) ----------------
__global__ void k_gate1(const float* __restrict__ ctxt, const float* __restrict__ Wg,
                        const float* __restrict__ Q, const float* __restrict__ lembuf,
                        const int* __restrict__ u2l, const unsigned int* __restrict__ flags,
                        const float* __restrict__ bg, float* __restrict__ out){
  __shared__ __align__(16) float As[64][SZ];
  __shared__ __align__(16) float Ws[64][SZ];
  __shared__ int lem_s[64];
  int r0=blockIdx.x*64, tid=threadIdx.x;
  for(int i=tid;i<64*SZ;i+=256){int lr=i>>8,j=i&(SZ-1);
    As[lr][j]=ctxt[(long)(r0+lr)*SZ+j];}
  if(tid<64){int r=r0+tid; lem_s[tid]=u2l[r%NW];}
  int cl=tid&63, rg=tid>>6;
  float acc[16][4];
  #pragma unroll
  for(int i=0;i<16;i++){acc[i][0]=acc[i][1]=acc[i][2]=acc[i][3]=0.f;}
  for(int kb=0;kb<4;kb++){
    __syncthreads();
    for(int i=tid;i<64*SZ;i+=256){int lr=i>>8,j=i&(SZ-1);
      Ws[lr][j]=Wg[(long)(kb*64+lr)*SZ+j];}
    __syncthreads();
    for(int k=0;k<64;k+=4){
      float4 a4[16];
      #pragma unroll
      for(int i=0;i<16;i++) a4[i]=*(const float4*)&As[rg*16+i][kb*64+k];
      #pragma unroll
      for(int j=0;j<4;j++){
        float w0=Ws[k+j][cl],w1=Ws[k+j][cl+64],w2=Ws[k+j][cl+128],w3=Ws[k+j][cl+192];
        #pragma unroll
        for(int i=0;i<16;i++){
          float a=(j==0)?a4[i].x:(j==1)?a4[i].y:(j==2)?a4[i].z:a4[i].w;
          acc[i][0]=fmaf(a,w0,acc[i][0]);acc[i][1]=fmaf(a,w1,acc[i][1]);
          acc[i][2]=fmaf(a,w2,acc[i][2]);acc[i][3]=fmaf(a,w3,acc[i][3]);
        }
      }
    }
  }
  #pragma unroll
  for(int i=0;i<16;i++){
    int lr=rg*16+i, r=r0+lr, b=r/NW;
    long base=((long)b*NLEM+lem_s[lr])*SZ;
    unsigned int fl=flags[(long)b*NLEM+lem_s[lr]];
    #pragma unroll
    for(int cc=0;cc<4;cc++){
      int col=cl+cc*64;
      float qv=0.f, nw=0.f;
      if(fl){ qv=Q[base+col]; nw=lembuf[base+col]; }
      float g=sigf(acc[i][cc]+qv+bg[col]);
      out[(long)r*SZ+col]=As[lr][col]*g+(1.f-g)*nw;
    }
  }
}

extern "C" void kernel_launch(void* const* d_in, const int* in_sizes, int n_in,
                              void* d_out, int out_size, void* d_ws, size_t ws_size,
                              hipStream_t stream){
  const float* emb  =(const float*)d_in[0];
  const float* Wp   =(const float*)d_in[1];
  const float* bp   =(const float*)d_in[2];
  const float* Wi_f =(const float*)d_in[3];
  const float* Wh_f =(const float*)d_in[4];
  const float* b_f  =(const float*)d_in[5];
  const float* Wi_b =(const float*)d_in[6];
  const float* Wh_b =(const float*)d_in[7];
  const float* b_b  =(const float*)d_in[8];
  const float* Wenc =(const float*)d_in[9];
  const float* benc =(const float*)d_in[10];
  const float* Wg   =(const float*)d_in[11];
  const float* bg   =(const float*)d_in[12];
  const int*   seq0 =(const int*)d_in[13];
  const int*   seq1 =(const int*)d_in[14];
  const int*   len0 =(const int*)d_in[15];
  const int*   len1 =(const int*)d_in[16];
  const int*   u2l  =(const int*)d_in[17];

  float* ws    = (float*)d_ws;
  float* we    = ws;                       // 2,560,000
  float* xwi   = we    + 2560000;          // 4,194,304 (fragment layout)
  float* hglob = xwi   + 4194304;          // 1,048,576
  float* lembuf= hglob + 1048576;          // 12,288,000
  float* flags = lembuf+ 12288000;         // 48,000 (uint)
  float* Q     = flags + 48000;            // 12,288,000
  float* P0    = Q     + 12288000;         // 2,560,000 (becomes P1base)
  short* whb   = (short*)(P0 + 2560000);   // 524,288 shorts = 262,144 floats
  int*   idxmap= (int*)(P0 + 2560000 + 262144);   // 160,000
  int*   list  = idxmap + 160000;          // NCAPMAX
  int*   cnt   = list + NCAPMAX;           // 1 (+3 pad)
  float* Ptouch= (float*)(cnt + 4);        // up to NCAPMAX*256
  long base_floats = (long)(Ptouch - ws);
  long avail = ((long)(ws_size/4) - base_floats)/SZ;
  int ncap = (int)(avail > NCAPMAX ? NCAPMAX : (avail<0?0:avail));
  int sparse_ok = (ncap >= 16384);
  float* out   = (float*)d_out;

  hipFuncSetAttribute((const void*)k_lstm_mfma,
                      hipFuncAttributeMaxDynamicSharedMemorySize, 147968);

  k_we<<<NW/16,256,0,stream>>>(emb,Wp,bp,we);
  k_rowgemm<<<NW/16,256,0,stream>>>(we,Wg,P0,nullptr);            // P0 = we@Wg1
  k_prep<<<256,256,0,stream>>>(Wh_f,Wh_b,whb);

  const int* seqs[2]={seq0,seq1};
  const int* lens[2]={len0,len1};
  for(int i=0;i<2;i++){
    hipMemsetAsync(lembuf,0,(size_t)(12288000+48000)*4,stream);   // lembuf + flags
    const float* src = (i==0)? we : out;
    long bstride     = (i==0)? 0L : (long)NW*SZ;
    dim3 gx(64,4);
    k_xwi<<<gx,256,0,stream>>>(seqs[i],lens[i],src,bstride,Wi_f,b_f,Wi_b,b_b,i,xwi);
    k_lstm_mfma<<<2,256,147968,stream>>>(whb,xwi,hglob);
    k_enc<<<BB*LL/16,256,0,stream>>>(seqs[i],lens[i],u2l,hglob,Wenc,benc,
                                     (unsigned int*)lembuf,(unsigned int*)flags);
    k_rowgemm<<<BB*NLEM/16,256,0,stream>>>(lembuf,Wg+(long)SZ*SZ,Q,
                                           (const unsigned int*)flags); // Q = nw@Wg2
    if(i==0){
      long nb=((long)BB*NW*SZ/4+255)/256;
      k_gate0<<<(int)nb,256,0,stream>>>(we,P0,Q,lembuf,u2l,
                                        (const unsigned int*)flags,bg,out);
      if(sparse_ok){
        // touched-row decomposition for iter-1's ctxt@Wg1
        hipMemsetAsync(cnt,0,4,stream);
        k_compact<<<(BB*NW+255)/256,256,0,stream>>>(u2l,(const unsigned int*)flags,
                                                    cnt,list,idxmap,ncap);
        k_ptouch<<<(ncap+15)/16,256,0,stream>>>(out,Wg,cnt,list,Ptouch);
        k_p1base<<<NW/16,256,0,stream>>>(we,P0,bg,Wg);   // P0 <- C0@Wg1
      }
    }else{
      if(sparse_ok){
        long nb=((long)BB*NW*SZ/4+255)/256;
        k_gate1e<<<(int)nb,256,0,stream>>>(P0,Ptouch,idxmap,Q,lembuf,u2l,
                                           (const unsigned int*)flags,bg,out);
      }else{
        k_gate1<<<BB*NW/64,256,0,stream>>>(out,Wg,Q,lembuf,u2l,
                                           (const unsigned int*)flags,bg,out);
      }
    }
  }
}

// Round 5
// 2274.702 us; speedup vs baseline: 3.4099x; 1.0880x over previous
//
#include <hip/hip_runtime.h>

#define NW    10000
#define INDIM 300
#define SZ    256
#define BB    16
#define LL    128
#define NLEM  3000
#define FH    1024   // 4*SZ
#define NCAPMAX 32768

typedef short  bf16x8 __attribute__((ext_vector_type(8)));
typedef float  f32x4  __attribute__((ext_vector_type(4)));

// fast sigmoid/tanh: v_exp_f32 (=2^x) + v_rcp_f32, no IEEE divide sequences
__device__ __forceinline__ float sigf(float x){
  return __builtin_amdgcn_rcpf(1.f+__builtin_amdgcn_exp2f(-1.442695041f*x));
}
__device__ __forceinline__ float tanhf_(float x){
  return fmaf(-2.f, __builtin_amdgcn_rcpf(1.f+__builtin_amdgcn_exp2f(2.885390082f*x)), 1.f);
}
__device__ __forceinline__ short f2b(float f){
  unsigned u=__float_as_uint(f); u += 0x7FFFu + ((u>>16)&1u); return (short)(u>>16);
}

// ---------------- we = relu(emb @ Wp + bp) : [10000,300]@[300,256] ----------
__global__ void k_we(const float* __restrict__ emb, const float* __restrict__ Wp,
                     const float* __restrict__ bp, float* __restrict__ we){
  __shared__ __align__(16) float As[16][INDIM];
  int r0 = blockIdx.x*16, tid = threadIdx.x;
  for(int i=tid;i<16*INDIM;i+=256){int lr=i/INDIM,d=i-lr*INDIM;
    As[lr][d]=emb[(long)(r0+lr)*INDIM+d];}
  __syncthreads();
  int cl=tid&63, rg=tid>>6;
  float acc[4][4];
  #pragma unroll
  for(int i=0;i<4;i++){acc[i][0]=acc[i][1]=acc[i][2]=acc[i][3]=0.f;}
  for(int k=0;k<INDIM;k+=4){
    float4 a4[4];
    #pragma unroll
    for(int i=0;i<4;i++) a4[i]=*(const float4*)&As[rg*4+i][k];
    #pragma unroll
    for(int j=0;j<4;j++){
      const float* wr=Wp+(long)(k+j)*SZ+cl;
      float w0=wr[0],w1=wr[64],w2=wr[128],w3=wr[192];
      #pragma unroll
      for(int i=0;i<4;i++){
        float a=(j==0)?a4[i].x:(j==1)?a4[i].y:(j==2)?a4[i].z:a4[i].w;
        acc[i][0]=fmaf(a,w0,acc[i][0]);acc[i][1]=fmaf(a,w1,acc[i][1]);
        acc[i][2]=fmaf(a,w2,acc[i][2]);acc[i][3]=fmaf(a,w3,acc[i][3]);
      }
    }
  }
  #pragma unroll
  for(int i=0;i<4;i++){
    int r=r0+rg*4+i;
    #pragma unroll
    for(int cc=0;cc<4;cc++){int col=cl+cc*64;
      we[(long)r*SZ+col]=fmaxf(acc[i][cc]+bp[col],0.f);}
  }
}

// ---- xwi (fragment-layout output): value = x_row @ Wi[:256] + Wi[256+iseq] + b
__global__ void k_xwi(const int* __restrict__ seq, const int* __restrict__ len,
                      const float* __restrict__ src, long bstride,
                      const float* __restrict__ Wi_f, const float* __restrict__ bvf,
                      const float* __restrict__ Wi_b, const float* __restrict__ bvb,
                      int iseq, float* __restrict__ xwi){
  __shared__ __align__(16) float As[64][SZ];
  __shared__ const float* rowp[64];
  int r0=blockIdx.x*64, cb=blockIdx.y, tid=threadIdx.x;
  int dir=r0>>11;
  if(tid<64){
    int grow=r0+tid;
    int t=(grow>>4)&(LL-1), b=grow&(BB-1);
    int lb=len[b];
    int tt=(dir==0)? t : ((t<lb)? (lb-1-t) : t);
    int tok=seq[b*LL+tt];
    rowp[tid]=src + (long)b*bstride + (long)tok*SZ;
  }
  __syncthreads();
  for(int i=tid;i<64*SZ;i+=256){int lr=i>>8,j=i&(SZ-1);As[lr][j]=rowp[lr][j];}
  __syncthreads();
  const float* __restrict__ Wi = dir? Wi_b : Wi_f;
  const float* __restrict__ bv = dir? bvb : bvf;
  int cl=tid&63, rg=tid>>6, c0=cb*256+cl;
  float acc[16][4];
  #pragma unroll
  for(int i=0;i<16;i++){acc[i][0]=acc[i][1]=acc[i][2]=acc[i][3]=0.f;}
  for(int k=0;k<SZ;k+=4){
    float4 a4[16];
    #pragma unroll
    for(int i=0;i<16;i++) a4[i]=*(const float4*)&As[rg*16+i][k];
    #pragma unroll
    for(int j=0;j<4;j++){
      const float* wr=Wi+(long)(k+j)*FH+c0;
      float w0=wr[0],w1=wr[64],w2=wr[128],w3=wr[192];
      #pragma unroll
      for(int i=0;i<16;i++){
        float a=(j==0)?a4[i].x:(j==1)?a4[i].y:(j==2)?a4[i].z:a4[i].w;
        acc[i][0]=fmaf(a,w0,acc[i][0]);acc[i][1]=fmaf(a,w1,acc[i][1]);
        acc[i][2]=fmaf(a,w2,acc[i][2]);acc[i][3]=fmaf(a,w3,acc[i][3]);
      }
    }
  }
  #pragma unroll
  for(int cc=0;cc<4;cc++){
    int cx=c0+cc*64;
    float be=Wi[(long)(SZ+iseq)*FH+cx]+bv[cx];
    int g=cx>>8, rem=cx&255, w2=rem>>6, ug=(rem>>4)&3, nl=rem&15, nt=ug*4+g;
    #pragma unroll
    for(int i=0;i<16;i++){
      int grow=r0+rg*16+i;
      int b=grow&15, t=(grow>>4)&127, d2=grow>>11;
      long idx3=((((long)d2*128+t)*4+w2)*64 + (b>>2)*16+nl)*64 + nt*4 + (b&3);
      xwi[idx3]=acc[i][cc]+be;
    }
  }
}

// ---- prep: Wh -> bf16 MFMA B-fragments, gate-grouped column permutation ----
__global__ void k_prep(const float* __restrict__ Wh_f, const float* __restrict__ Wh_b,
                       short* __restrict__ frag){
  int tid = blockIdx.x*256 + threadIdx.x;   // 65536 total
  int l = tid&63, T=(tid>>6)&127, w=(tid>>13)&3, dir=tid>>15;
  const float* Wh = dir? Wh_b : Wh_f;
  int nt=T>>3, ks=T&7, ug=nt>>2, g=nt&3;
  int col = g*256 + w*64 + ug*16 + (l&15);
  int k0 = ks*32 + 8*(l>>4);
  short v[8];
  #pragma unroll
  for(int j=0;j<8;j++) v[j]=f2b(Wh[(long)(k0+j)*FH + col]);
  *(bf16x8*)(frag + (long)tid*8) = *(bf16x8*)v;
}

// --------- MFMA batched persistent LSTM: 1 block/dir, 256 thr ---------------
#define MF(a,b,c) __builtin_amdgcn_mfma_f32_16x16x32_bf16(a,b,c,0,0,0)
#define LDF(T)    (*(const bf16x8*)(fr + (long)(T)*512 + l*8))
#define LDL(nt,ks) (*(const bf16x8*)(bl + ((nt)-9)*4096 + (ks)*512 + l*8))
#define DECLR(nt) bf16x8 R##nt##_0=LDF(nt*8+0),R##nt##_1=LDF(nt*8+1),R##nt##_2=LDF(nt*8+2),R##nt##_3=LDF(nt*8+3),R##nt##_4=LDF(nt*8+4),R##nt##_5=LDF(nt*8+5),R##nt##_6=LDF(nt*8+6),R##nt##_7=LDF(nt*8+7);
#define DECLC(nt) f32x4 C##nt={0.f,0.f,0.f,0.f};
#define MMR(nt) { C##nt=MF(A0,R##nt##_0,C##nt); C##nt=MF(A1,R##nt##_1,C##nt); C##nt=MF(A2,R##nt##_2,C##nt); C##nt=MF(A3,R##nt##_3,C##nt); C##nt=MF(A4,R##nt##_4,C##nt); C##nt=MF(A5,R##nt##_5,C##nt); C##nt=MF(A6,R##nt##_6,C##nt); C##nt=MF(A7,R##nt##_7,C##nt); }
#define MML(nt) { C##nt=MF(A0,LDL(nt,0),C##nt); C##nt=MF(A1,LDL(nt,1),C##nt); C##nt=MF(A2,LDL(nt,2),C##nt); C##nt=MF(A3,LDL(nt,3),C##nt); C##nt=MF(A4,LDL(nt,4),C##nt); C##nt=MF(A5,LDL(nt,5),C##nt); C##nt=MF(A6,LDL(nt,6),C##nt); C##nt=MF(A7,LDL(nt,7),C##nt); }
#define LOADSB(buf,T0) buf##0=LDF((T0)+0); buf##1=LDF((T0)+1); buf##2=LDF((T0)+2); buf##3=LDF((T0)+3); buf##4=LDF((T0)+4); buf##5=LDF((T0)+5); buf##6=LDF((T0)+6); buf##7=LDF((T0)+7);
#define MMSB(nt,buf) { C##nt=MF(A0,buf##0,C##nt); C##nt=MF(A1,buf##1,C##nt); C##nt=MF(A2,buf##2,C##nt); C##nt=MF(A3,buf##3,C##nt); C##nt=MF(A4,buf##4,C##nt); C##nt=MF(A5,buf##5,C##nt); C##nt=MF(A6,buf##6,C##nt); C##nt=MF(A7,buf##7,C##nt); }
#define XLD(ug,g) (*(const f32x4*)(xp + ((ug)*4+(g))*4))
#define GATE1(ug,r,CA,CB,CC,CD,X0,X1,X2,X3) { \
  float zi=CA[r]+X0[r], zf=CB[r]+X1[r], zg=CC[r]+X2[r], zo=CD[r]+X3[r]; \
  cst_##ug##_##r = sigf(zf)*cst_##ug##_##r + sigf(zi)*tanhf_(zg); \
  float hv = sigf(zo)*tanhf_(cst_##ug##_##r); \
  int b_=4*(l>>4)+(r); int u_=w*64+(ug)*16+(l&15); \
  hbn[b_*264+u_]=f2b(hv); \
  hg[((long)t*16+b_)*256+u_]=hv; }
#define GATES(ug,CA,CB,CC,CD,X0,X1,X2,X3) \
  GATE1(ug,0,CA,CB,CC,CD,X0,X1,X2,X3) GATE1(ug,1,CA,CB,CC,CD,X0,X1,X2,X3) \
  GATE1(ug,2,CA,CB,CC,CD,X0,X1,X2,X3) GATE1(ug,3,CA,CB,CC,CD,X0,X1,X2,X3)

extern __shared__ char smem_raw[];

__global__ __launch_bounds__(256,1) void k_lstm_mfma(
    const short* __restrict__ frag, const float* __restrict__ xwi3,
    float* __restrict__ hglob){
  const int dir = blockIdx.x;
  const int tid = threadIdx.x;
  const int w = tid>>6, l = tid&63;
  short* hb = (short*)smem_raw;                        // 2 x 16 x 264 shorts
  short* bl = (short*)(smem_raw + 16896) + w*16384;    // per-wave LDS B tiles
  const short* fr = frag + (long)(dir*4+w)*128*512;

  for(int i=tid;i<4224;i+=256) ((int*)smem_raw)[i]=0;  // zero both h buffers

  #pragma unroll 4
  for(int c2=0;c2<32;c2++)
    *(f32x4*)(bl + c2*512 + l*8) = *(const f32x4*)(fr + 72*512 + c2*512 + l*8);

  DECLR(0) DECLR(1) DECLR(2) DECLR(3) DECLR(4) DECLR(5) DECLR(6) DECLR(7) DECLR(8)

  float cst_0_0=0,cst_0_1=0,cst_0_2=0,cst_0_3=0, cst_1_0=0,cst_1_1=0,cst_1_2=0,cst_1_3=0,
        cst_2_0=0,cst_2_1=0,cst_2_2=0,cst_2_3=0, cst_3_0=0,cst_3_1=0,cst_3_2=0,cst_3_3=0;
  bf16x8 S0_0,S0_1,S0_2,S0_3,S0_4,S0_5,S0_6,S0_7;
  bf16x8 S1_0,S1_1,S1_2,S1_3,S1_4,S1_5,S1_6,S1_7;
  __syncthreads();

  const float* xwb = xwi3 + (long)dir*2097152 + (long)(w*64+l)*64;
  float* hg = hglob + (long)dir*524288;

  for(int t=0;t<LL;t++){
    const int cur=t&1, nxt=cur^1;
    const float* xp = xwb + (long)t*16384;
    // ---- early issue: streamed B tiles 13,14 + first half of x ----
    LOADSB(S0_,13*8) LOADSB(S1_,14*8)
    f32x4 xa0=XLD(0,0), xa1=XLD(0,1), xa2=XLD(0,2), xa3=XLD(0,3);
    f32x4 xb0=XLD(1,0), xb1=XLD(1,1), xb2=XLD(1,2), xb3=XLD(1,3);
    const short* hr = hb + cur*4224 + (l&15)*264 + (l>>4)*8;
    bf16x8 A0=*(const bf16x8*)(hr+0),   A1=*(const bf16x8*)(hr+32),
           A2=*(const bf16x8*)(hr+64),  A3=*(const bf16x8*)(hr+96),
           A4=*(const bf16x8*)(hr+128), A5=*(const bf16x8*)(hr+160),
           A6=*(const bf16x8*)(hr+192), A7=*(const bf16x8*)(hr+224);
    DECLC(0) DECLC(1) DECLC(2) DECLC(3) DECLC(4) DECLC(5) DECLC(6) DECLC(7)
    DECLC(8) DECLC(9) DECLC(10) DECLC(11) DECLC(12) DECLC(13) DECLC(14) DECLC(15)
    MMR(0) MMR(1) MMR(2) MMR(3) MMR(4) MMR(5) MMR(6) MMR(7) MMR(8)
    short* hbn = hb + nxt*4224;
    GATES(0, C0,C1,C2,C3,     xa0,xa1,xa2,xa3)
    f32x4 xc0=XLD(2,0), xc1=XLD(2,1), xc2=XLD(2,2), xc3=XLD(2,3);
    GATES(1, C4,C5,C6,C7,     xb0,xb1,xb2,xb3)
    MML(9) MML(10) MML(11) MML(12)
    f32x4 xd0=XLD(3,0), xd1=XLD(3,1), xd2=XLD(3,2), xd3=XLD(3,3);
    GATES(2, C8,C9,C10,C11,   xc0,xc1,xc2,xc3)
    MMSB(13,S0_)
    LOADSB(S0_,15*8)                 // refill buffer 0 with tile 15
    MMSB(14,S1_)
    MMSB(15,S0_)
    GATES(3, C12,C13,C14,C15, xd0,xd1,xd2,xd3)
    __syncthreads();
  }
}

// ---- enc = [hf|hb] @ Wenc + benc, relu(max) scatter into lembuf + flags ----
__global__ void k_enc(const int* __restrict__ seq, const int* __restrict__ len,
                      const int* __restrict__ u2l, const float* __restrict__ hglob,
                      const float* __restrict__ Wenc, const float* __restrict__ benc,
                      unsigned int* __restrict__ lembuf, unsigned int* __restrict__ flags){
  __shared__ __align__(16) float As[16][2*SZ];
  __shared__ const float* pf16[16]; __shared__ const float* pb16[16];
  __shared__ int lem_s[16], val_s[16], b_s[16];
  int r0=blockIdx.x*16, tid=threadIdx.x;
  if(tid<16){
    int r=r0+tid, b=r>>7, t=r&127, lb=len[b];
    int v=(t<lb); val_s[tid]=v; b_s[tid]=b;
    int lem=u2l[seq[r]];
    lem_s[tid]=lem;
    pf16[tid]=hglob+((long)t*BB+b)*SZ;
    int tr=v? (lb-1-t) : t;
    pb16[tid]=hglob+((long)(LL+tr)*BB+b)*SZ;
    if(v) flags[(long)b*NLEM+lem]=1u;
  }
  __syncthreads();
  for(int i=tid;i<16*SZ;i+=256){int lr=i>>8,j=i&(SZ-1);
    As[lr][j]=pf16[lr][j]; As[lr][SZ+j]=pb16[lr][j];}
  __syncthreads();
  int cl=tid&63, rg=tid>>6;
  float acc[4][4];
  #pragma unroll
  for(int i=0;i<4;i++){acc[i][0]=acc[i][1]=acc[i][2]=acc[i][3]=0.f;}
  for(int k=0;k<2*SZ;k+=4){
    float4 a4[4];
    #pragma unroll
    for(int i=0;i<4;i++) a4[i]=*(const float4*)&As[rg*4+i][k];
    #pragma unroll
    for(int j=0;j<4;j++){
      const float* wr=Wenc+(long)(k+j)*SZ+cl;
      float w0=wr[0],w1=wr[64],w2=wr[128],w3=wr[192];
      #pragma unroll
      for(int i=0;i<4;i++){
        float a=(j==0)?a4[i].x:(j==1)?a4[i].y:(j==2)?a4[i].z:a4[i].w;
        acc[i][0]=fmaf(a,w0,acc[i][0]);acc[i][1]=fmaf(a,w1,acc[i][1]);
        acc[i][2]=fmaf(a,w2,acc[i][2]);acc[i][3]=fmaf(a,w3,acc[i][3]);
      }
    }
  }
  #pragma unroll
  for(int i=0;i<4;i++){
    int lr=rg*4+i;
    if(val_s[lr]){
      long base=((long)b_s[lr]*NLEM+lem_s[lr])*SZ;
      #pragma unroll
      for(int cc=0;cc<4;cc++){
        int col=cl+cc*64;
        float e=fmaxf(acc[i][cc]+benc[col],0.f);
        atomicMax(&lembuf[base+col], __float_as_uint(e));
      }
    }
  }
}

// ------------ generic C[r] = A[r] @ W  (K=256), optional touched-flags ------
__global__ void k_rowgemm(const float* __restrict__ A, const float* __restrict__ W,
                          float* __restrict__ C, const unsigned int* __restrict__ flags){
  __shared__ __align__(16) float As[16][SZ];
  __shared__ int any_s;
  int r0=blockIdx.x*16, tid=threadIdx.x;
  if(tid==0){
    int a = flags? 0 : 1;
    if(flags){ for(int i=0;i<16;i++) a |= (int)flags[r0+i]; }
    any_s=a;
  }
  __syncthreads();
  if(!any_s) return;
  for(int i=tid;i<16*SZ;i+=256){int lr=i>>8,j=i&(SZ-1);As[lr][j]=A[(long)(r0+lr)*SZ+j];}
  __syncthreads();
  int cl=tid&63, rg=tid>>6;
  float acc[4][4];
  #pragma unroll
  for(int i=0;i<4;i++){acc[i][0]=acc[i][1]=acc[i][2]=acc[i][3]=0.f;}
  for(int k=0;k<SZ;k+=4){
    float4 a4[4];
    #pragma unroll
    for(int i=0;i<4;i++) a4[i]=*(const float4*)&As[rg*4+i][k];
    #pragma unroll
    for(int j=0;j<4;j++){
      const float* wr=W+(long)(k+j)*SZ+cl;
      float w0=wr[0],w1=wr[64],w2=wr[128],w3=wr[192];
      #pragma unroll
      for(int i=0;i<4;i++){
        float a=(j==0)?a4[i].x:(j==1)?a4[i].y:(j==2)?a4[i].z:a4[i].w;
        acc[i][0]=fmaf(a,w0,acc[i][0]);acc[i][1]=fmaf(a,w1,acc[i][1]);
        acc[i][2]=fmaf(a,w2,acc[i][2]);acc[i][3]=fmaf(a,w3,acc[i][3]);
      }
    }
  }
  #pragma unroll
  for(int i=0;i<4;i++){
    int r=r0+rg*4+i;
    #pragma unroll
    for(int cc=0;cc<4;cc++) C[(long)r*SZ+cl+cc*64]=acc[i][cc];
  }
}

// ---- P1base: A=we*sig(P0+bg) staged on the fly; result overwrites P0 -------
__global__ void k_p1base(const float* __restrict__ we, float* __restrict__ P0,
                         const float* __restrict__ bg, const float* __restrict__ W){
  __shared__ __align__(16) float As[16][SZ];
  int r0=blockIdx.x*16, tid=threadIdx.x;
  for(int i=tid;i<16*SZ;i+=256){int lr=i>>8,j=i&(SZ-1);
    long off=(long)(r0+lr)*SZ+j;
    As[lr][j]=we[off]*sigf(P0[off]+bg[j]);}
  __syncthreads();
  int cl=tid&63, rg=tid>>6;
  float acc[4][4];
  #pragma unroll
  for(int i=0;i<4;i++){acc[i][0]=acc[i][1]=acc[i][2]=acc[i][3]=0.f;}
  for(int k=0;k<SZ;k+=4){
    float4 a4[4];
    #pragma unroll
    for(int i=0;i<4;i++) a4[i]=*(const float4*)&As[rg*4+i][k];
    #pragma unroll
    for(int j=0;j<4;j++){
      const float* wr=W+(long)(k+j)*SZ+cl;
      float w0=wr[0],w1=wr[64],w2=wr[128],w3=wr[192];
      #pragma unroll
      for(int i=0;i<4;i++){
        float a=(j==0)?a4[i].x:(j==1)?a4[i].y:(j==2)?a4[i].z:a4[i].w;
        acc[i][0]=fmaf(a,w0,acc[i][0]);acc[i][1]=fmaf(a,w1,acc[i][1]);
        acc[i][2]=fmaf(a,w2,acc[i][2]);acc[i][3]=fmaf(a,w3,acc[i][3]);
      }
    }
  }
  #pragma unroll
  for(int i=0;i<4;i++){
    int r=r0+rg*4+i;
    #pragma unroll
    for(int cc=0;cc<4;cc++) P0[(long)r*SZ+cl+cc*64]=acc[i][cc];
  }
}

// ---- compact list of rows whose lemma was touched in iter 0 ----------------
__global__ void k_compact(const int* __restrict__ u2l, const unsigned int* __restrict__ flags,
                          int* __restrict__ cnt, int* __restrict__ list,
                          int* __restrict__ idxmap, int ncap){
  int r = blockIdx.x*256+threadIdx.x;
  if(r>=BB*NW) return;
  int b=r/NW, w=r-b*NW;
  int im=-1;
  if(flags[(long)b*NLEM+u2l[w]]){
    int idx=atomicAdd(cnt,1);
    if(idx<ncap){ list[idx]=r; im=idx; }
  }
  idxmap[r]=im;
}

// ---- Ptouch[i] = out[list[i]] @ Wg1 over the compacted rows ----------------
__global__ void k_ptouch(const float* __restrict__ out, const float* __restrict__ W,
                         const int* __restrict__ cnt, const int* __restrict__ list,
                         float* __restrict__ Pt){
  __shared__ __align__(16) float As[16][SZ];
  __shared__ const float* rp[16];
  int n=*cnt;
  int r0=blockIdx.x*16, tid=threadIdx.x;
  if(r0>=n) return;
  if(tid<16){
    int idx=r0+tid;
    rp[tid]=(idx<n)? out+(long)list[idx]*SZ : nullptr;
  }
  __syncthreads();
  for(int i=tid;i<16*SZ;i+=256){int lr=i>>8,j=i&(SZ-1);
    As[lr][j]= rp[lr]? rp[lr][j] : 0.f;}
  __syncthreads();
  int cl=tid&63, rg=tid>>6;
  float acc[4][4];
  #pragma unroll
  for(int i=0;i<4;i++){acc[i][0]=acc[i][1]=acc[i][2]=acc[i][3]=0.f;}
  for(int k=0;k<SZ;k+=4){
    float4 a4[4];
    #pragma unroll
    for(int i=0;i<4;i++) a4[i]=*(const float4*)&As[rg*4+i][k];
    #pragma unroll
    for(int j=0;j<4;j++){
      const float* wr=W+(long)(k+j)*SZ+cl;
      float w0=wr[0],w1=wr[64],w2=wr[128],w3=wr[192];
      #pragma unroll
      for(int i=0;i<4;i++){
        float a=(j==0)?a4[i].x:(j==1)?a4[i].y:(j==2)?a4[i].z:a4[i].w;
        acc[i][0]=fmaf(a,w0,acc[i][0]);acc[i][1]=fmaf(a,w1,acc[i][1]);
        acc[i][2]=fmaf(a,w2,acc[i][2]);acc[i][3]=fmaf(a,w3,acc[i][3]);
      }
    }
  }
  #pragma unroll
  for(int i=0;i<4;i++){
    int idx=r0+rg*4+i;
    if(idx<n){
      #pragma unroll
      for(int cc=0;cc<4;cc++) Pt[(long)idx*SZ+cl+cc*64]=acc[i][cc];
    }
  }
}

// ------- iter-0 gate: ctxt==tile(we) -> pure elementwise from P0/Q ----------
__global__ void k_gate0(const float* __restrict__ we, const float* __restrict__ P0,
                        const float* __restrict__ Q, const float* __restrict__ lembuf,
                        const int* __restrict__ u2l, const unsigned int* __restrict__ flags,
                        const float* __restrict__ bg, float* __restrict__ out){
  long idx=(long)blockIdx.x*256+threadIdx.x;
  const long TOTAL4=(long)BB*NW*SZ/4;
  if(idx>=TOTAL4) return;
  long row=idx>>6; int k4=(int)(idx&63);
  int r32=(int)row;
  int b=r32/NW, w=r32-b*NW;
  int lem=u2l[w];
  long qb=((long)b*NLEM+lem)*SZ;
  unsigned int fl=flags[(long)b*NLEM+lem];
  float4 p =((const float4*)(P0+(long)w*SZ))[k4];
  float4 wv=((const float4*)(we+(long)w*SZ))[k4];
  float4 bgv=((const float4*)bg)[k4];
  float4 q, nw;
  if(fl){ q=((const float4*)(Q+qb))[k4]; nw=((const float4*)(lembuf+qb))[k4]; }
  else  { q=make_float4(0.f,0.f,0.f,0.f); nw=q; }
  float4 o;
  { float g=sigf(p.x+q.x+bgv.x); o.x=wv.x*g+(1.f-g)*nw.x; }
  { float g=sigf(p.y+q.y+bgv.y); o.y=wv.y*g+(1.f-g)*nw.y; }
  { float g=sigf(p.z+q.z+bgv.z); o.z=wv.z*g+(1.f-g)*nw.z; }
  { float g=sigf(p.w+q.w+bgv.w); o.w=wv.w*g+(1.f-g)*nw.w; }
  ((float4*)out)[idx]=o;
}

// ------- iter-1 gate, elementwise: P from Ptouch (touched0) or P1base -------
__global__ void k_gate1e(const float* __restrict__ P1base, const float* __restrict__ Pt,
                         const int* __restrict__ idxmap,
                         const float* __restrict__ Q, const float* __restrict__ lembuf,
                         const int* __restrict__ u2l, const unsigned int* __restrict__ flags,
                         const float* __restrict__ bg, float* __restrict__ out){
  long idx=(long)blockIdx.x*256+threadIdx.x;
  const long TOTAL4=(long)BB*NW*SZ/4;
  if(idx>=TOTAL4) return;
  long row=idx>>6; int k4=(int)(idx&63);
  int r32=(int)row;
  int b=r32/NW, w=r32-b*NW;
  int im=idxmap[r32];
  int lem=u2l[w];
  long qb=((long)b*NLEM+lem)*SZ;
  unsigned int fl=flags[(long)b*NLEM+lem];
  float4 p = (im>=0)? ((const float4*)(Pt+(long)im*SZ))[k4]
                    : ((const float4*)(P1base+(long)w*SZ))[k4];
  float4 cv=((const float4*)(out+(long)row*SZ))[k4];
  float4 bgv=((const float4*)bg)[k4];
  float4 q, nw;
  if(fl){ q=((const float4*)(Q+qb))[k4]; nw=((const float4*)(lembuf+qb))[k4]; }
  else  { q=make_float4(0.f,0.f,0.f,0.f); nw=q; }
  float4 o;
  { float g=sigf(p.x+q.x+bgv.x); o.x=cv.x*g+(1.f-g)*nw.x; }
  { float g=sigf(p.y+q.y+bgv.y); o.y=cv.y*g+(1.f-g)*nw.y; }
  { float g=sigf(p.z+q.z+bgv.z); o.z=cv.z*g+(1.f-g)*nw.z; }
  { float g=sigf(p.w+q.w+bgv.w); o.w=cv.w*g+(1.f-g)*nw.w; }
  ((float4*)out)[idx]=o;
}

// ------- legacy dense iter-1 gate (fallback if ws too small) ----------------
__global__ void k_gate1(const float* __restrict__ ctxt, const float* __restrict__ Wg,
                        const float* __restrict__ Q, const float* __restrict__ lembuf,
                        const int* __restrict__ u2l, const unsigned int* __restrict__ flags,
                        const float* __restrict__ bg, float* __restrict__ out){
  __shared__ __align__(16) float As[64][SZ];
  __shared__ __align__(16) float Ws[64][SZ];
  __shared__ int lem_s[64];
  int r0=blockIdx.x*64, tid=threadIdx.x;
  for(int i=tid;i<64*SZ;i+=256){int lr=i>>8,j=i&(SZ-1);
    As[lr][j]=ctxt[(long)(r0+lr)*SZ+j];}
  if(tid<64){int r=r0+tid; lem_s[tid]=u2l[r%NW];}
  int cl=tid&63, rg=tid>>6;
  float acc[16][4];
  #pragma unroll
  for(int i=0;i<16;i++){acc[i][0]=acc[i][1]=acc[i][2]=acc[i][3]=0.f;}
  for(int kb=0;kb<4;kb++){
    __syncthreads();
    for(int i=tid;i<64*SZ;i+=256){int lr=i>>8,j=i&(SZ-1);
      Ws[lr][j]=Wg[(long)(kb*64+lr)*SZ+j];}
    __syncthreads();
    for(int k=0;k<64;k+=4){
      float4 a4[16];
      #pragma unroll
      for(int i=0;i<16;i++) a4[i]=*(const float4*)&As[rg*16+i][kb*64+k];
      #pragma unroll
      for(int j=0;j<4;j++){
        float w0=Ws[k+j][cl],w1=Ws[k+j][cl+64],w2=Ws[k+j][cl+128],w3=Ws[k+j][cl+192];
        #pragma unroll
        for(int i=0;i<16;i++){
          float a=(j==0)?a4[i].x:(j==1)?a4[i].y:(j==2)?a4[i].z:a4[i].w;
          acc[i][0]=fmaf(a,w0,acc[i][0]);acc[i][1]=fmaf(a,w1,acc[i][1]);
          acc[i][2]=fmaf(a,w2,acc[i][2]);acc[i][3]=fmaf(a,w3,acc[i][3]);
        }
      }
    }
  }
  #pragma unroll
  for(int i=0;i<16;i++){
    int lr=rg*16+i, r=r0+lr, b=r/NW;
    long base=((long)b*NLEM+lem_s[lr])*SZ;
    unsigned int fl=flags[(long)b*NLEM+lem_s[lr]];
    #pragma unroll
    for(int cc=0;cc<4;cc++){
      int col=cl+cc*64;
      float qv=0.f, nw=0.f;
      if(fl){ qv=Q[base+col]; nw=lembuf[base+col]; }
      float g=sigf(acc[i][cc]+qv+bg[col]);
      out[(long)r*SZ+col]=As[lr][col]*g+(1.f-g)*nw;
    }
  }
}

extern "C" void kernel_launch(void* const* d_in, const int* in_sizes, int n_in,
                              void* d_out, int out_size, void* d_ws, size_t ws_size,
                              hipStream_t stream){
  const float* emb  =(const float*)d_in[0];
  const float* Wp   =(const float*)d_in[1];
  const float* bp   =(const float*)d_in[2];
  const float* Wi_f =(const float*)d_in[3];
  const float* Wh_f =(const float*)d_in[4];
  const float* b_f  =(const float*)d_in[5];
  const float* Wi_b =(const float*)d_in[6];
  const float* Wh_b =(const float*)d_in[7];
  const float* b_b  =(const float*)d_in[8];
  const float* Wenc =(const float*)d_in[9];
  const float* benc =(const float*)d_in[10];
  const float* Wg   =(const float*)d_in[11];
  const float* bg   =(const float*)d_in[12];
  const int*   seq0 =(const int*)d_in[13];
  const int*   seq1 =(const int*)d_in[14];
  const int*   len0 =(const int*)d_in[15];
  const int*   len1 =(const int*)d_in[16];
  const int*   u2l  =(const int*)d_in[17];

  float* ws    = (float*)d_ws;
  float* we    = ws;                       // 2,560,000
  float* xwi   = we    + 2560000;          // 4,194,304 (fragment layout)
  float* hglob = xwi   + 4194304;          // 1,048,576
  float* lembuf= hglob + 1048576;          // 12,288,000
  float* flags = lembuf+ 12288000;         // 48,000 (uint)
  float* Q     = flags + 48000;            // 12,288,000
  float* P0    = Q     + 12288000;         // 2,560,000 (becomes P1base)
  short* whb   = (short*)(P0 + 2560000);   // 524,288 shorts = 262,144 floats
  int*   idxmap= (int*)(P0 + 2560000 + 262144);   // 160,000
  int*   list  = idxmap + 160000;          // NCAPMAX
  int*   cnt   = list + NCAPMAX;           // 1 (+3 pad)
  float* Ptouch= (float*)(cnt + 4);        // up to NCAPMAX*256
  long base_floats = (long)(Ptouch - ws);
  long avail = ((long)(ws_size/4) - base_floats)/SZ;
  int ncap = (int)(avail > NCAPMAX ? NCAPMAX : (avail<0?0:avail));
  int sparse_ok = (ncap >= 16384);
  float* out   = (float*)d_out;

  hipFuncSetAttribute((const void*)k_lstm_mfma,
                      hipFuncAttributeMaxDynamicSharedMemorySize, 147968);

  k_we<<<NW/16,256,0,stream>>>(emb,Wp,bp,we);
  k_rowgemm<<<NW/16,256,0,stream>>>(we,Wg,P0,nullptr);            // P0 = we@Wg1
  k_prep<<<256,256,0,stream>>>(Wh_f,Wh_b,whb);

  const int* seqs[2]={seq0,seq1};
  const int* lens[2]={len0,len1};
  for(int i=0;i<2;i++){
    hipMemsetAsync(lembuf,0,(size_t)(12288000+48000)*4,stream);   // lembuf + flags
    const float* src = (i==0)? we : out;
    long bstride     = (i==0)? 0L : (long)NW*SZ;
    dim3 gx(64,4);
    k_xwi<<<gx,256,0,stream>>>(seqs[i],lens[i],src,bstride,Wi_f,b_f,Wi_b,b_b,i,xwi);
    k_lstm_mfma<<<2,256,147968,stream>>>(whb,xwi,hglob);
    k_enc<<<BB*LL/16,256,0,stream>>>(seqs[i],lens[i],u2l,hglob,Wenc,benc,
                                     (unsigned int*)lembuf,(unsigned int*)flags);
    k_rowgemm<<<BB*NLEM/16,256,0,stream>>>(lembuf,Wg+(long)SZ*SZ,Q,
                                           (const unsigned int*)flags); // Q = nw@Wg2
    if(i==0){
      long nb=((long)BB*NW*SZ/4+255)/256;
      k_gate0<<<(int)nb,256,0,stream>>>(we,P0,Q,lembuf,u2l,
                                        (const unsigned int*)flags,bg,out);
      if(sparse_ok){
        hipMemsetAsync(cnt,0,4,stream);
        k_compact<<<(BB*NW+255)/256,256,0,stream>>>(u2l,(const unsigned int*)flags,
                                                    cnt,list,idxmap,ncap);
        k_ptouch<<<(ncap+15)/16,256,0,stream>>>(out,Wg,cnt,list,Ptouch);
        k_p1base<<<NW/16,256,0,stream>>>(we,P0,bg,Wg);   // P0 <- C0@Wg1
      }
    }else{
      if(sparse_ok){
        long nb=((long)BB*NW*SZ/4+255)/256;
        k_gate1e<<<(int)nb,256,0,stream>>>(P0,Ptouch,idxmap,Q,lembuf,u2l,
                                           (const unsigned int*)flags,bg,out);
      }else{
        k_gate1<<<BB*NW/64,256,0,stream>>>(out,Wg,Q,lembuf,u2l,
                                           (const unsigned int*)flags,bg,out);
      }
    }
  }
}

// Round 6
// 2060.064 us; speedup vs baseline: 3.7651x; 1.1042x over previous
//
#include <hip/hip_runtime.h>

#define NW    10000
#define INDIM 300
#define SZ    256
#define BB    16
#define LL    128
#define NLEM  3000
#define FH    1024   // 4*SZ
#define NCAPMAX 32768

typedef short  bf16x8 __attribute__((ext_vector_type(8)));
typedef float  f32x4  __attribute__((ext_vector_type(4)));

// fast sigmoid/tanh: v_exp_f32 (=2^x) + v_rcp_f32, no IEEE divide sequences
__device__ __forceinline__ float sigf(float x){
  return __builtin_amdgcn_rcpf(1.f+__builtin_amdgcn_exp2f(-1.442695041f*x));
}
__device__ __forceinline__ float tanhf_(float x){
  return fmaf(-2.f, __builtin_amdgcn_rcpf(1.f+__builtin_amdgcn_exp2f(2.885390082f*x)), 1.f);
}
__device__ __forceinline__ short f2b(float f){
  unsigned u=__float_as_uint(f); u += 0x7FFFu + ((u>>16)&1u); return (short)(u>>16);
}
#define B2F(s) __uint_as_float(((unsigned)(unsigned short)(s))<<16)

// ---------------- we = relu(emb @ Wp + bp) : [10000,300]@[300,256] ----------
__global__ void k_we(const float* __restrict__ emb, const float* __restrict__ Wp,
                     const float* __restrict__ bp, float* __restrict__ we){
  __shared__ __align__(16) float As[16][INDIM];
  int r0 = blockIdx.x*16, tid = threadIdx.x;
  for(int i=tid;i<16*INDIM;i+=256){int lr=i/INDIM,d=i-lr*INDIM;
    As[lr][d]=emb[(long)(r0+lr)*INDIM+d];}
  __syncthreads();
  int cl=tid&63, rg=tid>>6;
  float acc[4][4];
  #pragma unroll
  for(int i=0;i<4;i++){acc[i][0]=acc[i][1]=acc[i][2]=acc[i][3]=0.f;}
  for(int k=0;k<INDIM;k+=4){
    float4 a4[4];
    #pragma unroll
    for(int i=0;i<4;i++) a4[i]=*(const float4*)&As[rg*4+i][k];
    #pragma unroll
    for(int j=0;j<4;j++){
      const float* wr=Wp+(long)(k+j)*SZ+cl;
      float w0=wr[0],w1=wr[64],w2=wr[128],w3=wr[192];
      #pragma unroll
      for(int i=0;i<4;i++){
        float a=(j==0)?a4[i].x:(j==1)?a4[i].y:(j==2)?a4[i].z:a4[i].w;
        acc[i][0]=fmaf(a,w0,acc[i][0]);acc[i][1]=fmaf(a,w1,acc[i][1]);
        acc[i][2]=fmaf(a,w2,acc[i][2]);acc[i][3]=fmaf(a,w3,acc[i][3]);
      }
    }
  }
  #pragma unroll
  for(int i=0;i<4;i++){
    int r=r0+rg*4+i;
    #pragma unroll
    for(int cc=0;cc<4;cc++){int col=cl+cc*64;
      we[(long)r*SZ+col]=fmaxf(acc[i][cc]+bp[col],0.f);}
  }
}

// ---- xwi (bf16, lane-contiguous layout):
// short idx = (((dir*128+t)*4+w)*4096) + j*512 + lane*8 + elem
//   col=g*256+w*64+ug*16+nl -> j=ug*2+(g>>1), lane=(b>>2)*16+nl, elem=(g&1)*4+(b&3)
__global__ void k_xwi(const int* __restrict__ seq, const int* __restrict__ len,
                      const float* __restrict__ src, long bstride,
                      const float* __restrict__ Wi_f, const float* __restrict__ bvf,
                      const float* __restrict__ Wi_b, const float* __restrict__ bvb,
                      int iseq, short* __restrict__ xwo){
  __shared__ __align__(16) float As[64][SZ];
  __shared__ const float* rowp[64];
  int r0=blockIdx.x*64, cb=blockIdx.y, tid=threadIdx.x;
  int dir=r0>>11;
  if(tid<64){
    int grow=r0+tid;
    int t=(grow>>4)&(LL-1), b=grow&(BB-1);
    int lb=len[b];
    int tt=(dir==0)? t : ((t<lb)? (lb-1-t) : t);
    int tok=seq[b*LL+tt];
    rowp[tid]=src + (long)b*bstride + (long)tok*SZ;
  }
  __syncthreads();
  for(int i=tid;i<64*SZ;i+=256){int lr=i>>8,j=i&(SZ-1);As[lr][j]=rowp[lr][j];}
  __syncthreads();
  const float* __restrict__ Wi = dir? Wi_b : Wi_f;
  const float* __restrict__ bv = dir? bvb : bvf;
  int cl=tid&63, rg=tid>>6, c0=cb*256+cl;
  float acc[16][4];
  #pragma unroll
  for(int i=0;i<16;i++){acc[i][0]=acc[i][1]=acc[i][2]=acc[i][3]=0.f;}
  for(int k=0;k<SZ;k+=4){
    float4 a4[16];
    #pragma unroll
    for(int i=0;i<16;i++) a4[i]=*(const float4*)&As[rg*16+i][k];
    #pragma unroll
    for(int j=0;j<4;j++){
      const float* wr=Wi+(long)(k+j)*FH+c0;
      float w0=wr[0],w1=wr[64],w2=wr[128],w3=wr[192];
      #pragma unroll
      for(int i=0;i<16;i++){
        float a=(j==0)?a4[i].x:(j==1)?a4[i].y:(j==2)?a4[i].z:a4[i].w;
        acc[i][0]=fmaf(a,w0,acc[i][0]);acc[i][1]=fmaf(a,w1,acc[i][1]);
        acc[i][2]=fmaf(a,w2,acc[i][2]);acc[i][3]=fmaf(a,w3,acc[i][3]);
      }
    }
  }
  #pragma unroll
  for(int cc=0;cc<4;cc++){
    int cx=c0+cc*64;
    float be=Wi[(long)(SZ+iseq)*FH+cx]+bv[cx];
    int g=cx>>8, rem=cx&255, w2=rem>>6, ug=(rem>>4)&3, nl=rem&15;
    int j2=ug*2+(g>>1);
    #pragma unroll
    for(int i=0;i<16;i++){
      int grow=r0+rg*16+i;
      int b=grow&15, t=(grow>>4)&127, d2=grow>>11;
      long sidx=((((long)d2*128+t)*4+w2)*4096) + j2*512 + ((b>>2)*16+nl)*8 + (g&1)*4 + (b&3);
      xwo[sidx]=f2b(acc[i][cc]+be);
    }
  }
}

// ---- prep: Wh -> bf16 MFMA B-fragments, gate-grouped column permutation ----
__global__ void k_prep(const float* __restrict__ Wh_f, const float* __restrict__ Wh_b,
                       short* __restrict__ frag){
  int tid = blockIdx.x*256 + threadIdx.x;   // 65536 total
  int l = tid&63, T=(tid>>6)&127, w=(tid>>13)&3, dir=tid>>15;
  const float* Wh = dir? Wh_b : Wh_f;
  int nt=T>>3, ks=T&7, ug=nt>>2, g=nt&3;
  int col = g*256 + w*64 + ug*16 + (l&15);
  int k0 = ks*32 + 8*(l>>4);
  short v[8];
  #pragma unroll
  for(int j=0;j<8;j++) v[j]=f2b(Wh[(long)(k0+j)*FH + col]);
  *(bf16x8*)(frag + (long)tid*8) = *(bf16x8*)v;
}

// --------- MFMA batched persistent LSTM: 1 block/dir, 256 thr ---------------
#define MF(a,b,c) __builtin_amdgcn_mfma_f32_16x16x32_bf16(a,b,c,0,0,0)
#define LDF(T)    (*(const bf16x8*)(fr + (long)(T)*512 + l*8))
#define LDL(nt,ks) (*(const bf16x8*)(bl + ((nt)-10)*4096 + (ks)*512 + l*8))
#define DECLR(nt) bf16x8 R##nt##_0=LDF(nt*8+0),R##nt##_1=LDF(nt*8+1),R##nt##_2=LDF(nt*8+2),R##nt##_3=LDF(nt*8+3),R##nt##_4=LDF(nt*8+4),R##nt##_5=LDF(nt*8+5),R##nt##_6=LDF(nt*8+6),R##nt##_7=LDF(nt*8+7);
#define DECLC(nt) f32x4 C##nt={0.f,0.f,0.f,0.f};
#define MMR(nt) { C##nt=MF(A0,R##nt##_0,C##nt); C##nt=MF(A1,R##nt##_1,C##nt); C##nt=MF(A2,R##nt##_2,C##nt); C##nt=MF(A3,R##nt##_3,C##nt); C##nt=MF(A4,R##nt##_4,C##nt); C##nt=MF(A5,R##nt##_5,C##nt); C##nt=MF(A6,R##nt##_6,C##nt); C##nt=MF(A7,R##nt##_7,C##nt); }
#define MML(nt) { C##nt=MF(A0,LDL(nt,0),C##nt); C##nt=MF(A1,LDL(nt,1),C##nt); C##nt=MF(A2,LDL(nt,2),C##nt); C##nt=MF(A3,LDL(nt,3),C##nt); C##nt=MF(A4,LDL(nt,4),C##nt); C##nt=MF(A5,LDL(nt,5),C##nt); C##nt=MF(A6,LDL(nt,6),C##nt); C##nt=MF(A7,LDL(nt,7),C##nt); }
#define LOADSB(buf,T0) buf##0=LDF((T0)+0); buf##1=LDF((T0)+1); buf##2=LDF((T0)+2); buf##3=LDF((T0)+3); buf##4=LDF((T0)+4); buf##5=LDF((T0)+5); buf##6=LDF((T0)+6); buf##7=LDF((T0)+7);
#define MMSB(nt,buf) { C##nt=MF(A0,buf##0,C##nt); C##nt=MF(A1,buf##1,C##nt); C##nt=MF(A2,buf##2,C##nt); C##nt=MF(A3,buf##3,C##nt); C##nt=MF(A4,buf##4,C##nt); C##nt=MF(A5,buf##5,C##nt); C##nt=MF(A6,buf##6,C##nt); C##nt=MF(A7,buf##7,C##nt); }
// gates: x from two bf16x8 (XA: gates 0,1 ; XB: gates 2,3), h kept in regs
#define GATE1(ug,r,CA,CB,CC,CD,XA,XB) { \
  float zi=CA[r]+B2F(XA[r]), zf=CB[r]+B2F(XA[4+(r)]), zg=CC[r]+B2F(XB[r]), zo=CD[r]+B2F(XB[4+(r)]); \
  cst_##ug##_##r = sigf(zf)*cst_##ug##_##r + sigf(zi)*tanhf_(zg); \
  float hv = sigf(zo)*tanhf_(cst_##ug##_##r); \
  hv_##ug##_##r = hv; \
  int b_=4*(l>>4)+(r); int u_=w*64+(ug)*16+(l&15); \
  hbn[b_*264+u_]=f2b(hv); }
#define GATES(ug,CA,CB,CC,CD,XA,XB) \
  GATE1(ug,0,CA,CB,CC,CD,XA,XB) GATE1(ug,1,CA,CB,CC,CD,XA,XB) \
  GATE1(ug,2,CA,CB,CC,CD,XA,XB) GATE1(ug,3,CA,CB,CC,CD,XA,XB)
#define STOREH1(ug,r,tt) { int b_=4*(l>>4)+(r); int u_=w*64+(ug)*16+(l&15); \
  hg[((long)(tt)*16+b_)*256+u_]=hv_##ug##_##r; }
#define STOREH(tt) \
  STOREH1(0,0,tt) STOREH1(0,1,tt) STOREH1(0,2,tt) STOREH1(0,3,tt) \
  STOREH1(1,0,tt) STOREH1(1,1,tt) STOREH1(1,2,tt) STOREH1(1,3,tt) \
  STOREH1(2,0,tt) STOREH1(2,1,tt) STOREH1(2,2,tt) STOREH1(2,3,tt) \
  STOREH1(3,0,tt) STOREH1(3,1,tt) STOREH1(3,2,tt) STOREH1(3,3,tt)

extern __shared__ char smem_raw[];

__global__ __launch_bounds__(256,1) void k_lstm_mfma(
    const short* __restrict__ frag, const short* __restrict__ xwi2,
    float* __restrict__ hglob){
  const int dir = blockIdx.x;
  const int tid = threadIdx.x;
  const int w = tid>>6, l = tid&63;
  short* hb = (short*)smem_raw;                        // 2 x 16 x 264 shorts
  short* bl = (short*)(smem_raw + 16896) + w*16384;    // per-wave LDS B tiles (nt 10..13)
  const short* fr = frag + (long)(dir*4+w)*128*512;

  for(int i=tid;i<4224;i+=256) ((int*)smem_raw)[i]=0;  // zero both h buffers

  // stage LDS tiles nt 10..13 (T=80..111), 32 KB per wave
  #pragma unroll 4
  for(int c2=0;c2<32;c2++)
    *(f32x4*)(bl + c2*512 + l*8) = *(const f32x4*)(fr + 80*512 + c2*512 + l*8);

  DECLR(0) DECLR(1) DECLR(2) DECLR(3) DECLR(4) DECLR(5) DECLR(6) DECLR(7) DECLR(8) DECLR(9)

  float cst_0_0=0,cst_0_1=0,cst_0_2=0,cst_0_3=0, cst_1_0=0,cst_1_1=0,cst_1_2=0,cst_1_3=0,
        cst_2_0=0,cst_2_1=0,cst_2_2=0,cst_2_3=0, cst_3_0=0,cst_3_1=0,cst_3_2=0,cst_3_3=0;
  float hv_0_0=0,hv_0_1=0,hv_0_2=0,hv_0_3=0, hv_1_0=0,hv_1_1=0,hv_1_2=0,hv_1_3=0,
        hv_2_0=0,hv_2_1=0,hv_2_2=0,hv_2_3=0, hv_3_0=0,hv_3_1=0,hv_3_2=0,hv_3_3=0;
  bf16x8 S0_0,S0_1,S0_2,S0_3,S0_4,S0_5,S0_6,S0_7;
  bf16x8 S1_0,S1_1,S1_2,S1_3,S1_4,S1_5,S1_6,S1_7;
  // prefetch streamed tiles 14,15 (constant weights: loaded every step one step ahead)
  LOADSB(S0_,14*8) LOADSB(S1_,15*8)
  __syncthreads();

  const short* xwb = xwi2 + (long)dir*2097152 + (long)l*8;
  float* hg = hglob + (long)dir*524288;

  for(int t=0;t<LL;t++){
    const int cur=t&1, nxt=cur^1;
    if(t){ STOREH(t-1) }                       // deferred hglob stores (retire mid-step)
    const short* xp = xwb + ((long)t*4 + w)*4096;
    bf16x8 xj0=*(const bf16x8*)(xp+0*512), xj1=*(const bf16x8*)(xp+1*512),
           xj2=*(const bf16x8*)(xp+2*512), xj3=*(const bf16x8*)(xp+3*512),
           xj4=*(const bf16x8*)(xp+4*512), xj5=*(const bf16x8*)(xp+5*512),
           xj6=*(const bf16x8*)(xp+6*512), xj7=*(const bf16x8*)(xp+7*512);
    const short* hr = hb + cur*4224 + (l&15)*264 + (l>>4)*8;
    bf16x8 A0=*(const bf16x8*)(hr+0),   A1=*(const bf16x8*)(hr+32),
           A2=*(const bf16x8*)(hr+64),  A3=*(const bf16x8*)(hr+96),
           A4=*(const bf16x8*)(hr+128), A5=*(const bf16x8*)(hr+160),
           A6=*(const bf16x8*)(hr+192), A7=*(const bf16x8*)(hr+224);
    DECLC(0) DECLC(1) DECLC(2) DECLC(3) DECLC(4) DECLC(5) DECLC(6) DECLC(7)
    DECLC(8) DECLC(9) DECLC(10) DECLC(11) DECLC(12) DECLC(13) DECLC(14) DECLC(15)
    // consume prefetched streamed tiles first (zero stall), reissue for next step
    MMSB(14,S0_) MMSB(15,S1_)
    LOADSB(S0_,14*8) LOADSB(S1_,15*8)
    short* hbn = hb + nxt*4224;
    MMR(0) MMR(1) MMR(2) MMR(3)
    GATES(0, C0,C1,C2,C3,     xj0,xj1)
    MMR(4) MMR(5) MMR(6) MMR(7)
    GATES(1, C4,C5,C6,C7,     xj2,xj3)
    MMR(8) MMR(9) MML(10) MML(11)
    GATES(2, C8,C9,C10,C11,   xj4,xj5)
    MML(12) MML(13)
    GATES(3, C12,C13,C14,C15, xj6,xj7)
    __syncthreads();
  }
  STOREH(127)
}

// ---- enc = [hf|hb] @ Wenc + benc, relu(max) scatter into lembuf + flags ----
__global__ void k_enc(const int* __restrict__ seq, const int* __restrict__ len,
                      const int* __restrict__ u2l, const float* __restrict__ hglob,
                      const float* __restrict__ Wenc, const float* __restrict__ benc,
                      unsigned int* __restrict__ lembuf, unsigned int* __restrict__ flags){
  __shared__ __align__(16) float As[16][2*SZ];
  __shared__ const float* pf16[16]; __shared__ const float* pb16[16];
  __shared__ int lem_s[16], val_s[16], b_s[16];
  int r0=blockIdx.x*16, tid=threadIdx.x;
  if(tid<16){
    int r=r0+tid, b=r>>7, t=r&127, lb=len[b];
    int v=(t<lb); val_s[tid]=v; b_s[tid]=b;
    int lem=u2l[seq[r]];
    lem_s[tid]=lem;
    pf16[tid]=hglob+((long)t*BB+b)*SZ;
    int tr=v? (lb-1-t) : t;
    pb16[tid]=hglob+((long)(LL+tr)*BB+b)*SZ;
    if(v) flags[(long)b*NLEM+lem]=1u;
  }
  __syncthreads();
  for(int i=tid;i<16*SZ;i+=256){int lr=i>>8,j=i&(SZ-1);
    As[lr][j]=pf16[lr][j]; As[lr][SZ+j]=pb16[lr][j];}
  __syncthreads();
  int cl=tid&63, rg=tid>>6;
  float acc[4][4];
  #pragma unroll
  for(int i=0;i<4;i++){acc[i][0]=acc[i][1]=acc[i][2]=acc[i][3]=0.f;}
  for(int k=0;k<2*SZ;k+=4){
    float4 a4[4];
    #pragma unroll
    for(int i=0;i<4;i++) a4[i]=*(const float4*)&As[rg*4+i][k];
    #pragma unroll
    for(int j=0;j<4;j++){
      const float* wr=Wenc+(long)(k+j)*SZ+cl;
      float w0=wr[0],w1=wr[64],w2=wr[128],w3=wr[192];
      #pragma unroll
      for(int i=0;i<4;i++){
        float a=(j==0)?a4[i].x:(j==1)?a4[i].y:(j==2)?a4[i].z:a4[i].w;
        acc[i][0]=fmaf(a,w0,acc[i][0]);acc[i][1]=fmaf(a,w1,acc[i][1]);
        acc[i][2]=fmaf(a,w2,acc[i][2]);acc[i][3]=fmaf(a,w3,acc[i][3]);
      }
    }
  }
  #pragma unroll
  for(int i=0;i<4;i++){
    int lr=rg*4+i;
    if(val_s[lr]){
      long base=((long)b_s[lr]*NLEM+lem_s[lr])*SZ;
      #pragma unroll
      for(int cc=0;cc<4;cc++){
        int col=cl+cc*64;
        float e=fmaxf(acc[i][cc]+benc[col],0.f);
        atomicMax(&lembuf[base+col], __float_as_uint(e));
      }
    }
  }
}

// ------------ generic C[r] = A[r] @ W  (K=256), optional touched-flags ------
__global__ void k_rowgemm(const float* __restrict__ A, const float* __restrict__ W,
                          float* __restrict__ C, const unsigned int* __restrict__ flags){
  __shared__ __align__(16) float As[16][SZ];
  __shared__ int any_s;
  int r0=blockIdx.x*16, tid=threadIdx.x;
  if(tid==0){
    int a = flags? 0 : 1;
    if(flags){ for(int i=0;i<16;i++) a |= (int)flags[r0+i]; }
    any_s=a;
  }
  __syncthreads();
  if(!any_s) return;
  for(int i=tid;i<16*SZ;i+=256){int lr=i>>8,j=i&(SZ-1);As[lr][j]=A[(long)(r0+lr)*SZ+j];}
  __syncthreads();
  int cl=tid&63, rg=tid>>6;
  float acc[4][4];
  #pragma unroll
  for(int i=0;i<4;i++){acc[i][0]=acc[i][1]=acc[i][2]=acc[i][3]=0.f;}
  for(int k=0;k<SZ;k+=4){
    float4 a4[4];
    #pragma unroll
    for(int i=0;i<4;i++) a4[i]=*(const float4*)&As[rg*4+i][k];
    #pragma unroll
    for(int j=0;j<4;j++){
      const float* wr=W+(long)(k+j)*SZ+cl;
      float w0=wr[0],w1=wr[64],w2=wr[128],w3=wr[192];
      #pragma unroll
      for(int i=0;i<4;i++){
        float a=(j==0)?a4[i].x:(j==1)?a4[i].y:(j==2)?a4[i].z:a4[i].w;
        acc[i][0]=fmaf(a,w0,acc[i][0]);acc[i][1]=fmaf(a,w1,acc[i][1]);
        acc[i][2]=fmaf(a,w2,acc[i][2]);acc[i][3]=fmaf(a,w3,acc[i][3]);
      }
    }
  }
  #pragma unroll
  for(int i=0;i<4;i++){
    int r=r0+rg*4+i;
    #pragma unroll
    for(int cc=0;cc<4;cc++) C[(long)r*SZ+cl+cc*64]=acc[i][cc];
  }
}

// ---- P1base: A=we*sig(P0+bg) staged on the fly; result overwrites P0 -------
__global__ void k_p1base(const float* __restrict__ we, float* __restrict__ P0,
                         const float* __restrict__ bg, const float* __restrict__ W){
  __shared__ __align__(16) float As[16][SZ];
  int r0=blockIdx.x*16, tid=threadIdx.x;
  for(int i=tid;i<16*SZ;i+=256){int lr=i>>8,j=i&(SZ-1);
    long off=(long)(r0+lr)*SZ+j;
    As[lr][j]=we[off]*sigf(P0[off]+bg[j]);}
  __syncthreads();
  int cl=tid&63, rg=tid>>6;
  float acc[4][4];
  #pragma unroll
  for(int i=0;i<4;i++){acc[i][0]=acc[i][1]=acc[i][2]=acc[i][3]=0.f;}
  for(int k=0;k<SZ;k+=4){
    float4 a4[4];
    #pragma unroll
    for(int i=0;i<4;i++) a4[i]=*(const float4*)&As[rg*4+i][k];
    #pragma unroll
    for(int j=0;j<4;j++){
      const float* wr=W+(long)(k+j)*SZ+cl;
      float w0=wr[0],w1=wr[64],w2=wr[128],w3=wr[192];
      #pragma unroll
      for(int i=0;i<4;i++){
        float a=(j==0)?a4[i].x:(j==1)?a4[i].y:(j==2)?a4[i].z:a4[i].w;
        acc[i][0]=fmaf(a,w0,acc[i][0]);acc[i][1]=fmaf(a,w1,acc[i][1]);
        acc[i][2]=fmaf(a,w2,acc[i][2]);acc[i][3]=fmaf(a,w3,acc[i][3]);
      }
    }
  }
  #pragma unroll
  for(int i=0;i<4;i++){
    int r=r0+rg*4+i;
    #pragma unroll
    for(int cc=0;cc<4;cc++) P0[(long)r*SZ+cl+cc*64]=acc[i][cc];
  }
}

// ---- compact list of rows whose lemma was touched in iter 0 ----------------
__global__ void k_compact(const int* __restrict__ u2l, const unsigned int* __restrict__ flags,
                          int* __restrict__ cnt, int* __restrict__ list,
                          int* __restrict__ idxmap, int ncap){
  int r = blockIdx.x*256+threadIdx.x;
  if(r>=BB*NW) return;
  int b=r/NW, w=r-b*NW;
  int im=-1;
  if(flags[(long)b*NLEM+u2l[w]]){
    int idx=atomicAdd(cnt,1);
    if(idx<ncap){ list[idx]=r; im=idx; }
  }
  idxmap[r]=im;
}

// ---- Ptouch[i] = out[list[i]] @ Wg1 over the compacted rows ----------------
__global__ void k_ptouch(const float* __restrict__ out, const float* __restrict__ W,
                         const int* __restrict__ cnt, const int* __restrict__ list,
                         float* __restrict__ Pt){
  __shared__ __align__(16) float As[16][SZ];
  __shared__ const float* rp[16];
  int n=*cnt;
  int r0=blockIdx.x*16, tid=threadIdx.x;
  if(r0>=n) return;
  if(tid<16){
    int idx=r0+tid;
    rp[tid]=(idx<n)? out+(long)list[idx]*SZ : nullptr;
  }
  __syncthreads();
  for(int i=tid;i<16*SZ;i+=256){int lr=i>>8,j=i&(SZ-1);
    As[lr][j]= rp[lr]? rp[lr][j] : 0.f;}
  __syncthreads();
  int cl=tid&63, rg=tid>>6;
  float acc[4][4];
  #pragma unroll
  for(int i=0;i<4;i++){acc[i][0]=acc[i][1]=acc[i][2]=acc[i][3]=0.f;}
  for(int k=0;k<SZ;k+=4){
    float4 a4[4];
    #pragma unroll
    for(int i=0;i<4;i++) a4[i]=*(const float4*)&As[rg*4+i][k];
    #pragma unroll
    for(int j=0;j<4;j++){
      const float* wr=W+(long)(k+j)*SZ+cl;
      float w0=wr[0],w1=wr[64],w2=wr[128],w3=wr[192];
      #pragma unroll
      for(int i=0;i<4;i++){
        float a=(j==0)?a4[i].x:(j==1)?a4[i].y:(j==2)?a4[i].z:a4[i].w;
        acc[i][0]=fmaf(a,w0,acc[i][0]);acc[i][1]=fmaf(a,w1,acc[i][1]);
        acc[i][2]=fmaf(a,w2,acc[i][2]);acc[i][3]=fmaf(a,w3,acc[i][3]);
      }
    }
  }
  #pragma unroll
  for(int i=0;i<4;i++){
    int idx=r0+rg*4+i;
    if(idx<n){
      #pragma unroll
      for(int cc=0;cc<4;cc++) Pt[(long)idx*SZ+cl+cc*64]=acc[i][cc];
    }
  }
}

// ------- iter-0 gate: ctxt==tile(we) -> pure elementwise from P0/Q ----------
__global__ void k_gate0(const float* __restrict__ we, const float* __restrict__ P0,
                        const float* __restrict__ Q, const float* __restrict__ lembuf,
                        const int* __restrict__ u2l, const unsigned int* __restrict__ flags,
                        const float* __restrict__ bg, float* __restrict__ out){
  long idx=(long)blockIdx.x*256+threadIdx.x;
  const long TOTAL4=(long)BB*NW*SZ/4;
  if(idx>=TOTAL4) return;
  long row=idx>>6; int k4=(int)(idx&63);
  int r32=(int)row;
  int b=r32/NW, w=r32-b*NW;
  int lem=u2l[w];
  long qb=((long)b*NLEM+lem)*SZ;
  unsigned int fl=flags[(long)b*NLEM+lem];
  float4 p =((const float4*)(P0+(long)w*SZ))[k4];
  float4 wv=((const float4*)(we+(long)w*SZ))[k4];
  float4 bgv=((const float4*)bg)[k4];
  float4 q, nw;
  if(fl){ q=((const float4*)(Q+qb))[k4]; nw=((const float4*)(lembuf+qb))[k4]; }
  else  { q=make_float4(0.f,0.f,0.f,0.f); nw=q; }
  float4 o;
  { float g=sigf(p.x+q.x+bgv.x); o.x=wv.x*g+(1.f-g)*nw.x; }
  { float g=sigf(p.y+q.y+bgv.y); o.y=wv.y*g+(1.f-g)*nw.y; }
  { float g=sigf(p.z+q.z+bgv.z); o.z=wv.z*g+(1.f-g)*nw.z; }
  { float g=sigf(p.w+q.w+bgv.w); o.w=wv.w*g+(1.f-g)*nw.w; }
  ((float4*)out)[idx]=o;
}

// ------- iter-1 gate, elementwise: P from Ptouch (touched0) or P1base -------
__global__ void k_gate1e(const float* __restrict__ P1base, const float* __restrict__ Pt,
                         const int* __restrict__ idxmap,
                         const float* __restrict__ Q, const float* __restrict__ lembuf,
                         const int* __restrict__ u2l, const unsigned int* __restrict__ flags,
                         const float* __restrict__ bg, float* __restrict__ out){
  long idx=(long)blockIdx.x*256+threadIdx.x;
  const long TOTAL4=(long)BB*NW*SZ/4;
  if(idx>=TOTAL4) return;
  long row=idx>>6; int k4=(int)(idx&63);
  int r32=(int)row;
  int b=r32/NW, w=r32-b*NW;
  int im=idxmap[r32];
  int lem=u2l[w];
  long qb=((long)b*NLEM+lem)*SZ;
  unsigned int fl=flags[(long)b*NLEM+lem];
  float4 p = (im>=0)? ((const float4*)(Pt+(long)im*SZ))[k4]
                    : ((const float4*)(P1base+(long)w*SZ))[k4];
  float4 cv=((const float4*)(out+(long)row*SZ))[k4];
  float4 bgv=((const float4*)bg)[k4];
  float4 q, nw;
  if(fl){ q=((const float4*)(Q+qb))[k4]; nw=((const float4*)(lembuf+qb))[k4]; }
  else  { q=make_float4(0.f,0.f,0.f,0.f); nw=q; }
  float4 o;
  { float g=sigf(p.x+q.x+bgv.x); o.x=cv.x*g+(1.f-g)*nw.x; }
  { float g=sigf(p.y+q.y+bgv.y); o.y=cv.y*g+(1.f-g)*nw.y; }
  { float g=sigf(p.z+q.z+bgv.z); o.z=cv.z*g+(1.f-g)*nw.z; }
  { float g=sigf(p.w+q.w+bgv.w); o.w=cv.w*g+(1.f-g)*nw.w; }
  ((float4*)out)[idx]=o;
}

// ------- legacy dense iter-1 gate (fallback if ws too small) ----------------
__global__ void k_gate1(const float* __restrict__ ctxt, const float* __restrict__ Wg,
                        const float* __restrict__ Q, const float* __restrict__ lembuf,
                        const int* __restrict__ u2l, const unsigned int* __restrict__ flags,
                        const float* __restrict__ bg, float* __restrict__ out){
  __shared__ __align__(16) float As[64][SZ];
  __shared__ __align__(16) float Ws[64][SZ];
  __shared__ int lem_s[64];
  int r0=blockIdx.x*64, tid=threadIdx.x;
  for(int i=tid;i<64*SZ;i+=256){int lr=i>>8,j=i&(SZ-1);
    As[lr][j]=ctxt[(long)(r0+lr)*SZ+j];}
  if(tid<64){int r=r0+tid; lem_s[tid]=u2l[r%NW];}
  int cl=tid&63, rg=tid>>6;
  float acc[16][4];
  #pragma unroll
  for(int i=0;i<16;i++){acc[i][0]=acc[i][1]=acc[i][2]=acc[i][3]=0.f;}
  for(int kb=0;kb<4;kb++){
    __syncthreads();
    for(int i=tid;i<64*SZ;i+=256){int lr=i>>8,j=i&(SZ-1);
      Ws[lr][j]=Wg[(long)(kb*64+lr)*SZ+j];}
    __syncthreads();
    for(int k=0;k<64;k+=4){
      float4 a4[16];
      #pragma unroll
      for(int i=0;i<16;i++) a4[i]=*(const float4*)&As[rg*16+i][kb*64+k];
      #pragma unroll
      for(int j=0;j<4;j++){
        float w0=Ws[k+j][cl],w1=Ws[k+j][cl+64],w2=Ws[k+j][cl+128],w3=Ws[k+j][cl+192];
        #pragma unroll
        for(int i=0;i<16;i++){
          float a=(j==0)?a4[i].x:(j==1)?a4[i].y:(j==2)?a4[i].z:a4[i].w;
          acc[i][0]=fmaf(a,w0,acc[i][0]);acc[i][1]=fmaf(a,w1,acc[i][1]);
          acc[i][2]=fmaf(a,w2,acc[i][2]);acc[i][3]=fmaf(a,w3,acc[i][3]);
        }
      }
    }
  }
  #pragma unroll
  for(int i=0;i<16;i++){
    int lr=rg*16+i, r=r0+lr, b=r/NW;
    long base=((long)b*NLEM+lem_s[lr])*SZ;
    unsigned int fl=flags[(long)b*NLEM+lem_s[lr]];
    #pragma unroll
    for(int cc=0;cc<4;cc++){
      int col=cl+cc*64;
      float qv=0.f, nw=0.f;
      if(fl){ qv=Q[base+col]; nw=lembuf[base+col]; }
      float g=sigf(acc[i][cc]+qv+bg[col]);
      out[(long)r*SZ+col]=As[lr][col]*g+(1.f-g)*nw;
    }
  }
}

extern "C" void kernel_launch(void* const* d_in, const int* in_sizes, int n_in,
                              void* d_out, int out_size, void* d_ws, size_t ws_size,
                              hipStream_t stream){
  const float* emb  =(const float*)d_in[0];
  const float* Wp   =(const float*)d_in[1];
  const float* bp   =(const float*)d_in[2];
  const float* Wi_f =(const float*)d_in[3];
  const float* Wh_f =(const float*)d_in[4];
  const float* b_f  =(const float*)d_in[5];
  const float* Wi_b =(const float*)d_in[6];
  const float* Wh_b =(const float*)d_in[7];
  const float* b_b  =(const float*)d_in[8];
  const float* Wenc =(const float*)d_in[9];
  const float* benc =(const float*)d_in[10];
  const float* Wg   =(const float*)d_in[11];
  const float* bg   =(const float*)d_in[12];
  const int*   seq0 =(const int*)d_in[13];
  const int*   seq1 =(const int*)d_in[14];
  const int*   len0 =(const int*)d_in[15];
  const int*   len1 =(const int*)d_in[16];
  const int*   u2l  =(const int*)d_in[17];

  float* ws    = (float*)d_ws;
  float* we    = ws;                       // 2,560,000
  float* xwi   = we    + 2560000;          // 4,194,304 (bf16 fragment layout; oversized)
  float* hglob = xwi   + 4194304;          // 1,048,576
  float* lembuf= hglob + 1048576;          // 12,288,000
  float* flags = lembuf+ 12288000;         // 48,000 (uint)
  float* Q     = flags + 48000;            // 12,288,000
  float* P0    = Q     + 12288000;         // 2,560,000 (becomes P1base)
  short* whb   = (short*)(P0 + 2560000);   // 524,288 shorts = 262,144 floats
  int*   idxmap= (int*)(P0 + 2560000 + 262144);   // 160,000
  int*   list  = idxmap + 160000;          // NCAPMAX
  int*   cnt   = list + NCAPMAX;           // 1 (+3 pad)
  float* Ptouch= (float*)(cnt + 4);        // up to NCAPMAX*256
  long base_floats = (long)(Ptouch - ws);
  long avail = ((long)(ws_size/4) - base_floats)/SZ;
  int ncap = (int)(avail > NCAPMAX ? NCAPMAX : (avail<0?0:avail));
  int sparse_ok = (ncap >= 16384);
  float* out   = (float*)d_out;

  hipFuncSetAttribute((const void*)k_lstm_mfma,
                      hipFuncAttributeMaxDynamicSharedMemorySize, 147968);

  k_we<<<NW/16,256,0,stream>>>(emb,Wp,bp,we);
  k_rowgemm<<<NW/16,256,0,stream>>>(we,Wg,P0,nullptr);            // P0 = we@Wg1
  k_prep<<<256,256,0,stream>>>(Wh_f,Wh_b,whb);

  const int* seqs[2]={seq0,seq1};
  const int* lens[2]={len0,len1};
  for(int i=0;i<2;i++){
    hipMemsetAsync(lembuf,0,(size_t)(12288000+48000)*4,stream);   // lembuf + flags
    const float* src = (i==0)? we : out;
    long bstride     = (i==0)? 0L : (long)NW*SZ;
    dim3 gx(64,4);
    k_xwi<<<gx,256,0,stream>>>(seqs[i],lens[i],src,bstride,Wi_f,b_f,Wi_b,b_b,i,(short*)xwi);
    k_lstm_mfma<<<2,256,147968,stream>>>(whb,(const short*)xwi,hglob);
    k_enc<<<BB*LL/16,256,0,stream>>>(seqs[i],lens[i],u2l,hglob,Wenc,benc,
                                     (unsigned int*)lembuf,(unsigned int*)flags);
    k_rowgemm<<<BB*NLEM/16,256,0,stream>>>(lembuf,Wg+(long)SZ*SZ,Q,
                                           (const unsigned int*)flags); // Q = nw@Wg2
    if(i==0){
      long nb=((long)BB*NW*SZ/4+255)/256;
      k_gate0<<<(int)nb,256,0,stream>>>(we,P0,Q,lembuf,u2l,
                                        (const unsigned int*)flags,bg,out);
      if(sparse_ok){
        hipMemsetAsync(cnt,0,4,stream);
        k_compact<<<(BB*NW+255)/256,256,0,stream>>>(u2l,(const unsigned int*)flags,
                                                    cnt,list,idxmap,ncap);
        k_ptouch<<<(ncap+15)/16,256,0,stream>>>(out,Wg,cnt,list,Ptouch);
        k_p1base<<<NW/16,256,0,stream>>>(we,P0,bg,Wg);   // P0 <- C0@Wg1
      }
    }else{
      if(sparse_ok){
        long nb=((long)BB*NW*SZ/4+255)/256;
        k_gate1e<<<(int)nb,256,0,stream>>>(P0,Ptouch,idxmap,Q,lembuf,u2l,
                                           (const unsigned int*)flags,bg,out);
      }else{
        k_gate1<<<BB*NW/64,256,0,stream>>>(out,Wg,Q,lembuf,u2l,
                                           (const unsigned int*)flags,bg,out);
      }
    }
  }
}

// Round 7
// 2044.774 us; speedup vs baseline: 3.7933x; 1.0075x over previous
//
#include <hip/hip_runtime.h>

#define NW    10000
#define INDIM 300
#define SZ    256
#define BB    16
#define LL    128
#define NLEM  3000
#define FH    1024   // 4*SZ
#define NCAPMAX 32768

typedef short  bf16x8 __attribute__((ext_vector_type(8)));
typedef float  f32x4  __attribute__((ext_vector_type(4)));

// fast sigmoid/tanh: v_exp_f32 (=2^x) + v_rcp_f32, no IEEE divide sequences
__device__ __forceinline__ float sigf(float x){
  return __builtin_amdgcn_rcpf(1.f+__builtin_amdgcn_exp2f(-1.442695041f*x));
}
__device__ __forceinline__ float tanhf_(float x){
  return fmaf(-2.f, __builtin_amdgcn_rcpf(1.f+__builtin_amdgcn_exp2f(2.885390082f*x)), 1.f);
}
__device__ __forceinline__ short f2b(float f){
  unsigned u=__float_as_uint(f); u += 0x7FFFu + ((u>>16)&1u); return (short)(u>>16);
}
#define B2F(s) __uint_as_float(((unsigned)(unsigned short)(s))<<16)

// ---------------- we = relu(emb @ Wp + bp) : [10000,300]@[300,256] ----------
__global__ void k_we(const float* __restrict__ emb, const float* __restrict__ Wp,
                     const float* __restrict__ bp, float* __restrict__ we){
  __shared__ __align__(16) float As[16][INDIM];
  int r0 = blockIdx.x*16, tid = threadIdx.x;
  for(int i=tid;i<16*INDIM;i+=256){int lr=i/INDIM,d=i-lr*INDIM;
    As[lr][d]=emb[(long)(r0+lr)*INDIM+d];}
  __syncthreads();
  int cl=tid&63, rg=tid>>6;
  float acc[4][4];
  #pragma unroll
  for(int i=0;i<4;i++){acc[i][0]=acc[i][1]=acc[i][2]=acc[i][3]=0.f;}
  for(int k=0;k<INDIM;k+=4){
    float4 a4[4];
    #pragma unroll
    for(int i=0;i<4;i++) a4[i]=*(const float4*)&As[rg*4+i][k];
    #pragma unroll
    for(int j=0;j<4;j++){
      const float* wr=Wp+(long)(k+j)*SZ+cl;
      float w0=wr[0],w1=wr[64],w2=wr[128],w3=wr[192];
      #pragma unroll
      for(int i=0;i<4;i++){
        float a=(j==0)?a4[i].x:(j==1)?a4[i].y:(j==2)?a4[i].z:a4[i].w;
        acc[i][0]=fmaf(a,w0,acc[i][0]);acc[i][1]=fmaf(a,w1,acc[i][1]);
        acc[i][2]=fmaf(a,w2,acc[i][2]);acc[i][3]=fmaf(a,w3,acc[i][3]);
      }
    }
  }
  #pragma unroll
  for(int i=0;i<4;i++){
    int r=r0+rg*4+i;
    #pragma unroll
    for(int cc=0;cc<4;cc++){int col=cl+cc*64;
      we[(long)r*SZ+col]=fmaxf(acc[i][cc]+bp[col],0.f);}
  }
}

// ---- xwi (bf16, lane-contiguous layout):
// short idx = (((dir*128+t)*4+w)*4096) + j*512 + lane*8 + elem
//   col=g*256+w*64+ug*16+nl -> j=ug*2+(g>>1), lane=(b>>2)*16+nl, elem=(g&1)*4+(b&3)
__global__ void k_xwi(const int* __restrict__ seq, const int* __restrict__ len,
                      const float* __restrict__ src, long bstride,
                      const float* __restrict__ Wi_f, const float* __restrict__ bvf,
                      const float* __restrict__ Wi_b, const float* __restrict__ bvb,
                      int iseq, short* __restrict__ xwo){
  __shared__ __align__(16) float As[64][SZ];
  __shared__ const float* rowp[64];
  int r0=blockIdx.x*64, cb=blockIdx.y, tid=threadIdx.x;
  int dir=r0>>11;
  if(tid<64){
    int grow=r0+tid;
    int t=(grow>>4)&(LL-1), b=grow&(BB-1);
    int lb=len[b];
    int tt=(dir==0)? t : ((t<lb)? (lb-1-t) : t);
    int tok=seq[b*LL+tt];
    rowp[tid]=src + (long)b*bstride + (long)tok*SZ;
  }
  __syncthreads();
  for(int i=tid;i<64*SZ;i+=256){int lr=i>>8,j=i&(SZ-1);As[lr][j]=rowp[lr][j];}
  __syncthreads();
  const float* __restrict__ Wi = dir? Wi_b : Wi_f;
  const float* __restrict__ bv = dir? bvb : bvf;
  int cl=tid&63, rg=tid>>6, c0=cb*256+cl;
  float acc[16][4];
  #pragma unroll
  for(int i=0;i<16;i++){acc[i][0]=acc[i][1]=acc[i][2]=acc[i][3]=0.f;}
  for(int k=0;k<SZ;k+=4){
    float4 a4[16];
    #pragma unroll
    for(int i=0;i<16;i++) a4[i]=*(const float4*)&As[rg*16+i][k];
    #pragma unroll
    for(int j=0;j<4;j++){
      const float* wr=Wi+(long)(k+j)*FH+c0;
      float w0=wr[0],w1=wr[64],w2=wr[128],w3=wr[192];
      #pragma unroll
      for(int i=0;i<16;i++){
        float a=(j==0)?a4[i].x:(j==1)?a4[i].y:(j==2)?a4[i].z:a4[i].w;
        acc[i][0]=fmaf(a,w0,acc[i][0]);acc[i][1]=fmaf(a,w1,acc[i][1]);
        acc[i][2]=fmaf(a,w2,acc[i][2]);acc[i][3]=fmaf(a,w3,acc[i][3]);
      }
    }
  }
  #pragma unroll
  for(int cc=0;cc<4;cc++){
    int cx=c0+cc*64;
    float be=Wi[(long)(SZ+iseq)*FH+cx]+bv[cx];
    int g=cx>>8, rem=cx&255, w2=rem>>6, ug=(rem>>4)&3, nl=rem&15;
    int j2=ug*2+(g>>1);
    #pragma unroll
    for(int i=0;i<16;i++){
      int grow=r0+rg*16+i;
      int b=grow&15, t=(grow>>4)&127, d2=grow>>11;
      long sidx=((((long)d2*128+t)*4+w2)*4096) + j2*512 + ((b>>2)*16+nl)*8 + (g&1)*4 + (b&3);
      xwo[sidx]=f2b(acc[i][cc]+be);
    }
  }
}

// ---- prep: Wh -> bf16 MFMA B-fragments, gate-grouped column permutation ----
__global__ void k_prep(const float* __restrict__ Wh_f, const float* __restrict__ Wh_b,
                       short* __restrict__ frag){
  int tid = blockIdx.x*256 + threadIdx.x;   // 65536 total
  int l = tid&63, T=(tid>>6)&127, w=(tid>>13)&3, dir=tid>>15;
  const float* Wh = dir? Wh_b : Wh_f;
  int nt=T>>3, ks=T&7, ug=nt>>2, g=nt&3;
  int col = g*256 + w*64 + ug*16 + (l&15);
  int k0 = ks*32 + 8*(l>>4);
  short v[8];
  #pragma unroll
  for(int j=0;j<8;j++) v[j]=f2b(Wh[(long)(k0+j)*FH + col]);
  *(bf16x8*)(frag + (long)tid*8) = *(bf16x8*)v;
}

// --------- MFMA batched persistent LSTM: 1 block/dir, 256 thr ---------------
// ALL 16 weight tiles resident: 12 in VGPR/AGPR + 4 in LDS. Zero per-step
// weight streaming (R6's hidden L2 re-stream was the bottleneck). Two-pass
// accumulators (C regs 64->32) make the register budget fit (~500/508).
#define MF(a,b,c) __builtin_amdgcn_mfma_f32_16x16x32_bf16(a,b,c,0,0,0)
#define LDF(T)    (*(const bf16x8*)(fr + (long)(T)*512 + l*8))
#define LDL(nt,ks) (*(const bf16x8*)(bl + ((nt)-12)*4096 + (ks)*512 + l*8))
#define DECLR(nt) bf16x8 R##nt##_0=LDF(nt*8+0),R##nt##_1=LDF(nt*8+1),R##nt##_2=LDF(nt*8+2),R##nt##_3=LDF(nt*8+3),R##nt##_4=LDF(nt*8+4),R##nt##_5=LDF(nt*8+5),R##nt##_6=LDF(nt*8+6),R##nt##_7=LDF(nt*8+7);
#define DECLC(nt) f32x4 C##nt={0.f,0.f,0.f,0.f};
#define MMR(nt) { C##nt=MF(A0,R##nt##_0,C##nt); C##nt=MF(A1,R##nt##_1,C##nt); C##nt=MF(A2,R##nt##_2,C##nt); C##nt=MF(A3,R##nt##_3,C##nt); C##nt=MF(A4,R##nt##_4,C##nt); C##nt=MF(A5,R##nt##_5,C##nt); C##nt=MF(A6,R##nt##_6,C##nt); C##nt=MF(A7,R##nt##_7,C##nt); }
#define MML(nt) { C##nt=MF(A0,LDL(nt,0),C##nt); C##nt=MF(A1,LDL(nt,1),C##nt); C##nt=MF(A2,LDL(nt,2),C##nt); C##nt=MF(A3,LDL(nt,3),C##nt); C##nt=MF(A4,LDL(nt,4),C##nt); C##nt=MF(A5,LDL(nt,5),C##nt); C##nt=MF(A6,LDL(nt,6),C##nt); C##nt=MF(A7,LDL(nt,7),C##nt); }
// gates: x from two bf16x8 (XA: gates 0,1 ; XB: gates 2,3)
#define GATE1(ug,r,CA,CB,CC,CD,XA,XB) { \
  float zi=CA[r]+B2F(XA[r]), zf=CB[r]+B2F(XA[4+(r)]), zg=CC[r]+B2F(XB[r]), zo=CD[r]+B2F(XB[4+(r)]); \
  cst_##ug##_##r = sigf(zf)*cst_##ug##_##r + sigf(zi)*tanhf_(zg); \
  float hv = sigf(zo)*tanhf_(cst_##ug##_##r); \
  int b_=4*(l>>4)+(r); int u_=w*64+(ug)*16+(l&15); \
  hbn[b_*264+u_]=f2b(hv); \
  hg[((long)t*16+b_)*256+u_]=hv; }
#define GATES(ug,CA,CB,CC,CD,XA,XB) \
  GATE1(ug,0,CA,CB,CC,CD,XA,XB) GATE1(ug,1,CA,CB,CC,CD,XA,XB) \
  GATE1(ug,2,CA,CB,CC,CD,XA,XB) GATE1(ug,3,CA,CB,CC,CD,XA,XB)

extern __shared__ char smem_raw[];

__global__ __launch_bounds__(256,1) void k_lstm_mfma(
    const short* __restrict__ frag, const short* __restrict__ xwi2,
    float* __restrict__ hglob){
  const int dir = blockIdx.x;
  const int tid = threadIdx.x;
  const int w = tid>>6, l = tid&63;
  short* hb = (short*)smem_raw;                        // 2 x 16 x 264 shorts
  short* bl = (short*)(smem_raw + 16896) + w*16384;    // per-wave LDS B tiles (nt 12..15)
  const short* fr = frag + (long)(dir*4+w)*128*512;

  for(int i=tid;i<4224;i+=256) ((int*)smem_raw)[i]=0;  // zero both h buffers

  // stage LDS tiles nt 12..15 (T=96..127), 32 KB per wave
  #pragma unroll 4
  for(int c2=0;c2<32;c2++)
    *(f32x4*)(bl + c2*512 + l*8) = *(const f32x4*)(fr + 96*512 + c2*512 + l*8);

  // 12 resident weight tiles (384 regs, lands in VGPR+AGPR unified file)
  DECLR(0) DECLR(1) DECLR(2) DECLR(3) DECLR(4) DECLR(5)
  DECLR(6) DECLR(7) DECLR(8) DECLR(9) DECLR(10) DECLR(11)

  float cst_0_0=0,cst_0_1=0,cst_0_2=0,cst_0_3=0, cst_1_0=0,cst_1_1=0,cst_1_2=0,cst_1_3=0,
        cst_2_0=0,cst_2_1=0,cst_2_2=0,cst_2_3=0, cst_3_0=0,cst_3_1=0,cst_3_2=0,cst_3_3=0;
  __syncthreads();

  const short* xwb = xwi2 + (long)dir*2097152 + (long)l*8;
  float* hg = hglob + (long)dir*524288;

  for(int t=0;t<LL;t++){
    const int cur=t&1, nxt=cur^1;
    const short* xp = xwb + ((long)t*4 + w)*4096;
    bf16x8 xj0=*(const bf16x8*)(xp+0*512), xj1=*(const bf16x8*)(xp+1*512),
           xj2=*(const bf16x8*)(xp+2*512), xj3=*(const bf16x8*)(xp+3*512);
    const short* hr = hb + cur*4224 + (l&15)*264 + (l>>4)*8;
    bf16x8 A0=*(const bf16x8*)(hr+0),   A1=*(const bf16x8*)(hr+32),
           A2=*(const bf16x8*)(hr+64),  A3=*(const bf16x8*)(hr+96),
           A4=*(const bf16x8*)(hr+128), A5=*(const bf16x8*)(hr+160),
           A6=*(const bf16x8*)(hr+192), A7=*(const bf16x8*)(hr+224);
    short* hbn = hb + nxt*4224;
    // ---- pass 1: ntiles 0..7 (ug 0,1), all VGPR-resident ----
    DECLC(0) DECLC(1) DECLC(2) DECLC(3) DECLC(4) DECLC(5) DECLC(6) DECLC(7)
    MMR(0) MMR(1) MMR(2) MMR(3) MMR(4) MMR(5) MMR(6) MMR(7)
    bf16x8 xj4=*(const bf16x8*)(xp+4*512), xj5=*(const bf16x8*)(xp+5*512),
           xj6=*(const bf16x8*)(xp+6*512), xj7=*(const bf16x8*)(xp+7*512);
    GATES(0, C0,C1,C2,C3, xj0,xj1)
    GATES(1, C4,C5,C6,C7, xj2,xj3)
    // ---- pass 2: ntiles 8..15 (ug 2,3), 8..11 resident + 12..15 from LDS ----
    DECLC(8) DECLC(9) DECLC(10) DECLC(11) DECLC(12) DECLC(13) DECLC(14) DECLC(15)
    MMR(8) MMR(9) MMR(10) MMR(11)
    MML(12) MML(13) MML(14) MML(15)
    GATES(2, C8,C9,C10,C11,   xj4,xj5)
    GATES(3, C12,C13,C14,C15, xj6,xj7)
    __syncthreads();
  }
}

// ---- enc = [hf|hb] @ Wenc + benc, relu(max) scatter into lembuf + flags ----
__global__ void k_enc(const int* __restrict__ seq, const int* __restrict__ len,
                      const int* __restrict__ u2l, const float* __restrict__ hglob,
                      const float* __restrict__ Wenc, const float* __restrict__ benc,
                      unsigned int* __restrict__ lembuf, unsigned int* __restrict__ flags){
  __shared__ __align__(16) float As[16][2*SZ];
  __shared__ const float* pf16[16]; __shared__ const float* pb16[16];
  __shared__ int lem_s[16], val_s[16], b_s[16];
  int r0=blockIdx.x*16, tid=threadIdx.x;
  if(tid<16){
    int r=r0+tid, b=r>>7, t=r&127, lb=len[b];
    int v=(t<lb); val_s[tid]=v; b_s[tid]=b;
    int lem=u2l[seq[r]];
    lem_s[tid]=lem;
    pf16[tid]=hglob+((long)t*BB+b)*SZ;
    int tr=v? (lb-1-t) : t;
    pb16[tid]=hglob+((long)(LL+tr)*BB+b)*SZ;
    if(v) flags[(long)b*NLEM+lem]=1u;
  }
  __syncthreads();
  for(int i=tid;i<16*SZ;i+=256){int lr=i>>8,j=i&(SZ-1);
    As[lr][j]=pf16[lr][j]; As[lr][SZ+j]=pb16[lr][j];}
  __syncthreads();
  int cl=tid&63, rg=tid>>6;
  float acc[4][4];
  #pragma unroll
  for(int i=0;i<4;i++){acc[i][0]=acc[i][1]=acc[i][2]=acc[i][3]=0.f;}
  for(int k=0;k<2*SZ;k+=4){
    float4 a4[4];
    #pragma unroll
    for(int i=0;i<4;i++) a4[i]=*(const float4*)&As[rg*4+i][k];
    #pragma unroll
    for(int j=0;j<4;j++){
      const float* wr=Wenc+(long)(k+j)*SZ+cl;
      float w0=wr[0],w1=wr[64],w2=wr[128],w3=wr[192];
      #pragma unroll
      for(int i=0;i<4;i++){
        float a=(j==0)?a4[i].x:(j==1)?a4[i].y:(j==2)?a4[i].z:a4[i].w;
        acc[i][0]=fmaf(a,w0,acc[i][0]);acc[i][1]=fmaf(a,w1,acc[i][1]);
        acc[i][2]=fmaf(a,w2,acc[i][2]);acc[i][3]=fmaf(a,w3,acc[i][3]);
      }
    }
  }
  #pragma unroll
  for(int i=0;i<4;i++){
    int lr=rg*4+i;
    if(val_s[lr]){
      long base=((long)b_s[lr]*NLEM+lem_s[lr])*SZ;
      #pragma unroll
      for(int cc=0;cc<4;cc++){
        int col=cl+cc*64;
        float e=fmaxf(acc[i][cc]+benc[col],0.f);
        atomicMax(&lembuf[base+col], __float_as_uint(e));
      }
    }
  }
}

// ------------ generic C[r] = A[r] @ W  (K=256), optional touched-flags ------
__global__ void k_rowgemm(const float* __restrict__ A, const float* __restrict__ W,
                          float* __restrict__ C, const unsigned int* __restrict__ flags){
  __shared__ __align__(16) float As[16][SZ];
  __shared__ int any_s;
  int r0=blockIdx.x*16, tid=threadIdx.x;
  if(tid==0){
    int a = flags? 0 : 1;
    if(flags){ for(int i=0;i<16;i++) a |= (int)flags[r0+i]; }
    any_s=a;
  }
  __syncthreads();
  if(!any_s) return;
  for(int i=tid;i<16*SZ;i+=256){int lr=i>>8,j=i&(SZ-1);As[lr][j]=A[(long)(r0+lr)*SZ+j];}
  __syncthreads();
  int cl=tid&63, rg=tid>>6;
  float acc[4][4];
  #pragma unroll
  for(int i=0;i<4;i++){acc[i][0]=acc[i][1]=acc[i][2]=acc[i][3]=0.f;}
  for(int k=0;k<SZ;k+=4){
    float4 a4[4];
    #pragma unroll
    for(int i=0;i<4;i++) a4[i]=*(const float4*)&As[rg*4+i][k];
    #pragma unroll
    for(int j=0;j<4;j++){
      const float* wr=W+(long)(k+j)*SZ+cl;
      float w0=wr[0],w1=wr[64],w2=wr[128],w3=wr[192];
      #pragma unroll
      for(int i=0;i<4;i++){
        float a=(j==0)?a4[i].x:(j==1)?a4[i].y:(j==2)?a4[i].z:a4[i].w;
        acc[i][0]=fmaf(a,w0,acc[i][0]);acc[i][1]=fmaf(a,w1,acc[i][1]);
        acc[i][2]=fmaf(a,w2,acc[i][2]);acc[i][3]=fmaf(a,w3,acc[i][3]);
      }
    }
  }
  #pragma unroll
  for(int i=0;i<4;i++){
    int r=r0+rg*4+i;
    #pragma unroll
    for(int cc=0;cc<4;cc++) C[(long)r*SZ+cl+cc*64]=acc[i][cc];
  }
}

// ---- P1base: A=we*sig(P0+bg) staged on the fly; result overwrites P0 -------
__global__ void k_p1base(const float* __restrict__ we, float* __restrict__ P0,
                         const float* __restrict__ bg, const float* __restrict__ W){
  __shared__ __align__(16) float As[16][SZ];
  int r0=blockIdx.x*16, tid=threadIdx.x;
  for(int i=tid;i<16*SZ;i+=256){int lr=i>>8,j=i&(SZ-1);
    long off=(long)(r0+lr)*SZ+j;
    As[lr][j]=we[off]*sigf(P0[off]+bg[j]);}
  __syncthreads();
  int cl=tid&63, rg=tid>>6;
  float acc[4][4];
  #pragma unroll
  for(int i=0;i<4;i++){acc[i][0]=acc[i][1]=acc[i][2]=acc[i][3]=0.f;}
  for(int k=0;k<SZ;k+=4){
    float4 a4[4];
    #pragma unroll
    for(int i=0;i<4;i++) a4[i]=*(const float4*)&As[rg*4+i][k];
    #pragma unroll
    for(int j=0;j<4;j++){
      const float* wr=W+(long)(k+j)*SZ+cl;
      float w0=wr[0],w1=wr[64],w2=wr[128],w3=wr[192];
      #pragma unroll
      for(int i=0;i<4;i++){
        float a=(j==0)?a4[i].x:(j==1)?a4[i].y:(j==2)?a4[i].z:a4[i].w;
        acc[i][0]=fmaf(a,w0,acc[i][0]);acc[i][1]=fmaf(a,w1,acc[i][1]);
        acc[i][2]=fmaf(a,w2,acc[i][2]);acc[i][3]=fmaf(a,w3,acc[i][3]);
      }
    }
  }
  #pragma unroll
  for(int i=0;i<4;i++){
    int r=r0+rg*4+i;
    #pragma unroll
    for(int cc=0;cc<4;cc++) P0[(long)r*SZ+cl+cc*64]=acc[i][cc];
  }
}

// ---- compact list of rows whose lemma was touched in iter 0 ----------------
__global__ void k_compact(const int* __restrict__ u2l, const unsigned int* __restrict__ flags,
                          int* __restrict__ cnt, int* __restrict__ list,
                          int* __restrict__ idxmap, int ncap){
  int r = blockIdx.x*256+threadIdx.x;
  if(r>=BB*NW) return;
  int b=r/NW, w=r-b*NW;
  int im=-1;
  if(flags[(long)b*NLEM+u2l[w]]){
    int idx=atomicAdd(cnt,1);
    if(idx<ncap){ list[idx]=r; im=idx; }
  }
  idxmap[r]=im;
}

// ---- Ptouch[i] = out[list[i]] @ Wg1 over the compacted rows ----------------
__global__ void k_ptouch(const float* __restrict__ out, const float* __restrict__ W,
                         const int* __restrict__ cnt, const int* __restrict__ list,
                         float* __restrict__ Pt){
  __shared__ __align__(16) float As[16][SZ];
  __shared__ const float* rp[16];
  int n=*cnt;
  int r0=blockIdx.x*16, tid=threadIdx.x;
  if(r0>=n) return;
  if(tid<16){
    int idx=r0+tid;
    rp[tid]=(idx<n)? out+(long)list[idx]*SZ : nullptr;
  }
  __syncthreads();
  for(int i=tid;i<16*SZ;i+=256){int lr=i>>8,j=i&(SZ-1);
    As[lr][j]= rp[lr]? rp[lr][j] : 0.f;}
  __syncthreads();
  int cl=tid&63, rg=tid>>6;
  float acc[4][4];
  #pragma unroll
  for(int i=0;i<4;i++){acc[i][0]=acc[i][1]=acc[i][2]=acc[i][3]=0.f;}
  for(int k=0;k<SZ;k+=4){
    float4 a4[4];
    #pragma unroll
    for(int i=0;i<4;i++) a4[i]=*(const float4*)&As[rg*4+i][k];
    #pragma unroll
    for(int j=0;j<4;j++){
      const float* wr=W+(long)(k+j)*SZ+cl;
      float w0=wr[0],w1=wr[64],w2=wr[128],w3=wr[192];
      #pragma unroll
      for(int i=0;i<4;i++){
        float a=(j==0)?a4[i].x:(j==1)?a4[i].y:(j==2)?a4[i].z:a4[i].w;
        acc[i][0]=fmaf(a,w0,acc[i][0]);acc[i][1]=fmaf(a,w1,acc[i][1]);
        acc[i][2]=fmaf(a,w2,acc[i][2]);acc[i][3]=fmaf(a,w3,acc[i][3]);
      }
    }
  }
  #pragma unroll
  for(int i=0;i<4;i++){
    int idx=r0+rg*4+i;
    if(idx<n){
      #pragma unroll
      for(int cc=0;cc<4;cc++) Pt[(long)idx*SZ+cl+cc*64]=acc[i][cc];
    }
  }
}

// ------- iter-0 gate: ctxt==tile(we) -> pure elementwise from P0/Q ----------
__global__ void k_gate0(const float* __restrict__ we, const float* __restrict__ P0,
                        const float* __restrict__ Q, const float* __restrict__ lembuf,
                        const int* __restrict__ u2l, const unsigned int* __restrict__ flags,
                        const float* __restrict__ bg, float* __restrict__ out){
  long idx=(long)blockIdx.x*256+threadIdx.x;
  const long TOTAL4=(long)BB*NW*SZ/4;
  if(idx>=TOTAL4) return;
  long row=idx>>6; int k4=(int)(idx&63);
  int r32=(int)row;
  int b=r32/NW, w=r32-b*NW;
  int lem=u2l[w];
  long qb=((long)b*NLEM+lem)*SZ;
  unsigned int fl=flags[(long)b*NLEM+lem];
  float4 p =((const float4*)(P0+(long)w*SZ))[k4];
  float4 wv=((const float4*)(we+(long)w*SZ))[k4];
  float4 bgv=((const float4*)bg)[k4];
  float4 q, nw;
  if(fl){ q=((const float4*)(Q+qb))[k4]; nw=((const float4*)(lembuf+qb))[k4]; }
  else  { q=make_float4(0.f,0.f,0.f,0.f); nw=q; }
  float4 o;
  { float g=sigf(p.x+q.x+bgv.x); o.x=wv.x*g+(1.f-g)*nw.x; }
  { float g=sigf(p.y+q.y+bgv.y); o.y=wv.y*g+(1.f-g)*nw.y; }
  { float g=sigf(p.z+q.z+bgv.z); o.z=wv.z*g+(1.f-g)*nw.z; }
  { float g=sigf(p.w+q.w+bgv.w); o.w=wv.w*g+(1.f-g)*nw.w; }
  ((float4*)out)[idx]=o;
}

// ------- iter-1 gate, elementwise: P from Ptouch (touched0) or P1base -------
__global__ void k_gate1e(const float* __restrict__ P1base, const float* __restrict__ Pt,
                         const int* __restrict__ idxmap,
                         const float* __restrict__ Q, const float* __restrict__ lembuf,
                         const int* __restrict__ u2l, const unsigned int* __restrict__ flags,
                         const float* __restrict__ bg, float* __restrict__ out){
  long idx=(long)blockIdx.x*256+threadIdx.x;
  const long TOTAL4=(long)BB*NW*SZ/4;
  if(idx>=TOTAL4) return;
  long row=idx>>6; int k4=(int)(idx&63);
  int r32=(int)row;
  int b=r32/NW, w=r32-b*NW;
  int im=idxmap[r32];
  int lem=u2l[w];
  long qb=((long)b*NLEM+lem)*SZ;
  unsigned int fl=flags[(long)b*NLEM+lem];
  float4 p = (im>=0)? ((const float4*)(Pt+(long)im*SZ))[k4]
                    : ((const float4*)(P1base+(long)w*SZ))[k4];
  float4 cv=((const float4*)(out+(long)row*SZ))[k4];
  float4 bgv=((const float4*)bg)[k4];
  float4 q, nw;
  if(fl){ q=((const float4*)(Q+qb))[k4]; nw=((const float4*)(lembuf+qb))[k4]; }
  else  { q=make_float4(0.f,0.f,0.f,0.f); nw=q; }
  float4 o;
  { float g=sigf(p.x+q.x+bgv.x); o.x=cv.x*g+(1.f-g)*nw.x; }
  { float g=sigf(p.y+q.y+bgv.y); o.y=cv.y*g+(1.f-g)*nw.y; }
  { float g=sigf(p.z+q.z+bgv.z); o.z=cv.z*g+(1.f-g)*nw.z; }
  { float g=sigf(p.w+q.w+bgv.w); o.w=cv.w*g+(1.f-g)*nw.w; }
  ((float4*)out)[idx]=o;
}

// ------- legacy dense iter-1 gate (fallback if ws too small) ----------------
__global__ void k_gate1(const float* __restrict__ ctxt, const float* __restrict__ Wg,
                        const float* __restrict__ Q, const float* __restrict__ lembuf,
                        const int* __restrict__ u2l, const unsigned int* __restrict__ flags,
                        const float* __restrict__ bg, float* __restrict__ out){
  __shared__ __align__(16) float As[64][SZ];
  __shared__ __align__(16) float Ws[64][SZ];
  __shared__ int lem_s[64];
  int r0=blockIdx.x*64, tid=threadIdx.x;
  for(int i=tid;i<64*SZ;i+=256){int lr=i>>8,j=i&(SZ-1);
    As[lr][j]=ctxt[(long)(r0+lr)*SZ+j];}
  if(tid<64){int r=r0+tid; lem_s[tid]=u2l[r%NW];}
  int cl=tid&63, rg=tid>>6;
  float acc[16][4];
  #pragma unroll
  for(int i=0;i<16;i++){acc[i][0]=acc[i][1]=acc[i][2]=acc[i][3]=0.f;}
  for(int kb=0;kb<4;kb++){
    __syncthreads();
    for(int i=tid;i<64*SZ;i+=256){int lr=i>>8,j=i&(SZ-1);
      Ws[lr][j]=Wg[(long)(kb*64+lr)*SZ+j];}
    __syncthreads();
    for(int k=0;k<64;k+=4){
      float4 a4[16];
      #pragma unroll
      for(int i=0;i<16;i++) a4[i]=*(const float4*)&As[rg*16+i][kb*64+k];
      #pragma unroll
      for(int j=0;j<4;j++){
        float w0=Ws[k+j][cl],w1=Ws[k+j][cl+64],w2=Ws[k+j][cl+128],w3=Ws[k+j][cl+192];
        #pragma unroll
        for(int i=0;i<16;i++){
          float a=(j==0)?a4[i].x:(j==1)?a4[i].y:(j==2)?a4[i].z:a4[i].w;
          acc[i][0]=fmaf(a,w0,acc[i][0]);acc[i][1]=fmaf(a,w1,acc[i][1]);
          acc[i][2]=fmaf(a,w2,acc[i][2]);acc[i][3]=fmaf(a,w3,acc[i][3]);
        }
      }
    }
  }
  #pragma unroll
  for(int i=0;i<16;i++){
    int lr=rg*16+i, r=r0+lr, b=r/NW;
    long base=((long)b*NLEM+lem_s[lr])*SZ;
    unsigned int fl=flags[(long)b*NLEM+lem_s[lr]];
    #pragma unroll
    for(int cc=0;cc<4;cc++){
      int col=cl+cc*64;
      float qv=0.f, nw=0.f;
      if(fl){ qv=Q[base+col]; nw=lembuf[base+col]; }
      float g=sigf(acc[i][cc]+qv+bg[col]);
      out[(long)r*SZ+col]=As[lr][col]*g+(1.f-g)*nw;
    }
  }
}

extern "C" void kernel_launch(void* const* d_in, const int* in_sizes, int n_in,
                              void* d_out, int out_size, void* d_ws, size_t ws_size,
                              hipStream_t stream){
  const float* emb  =(const float*)d_in[0];
  const float* Wp   =(const float*)d_in[1];
  const float* bp   =(const float*)d_in[2];
  const float* Wi_f =(const float*)d_in[3];
  const float* Wh_f =(const float*)d_in[4];
  const float* b_f  =(const float*)d_in[5];
  const float* Wi_b =(const float*)d_in[6];
  const float* Wh_b =(const float*)d_in[7];
  const float* b_b  =(const float*)d_in[8];
  const float* Wenc =(const float*)d_in[9];
  const float* benc =(const float*)d_in[10];
  const float* Wg   =(const float*)d_in[11];
  const float* bg   =(const float*)d_in[12];
  const int*   seq0 =(const int*)d_in[13];
  const int*   seq1 =(const int*)d_in[14];
  const int*   len0 =(const int*)d_in[15];
  const int*   len1 =(const int*)d_in[16];
  const int*   u2l  =(const int*)d_in[17];

  float* ws    = (float*)d_ws;
  float* we    = ws;                       // 2,560,000
  float* xwi   = we    + 2560000;          // 4,194,304 (bf16 fragment layout; oversized)
  float* hglob = xwi   + 4194304;          // 1,048,576
  float* lembuf= hglob + 1048576;          // 12,288,000
  float* flags = lembuf+ 12288000;         // 48,000 (uint)
  float* Q     = flags + 48000;            // 12,288,000
  float* P0    = Q     + 12288000;         // 2,560,000 (becomes P1base)
  short* whb   = (short*)(P0 + 2560000);   // 524,288 shorts = 262,144 floats
  int*   idxmap= (int*)(P0 + 2560000 + 262144);   // 160,000
  int*   list  = idxmap + 160000;          // NCAPMAX
  int*   cnt   = list + NCAPMAX;           // 1 (+3 pad)
  float* Ptouch= (float*)(cnt + 4);        // up to NCAPMAX*256
  long base_floats = (long)(Ptouch - ws);
  long avail = ((long)(ws_size/4) - base_floats)/SZ;
  int ncap = (int)(avail > NCAPMAX ? NCAPMAX : (avail<0?0:avail));
  int sparse_ok = (ncap >= 16384);
  float* out   = (float*)d_out;

  hipFuncSetAttribute((const void*)k_lstm_mfma,
                      hipFuncAttributeMaxDynamicSharedMemorySize, 147968);

  k_we<<<NW/16,256,0,stream>>>(emb,Wp,bp,we);
  k_rowgemm<<<NW/16,256,0,stream>>>(we,Wg,P0,nullptr);            // P0 = we@Wg1
  k_prep<<<256,256,0,stream>>>(Wh_f,Wh_b,whb);

  const int* seqs[2]={seq0,seq1};
  const int* lens[2]={len0,len1};
  for(int i=0;i<2;i++){
    hipMemsetAsync(lembuf,0,(size_t)(12288000+48000)*4,stream);   // lembuf + flags
    const float* src = (i==0)? we : out;
    long bstride     = (i==0)? 0L : (long)NW*SZ;
    dim3 gx(64,4);
    k_xwi<<<gx,256,0,stream>>>(seqs[i],lens[i],src,bstride,Wi_f,b_f,Wi_b,b_b,i,(short*)xwi);
    k_lstm_mfma<<<2,256,147968,stream>>>(whb,(const short*)xwi,hglob);
    k_enc<<<BB*LL/16,256,0,stream>>>(seqs[i],lens[i],u2l,hglob,Wenc,benc,
                                     (unsigned int*)lembuf,(unsigned int*)flags);
    k_rowgemm<<<BB*NLEM/16,256,0,stream>>>(lembuf,Wg+(long)SZ*SZ,Q,
                                           (const unsigned int*)flags); // Q = nw@Wg2
    if(i==0){
      long nb=((long)BB*NW*SZ/4+255)/256;
      k_gate0<<<(int)nb,256,0,stream>>>(we,P0,Q,lembuf,u2l,
                                        (const unsigned int*)flags,bg,out);
      if(sparse_ok){
        hipMemsetAsync(cnt,0,4,stream);
        k_compact<<<(BB*NW+255)/256,256,0,stream>>>(u2l,(const unsigned int*)flags,
                                                    cnt,list,idxmap,ncap);
        k_ptouch<<<(ncap+15)/16,256,0,stream>>>(out,Wg,cnt,list,Ptouch);
        k_p1base<<<NW/16,256,0,stream>>>(we,P0,bg,Wg);   // P0 <- C0@Wg1
      }
    }else{
      if(sparse_ok){
        long nb=((long)BB*NW*SZ/4+255)/256;
        k_gate1e<<<(int)nb,256,0,stream>>>(P0,Ptouch,idxmap,Q,lembuf,u2l,
                                           (const unsigned int*)flags,bg,out);
      }else{
        k_gate1<<<BB*NW/64,256,0,stream>>>(out,Wg,Q,lembuf,u2l,
                                           (const unsigned int*)flags,bg,out);
      }
    }
  }
}

// Round 8
// 1912.950 us; speedup vs baseline: 4.0547x; 1.0689x over previous
//
#include <hip/hip_runtime.h>

#define NW    10000
#define INDIM 300
#define SZ    256
#define BB    16
#define LL    128
#define NLEM  3000
#define FH    1024   // 4*SZ
#define NCAPMAX 32768

typedef short  bf16x8 __attribute__((ext_vector_type(8)));
typedef float  f32x4  __attribute__((ext_vector_type(4)));

__device__ __forceinline__ float sigf(float x){
  return __builtin_amdgcn_rcpf(1.f+__builtin_amdgcn_exp2f(-1.442695041f*x));
}
__device__ __forceinline__ float tanhf_(float x){
  return fmaf(-2.f, __builtin_amdgcn_rcpf(1.f+__builtin_amdgcn_exp2f(2.885390082f*x)), 1.f);
}
__device__ __forceinline__ short f2b(float f){
  unsigned u=__float_as_uint(f); u += 0x7FFFu + ((u>>16)&1u); return (short)(u>>16);
}
#define B2F(s) __uint_as_float(((unsigned)(unsigned short)(s))<<16)

// ---------------- we = relu(emb @ Wp + bp) : [10000,300]@[300,256] ----------
__global__ void k_we(const float* __restrict__ emb, const float* __restrict__ Wp,
                     const float* __restrict__ bp, float* __restrict__ we){
  __shared__ __align__(16) float As[16][INDIM];
  int r0 = blockIdx.x*16, tid = threadIdx.x;
  for(int i=tid;i<16*INDIM;i+=256){int lr=i/INDIM,d=i-lr*INDIM;
    As[lr][d]=emb[(long)(r0+lr)*INDIM+d];}
  __syncthreads();
  int cl=tid&63, rg=tid>>6;
  float acc[4][4];
  #pragma unroll
  for(int i=0;i<4;i++){acc[i][0]=acc[i][1]=acc[i][2]=acc[i][3]=0.f;}
  for(int k=0;k<INDIM;k+=4){
    float4 a4[4];
    #pragma unroll
    for(int i=0;i<4;i++) a4[i]=*(const float4*)&As[rg*4+i][k];
    #pragma unroll
    for(int j=0;j<4;j++){
      const float* wr=Wp+(long)(k+j)*SZ+cl;
      float w0=wr[0],w1=wr[64],w2=wr[128],w3=wr[192];
      #pragma unroll
      for(int i=0;i<4;i++){
        float a=(j==0)?a4[i].x:(j==1)?a4[i].y:(j==2)?a4[i].z:a4[i].w;
        acc[i][0]=fmaf(a,w0,acc[i][0]);acc[i][1]=fmaf(a,w1,acc[i][1]);
        acc[i][2]=fmaf(a,w2,acc[i][2]);acc[i][3]=fmaf(a,w3,acc[i][3]);
      }
    }
  }
  #pragma unroll
  for(int i=0;i<4;i++){
    int r=r0+rg*4+i;
    #pragma unroll
    for(int cc=0;cc<4;cc++){int col=cl+cc*64;
      we[(long)r*SZ+col]=fmaxf(acc[i][cc]+bp[col],0.f);}
  }
}

// ---- xwi (bf16): sidx = (((dir*128+t)*16 + blk*4 + w)*64 + lane)*16 + g*4 + r
//   col=g*256+unit ; unit=blk*64+w*16+nl ; lane=(b>>2)*16+nl ; r=b&3
__global__ void k_xwi(const int* __restrict__ seq, const int* __restrict__ len,
                      const float* __restrict__ src, long bstride,
                      const float* __restrict__ Wi_f, const float* __restrict__ bvf,
                      const float* __restrict__ Wi_b, const float* __restrict__ bvb,
                      int iseq, short* __restrict__ xwo){
  __shared__ __align__(16) float As[64][SZ];
  __shared__ const float* rowp[64];
  int r0=blockIdx.x*64, cb=blockIdx.y, tid=threadIdx.x;
  int dir=r0>>11;
  if(tid<64){
    int grow=r0+tid;
    int t=(grow>>4)&(LL-1), b=grow&(BB-1);
    int lb=len[b];
    int tt=(dir==0)? t : ((t<lb)? (lb-1-t) : t);
    int tok=seq[b*LL+tt];
    rowp[tid]=src + (long)b*bstride + (long)tok*SZ;
  }
  __syncthreads();
  for(int i=tid;i<64*SZ;i+=256){int lr=i>>8,j=i&(SZ-1);As[lr][j]=rowp[lr][j];}
  __syncthreads();
  const float* __restrict__ Wi = dir? Wi_b : Wi_f;
  const float* __restrict__ bv = dir? bvb : bvf;
  int cl=tid&63, rg=tid>>6, c0=cb*256+cl;
  float acc[16][4];
  #pragma unroll
  for(int i=0;i<16;i++){acc[i][0]=acc[i][1]=acc[i][2]=acc[i][3]=0.f;}
  for(int k=0;k<SZ;k+=4){
    float4 a4[16];
    #pragma unroll
    for(int i=0;i<16;i++) a4[i]=*(const float4*)&As[rg*16+i][k];
    #pragma unroll
    for(int j=0;j<4;j++){
      const float* wr=Wi+(long)(k+j)*FH+c0;
      float w0=wr[0],w1=wr[64],w2=wr[128],w3=wr[192];
      #pragma unroll
      for(int i=0;i<16;i++){
        float a=(j==0)?a4[i].x:(j==1)?a4[i].y:(j==2)?a4[i].z:a4[i].w;
        acc[i][0]=fmaf(a,w0,acc[i][0]);acc[i][1]=fmaf(a,w1,acc[i][1]);
        acc[i][2]=fmaf(a,w2,acc[i][2]);acc[i][3]=fmaf(a,w3,acc[i][3]);
      }
    }
  }
  #pragma unroll
  for(int cc=0;cc<4;cc++){
    int cx=c0+cc*64;
    float be=Wi[(long)(SZ+iseq)*FH+cx]+bv[cx];
    int g=cx>>8, unit=cx&255, blk2=unit>>6, w2=(unit>>4)&3, nl=unit&15;
    #pragma unroll
    for(int i=0;i<16;i++){
      int grow=r0+rg*16+i;
      int b=grow&15, t=(grow>>4)&127, d2=grow>>11;
      long sidx=((((long)d2*128+t)*16 + blk2*4 + w2)*64 + (b>>2)*16+nl)*16 + g*4 + (b&3);
      xwo[sidx]=f2b(acc[i][cc]+be);
    }
  }
}

// ---- prep: Wh -> bf16 MFMA B-fragments, (dir,blk,w,g,ks,lane) tiling -------
__global__ void k_prep(const float* __restrict__ Wh_f, const float* __restrict__ Wh_b,
                       short* __restrict__ frag){
  int tid = blockIdx.x*256 + threadIdx.x;   // 65536 total
  int l=tid&63, ks=(tid>>6)&7, g=(tid>>9)&3, w=(tid>>11)&3, blk=(tid>>13)&3, dir=tid>>15;
  const float* Wh = dir? Wh_b : Wh_f;
  int col = g*256 + blk*64 + w*16 + (l&15);
  int k0  = ks*32 + (l>>4)*8;
  short v[8];
  #pragma unroll
  for(int j=0;j<8;j++) v[j]=f2b(Wh[(long)(k0+j)*FH + col]);
  *(bf16x8*)(frag + (long)tid*8) = *(bf16x8*)v;
}

// --------- multi-block persistent LSTM: 8 blocks (4 per dir) ----------------
// Each block owns 64 hidden units (256 gate-cols). All weights VGPR-resident.
// Per-step inter-block sync via device-scope atomics; h exchanged in global
// (double-buffered by step parity; writer is provably <=1 step ahead).
#define MFA(a,b,c) __builtin_amdgcn_mfma_f32_16x16x32_bf16(a,b,c,0,0,0)
#define LW(g,ks) (*(const bf16x8*)(fr + ((g)*8+(ks))*512 + l*8))
#define DECLW(g) bf16x8 W##g##_0=LW(g,0),W##g##_1=LW(g,1),W##g##_2=LW(g,2),W##g##_3=LW(g,3),W##g##_4=LW(g,4),W##g##_5=LW(g,5),W##g##_6=LW(g,6),W##g##_7=LW(g,7);
#define MM4(ks) { C0=MFA(A##ks,W0_##ks,C0); C1=MFA(A##ks,W1_##ks,C1); \
                  C2=MFA(A##ks,W2_##ks,C2); C3=MFA(A##ks,W3_##ks,C3); }

__global__ __launch_bounds__(256,1) void k_lstm_sync(
    const short* __restrict__ frag, const short* __restrict__ xq,
    float* __restrict__ hglob, short* __restrict__ hx, int* __restrict__ ctr){
  const int dir = blockIdx.x>>2, blk = blockIdx.x&3;
  const int tid = threadIdx.x, w = tid>>6, l = tid&63;
  const short* fr = frag + ((long)((dir*4+blk)*4 + w))*32*512;
  DECLW(0) DECLW(1) DECLW(2) DECLW(3)
  float cst0=0.f,cst1=0.f,cst2=0.f,cst3=0.f;
  const int unit = blk*64 + w*16 + (l&15);
  int* myctr = ctr + dir*LL;
  short* hxd = hx + dir*2*4096;
  float* hg  = hglob + (long)dir*524288;
  const short* xbase = xq + (((long)dir*LL*16 + blk*4 + w)*64 + l)*16;

  for(int t=0;t<LL;t++){
    const short* xp = xbase + (long)t*16384;   // 16 groups * 64 lanes * 16
    bf16x8 XA=*(const bf16x8*)xp, XB=*(const bf16x8*)(xp+8);
    f32x4 C0={0.f,0.f,0.f,0.f},C1=C0,C2=C0,C3=C0;
    if(t){
      // wait for all 4 blocks of this dir to publish h_{t-1}
      if(tid==0){
        while(__hip_atomic_load(myctr+t-1,__ATOMIC_ACQUIRE,__HIP_MEMORY_SCOPE_AGENT)<4){}
      }
      __syncthreads();
      const short* hr = hxd + ((t+1)&1)*4096 + (l&15)*256 + (l>>4)*8;
      bf16x8 A0=*(const bf16x8*)(hr+0),   A1=*(const bf16x8*)(hr+32),
             A2=*(const bf16x8*)(hr+64),  A3=*(const bf16x8*)(hr+96),
             A4=*(const bf16x8*)(hr+128), A5=*(const bf16x8*)(hr+160),
             A6=*(const bf16x8*)(hr+192), A7=*(const bf16x8*)(hr+224);
      MM4(0) MM4(1) MM4(2) MM4(3) MM4(4) MM4(5) MM4(6) MM4(7)
    }
    short* hw = hxd + (t&1)*4096;
    #pragma unroll
    for(int r=0;r<4;r++){
      float zi=C0[r]+B2F(XA[r]), zf=C1[r]+B2F(XA[4+r]),
            zg=C2[r]+B2F(XB[r]), zo=C3[r]+B2F(XB[4+r]);
      float cs = (r==0)?cst0:(r==1)?cst1:(r==2)?cst2:cst3;
      cs = sigf(zf)*cs + sigf(zi)*tanhf_(zg);
      if(r==0)cst0=cs; else if(r==1)cst1=cs; else if(r==2)cst2=cs; else cst3=cs;
      float hv = sigf(zo)*tanhf_(cs);
      int b_=4*(l>>4)+r;
      hw[b_*256+unit]=f2b(hv);
      hg[((long)t*16+b_)*256+unit]=hv;
    }
    __threadfence();          // make h_t visible device-wide
    __syncthreads();
    if(tid==0) __hip_atomic_fetch_add(myctr+t,1,__ATOMIC_RELEASE,__HIP_MEMORY_SCOPE_AGENT);
  }
}

// ---- enc = [hf|hb] @ Wenc + benc, relu(max) scatter into lembuf + flags ----
__global__ void k_enc(const int* __restrict__ seq, const int* __restrict__ len,
                      const int* __restrict__ u2l, const float* __restrict__ hglob,
                      const float* __restrict__ Wenc, const float* __restrict__ benc,
                      unsigned int* __restrict__ lembuf, unsigned int* __restrict__ flags){
  __shared__ __align__(16) float As[16][2*SZ];
  __shared__ const float* pf16[16]; __shared__ const float* pb16[16];
  __shared__ int lem_s[16], val_s[16], b_s[16];
  int r0=blockIdx.x*16, tid=threadIdx.x;
  if(tid<16){
    int r=r0+tid, b=r>>7, t=r&127, lb=len[b];
    int v=(t<lb); val_s[tid]=v; b_s[tid]=b;
    int lem=u2l[seq[r]];
    lem_s[tid]=lem;
    pf16[tid]=hglob+((long)t*BB+b)*SZ;
    int tr=v? (lb-1-t) : t;
    pb16[tid]=hglob+((long)(LL+tr)*BB+b)*SZ;
    if(v) flags[(long)b*NLEM+lem]=1u;
  }
  __syncthreads();
  for(int i=tid;i<16*SZ;i+=256){int lr=i>>8,j=i&(SZ-1);
    As[lr][j]=pf16[lr][j]; As[lr][SZ+j]=pb16[lr][j];}
  __syncthreads();
  int cl=tid&63, rg=tid>>6;
  float acc[4][4];
  #pragma unroll
  for(int i=0;i<4;i++){acc[i][0]=acc[i][1]=acc[i][2]=acc[i][3]=0.f;}
  for(int k=0;k<2*SZ;k+=4){
    float4 a4[4];
    #pragma unroll
    for(int i=0;i<4;i++) a4[i]=*(const float4*)&As[rg*4+i][k];
    #pragma unroll
    for(int j=0;j<4;j++){
      const float* wr=Wenc+(long)(k+j)*SZ+cl;
      float w0=wr[0],w1=wr[64],w2=wr[128],w3=wr[192];
      #pragma unroll
      for(int i=0;i<4;i++){
        float a=(j==0)?a4[i].x:(j==1)?a4[i].y:(j==2)?a4[i].z:a4[i].w;
        acc[i][0]=fmaf(a,w0,acc[i][0]);acc[i][1]=fmaf(a,w1,acc[i][1]);
        acc[i][2]=fmaf(a,w2,acc[i][2]);acc[i][3]=fmaf(a,w3,acc[i][3]);
      }
    }
  }
  #pragma unroll
  for(int i=0;i<4;i++){
    int lr=rg*4+i;
    if(val_s[lr]){
      long base=((long)b_s[lr]*NLEM+lem_s[lr])*SZ;
      #pragma unroll
      for(int cc=0;cc<4;cc++){
        int col=cl+cc*64;
        float e=fmaxf(acc[i][cc]+benc[col],0.f);
        atomicMax(&lembuf[base+col], __float_as_uint(e));
      }
    }
  }
}

// ------------ generic C[r] = A[r] @ W  (K=256), optional touched-flags ------
__global__ void k_rowgemm(const float* __restrict__ A, const float* __restrict__ W,
                          float* __restrict__ C, const unsigned int* __restrict__ flags){
  __shared__ __align__(16) float As[16][SZ];
  __shared__ int any_s;
  int r0=blockIdx.x*16, tid=threadIdx.x;
  if(tid==0){
    int a = flags? 0 : 1;
    if(flags){ for(int i=0;i<16;i++) a |= (int)flags[r0+i]; }
    any_s=a;
  }
  __syncthreads();
  if(!any_s) return;
  for(int i=tid;i<16*SZ;i+=256){int lr=i>>8,j=i&(SZ-1);As[lr][j]=A[(long)(r0+lr)*SZ+j];}
  __syncthreads();
  int cl=tid&63, rg=tid>>6;
  float acc[4][4];
  #pragma unroll
  for(int i=0;i<4;i++){acc[i][0]=acc[i][1]=acc[i][2]=acc[i][3]=0.f;}
  for(int k=0;k<SZ;k+=4){
    float4 a4[4];
    #pragma unroll
    for(int i=0;i<4;i++) a4[i]=*(const float4*)&As[rg*4+i][k];
    #pragma unroll
    for(int j=0;j<4;j++){
      const float* wr=W+(long)(k+j)*SZ+cl;
      float w0=wr[0],w1=wr[64],w2=wr[128],w3=wr[192];
      #pragma unroll
      for(int i=0;i<4;i++){
        float a=(j==0)?a4[i].x:(j==1)?a4[i].y:(j==2)?a4[i].z:a4[i].w;
        acc[i][0]=fmaf(a,w0,acc[i][0]);acc[i][1]=fmaf(a,w1,acc[i][1]);
        acc[i][2]=fmaf(a,w2,acc[i][2]);acc[i][3]=fmaf(a,w3,acc[i][3]);
      }
    }
  }
  #pragma unroll
  for(int i=0;i<4;i++){
    int r=r0+rg*4+i;
    #pragma unroll
    for(int cc=0;cc<4;cc++) C[(long)r*SZ+cl+cc*64]=acc[i][cc];
  }
}

// ---- P1base: A=we*sig(P0+bg) staged on the fly; result overwrites P0 -------
__global__ void k_p1base(const float* __restrict__ we, float* __restrict__ P0,
                         const float* __restrict__ bg, const float* __restrict__ W){
  __shared__ __align__(16) float As[16][SZ];
  int r0=blockIdx.x*16, tid=threadIdx.x;
  for(int i=tid;i<16*SZ;i+=256){int lr=i>>8,j=i&(SZ-1);
    long off=(long)(r0+lr)*SZ+j;
    As[lr][j]=we[off]*sigf(P0[off]+bg[j]);}
  __syncthreads();
  int cl=tid&63, rg=tid>>6;
  float acc[4][4];
  #pragma unroll
  for(int i=0;i<4;i++){acc[i][0]=acc[i][1]=acc[i][2]=acc[i][3]=0.f;}
  for(int k=0;k<SZ;k+=4){
    float4 a4[4];
    #pragma unroll
    for(int i=0;i<4;i++) a4[i]=*(const float4*)&As[rg*4+i][k];
    #pragma unroll
    for(int j=0;j<4;j++){
      const float* wr=W+(long)(k+j)*SZ+cl;
      float w0=wr[0],w1=wr[64],w2=wr[128],w3=wr[192];
      #pragma unroll
      for(int i=0;i<4;i++){
        float a=(j==0)?a4[i].x:(j==1)?a4[i].y:(j==2)?a4[i].z:a4[i].w;
        acc[i][0]=fmaf(a,w0,acc[i][0]);acc[i][1]=fmaf(a,w1,acc[i][1]);
        acc[i][2]=fmaf(a,w2,acc[i][2]);acc[i][3]=fmaf(a,w3,acc[i][3]);
      }
    }
  }
  #pragma unroll
  for(int i=0;i<4;i++){
    int r=r0+rg*4+i;
    #pragma unroll
    for(int cc=0;cc<4;cc++) P0[(long)r*SZ+cl+cc*64]=acc[i][cc];
  }
}

// ---- compact list of rows whose lemma was touched in iter 0 ----------------
__global__ void k_compact(const int* __restrict__ u2l, const unsigned int* __restrict__ flags,
                          int* __restrict__ cnt, int* __restrict__ list,
                          int* __restrict__ idxmap, int ncap){
  int r = blockIdx.x*256+threadIdx.x;
  if(r>=BB*NW) return;
  int b=r/NW, w=r-b*NW;
  int im=-1;
  if(flags[(long)b*NLEM+u2l[w]]){
    int idx=atomicAdd(cnt,1);
    if(idx<ncap){ list[idx]=r; im=idx; }
  }
  idxmap[r]=im;
}

// ---- Ptouch[i] = out[list[i]] @ Wg1 over the compacted rows ----------------
__global__ void k_ptouch(const float* __restrict__ out, const float* __restrict__ W,
                         const int* __restrict__ cnt, const int* __restrict__ list,
                         float* __restrict__ Pt){
  __shared__ __align__(16) float As[16][SZ];
  __shared__ const float* rp[16];
  int n=*cnt;
  int r0=blockIdx.x*16, tid=threadIdx.x;
  if(r0>=n) return;
  if(tid<16){
    int idx=r0+tid;
    rp[tid]=(idx<n)? out+(long)list[idx]*SZ : nullptr;
  }
  __syncthreads();
  for(int i=tid;i<16*SZ;i+=256){int lr=i>>8,j=i&(SZ-1);
    As[lr][j]= rp[lr]? rp[lr][j] : 0.f;}
  __syncthreads();
  int cl=tid&63, rg=tid>>6;
  float acc[4][4];
  #pragma unroll
  for(int i=0;i<4;i++){acc[i][0]=acc[i][1]=acc[i][2]=acc[i][3]=0.f;}
  for(int k=0;k<SZ;k+=4){
    float4 a4[4];
    #pragma unroll
    for(int i=0;i<4;i++) a4[i]=*(const float4*)&As[rg*4+i][k];
    #pragma unroll
    for(int j=0;j<4;j++){
      const float* wr=W+(long)(k+j)*SZ+cl;
      float w0=wr[0],w1=wr[64],w2=wr[128],w3=wr[192];
      #pragma unroll
      for(int i=0;i<4;i++){
        float a=(j==0)?a4[i].x:(j==1)?a4[i].y:(j==2)?a4[i].z:a4[i].w;
        acc[i][0]=fmaf(a,w0,acc[i][0]);acc[i][1]=fmaf(a,w1,acc[i][1]);
        acc[i][2]=fmaf(a,w2,acc[i][2]);acc[i][3]=fmaf(a,w3,acc[i][3]);
      }
    }
  }
  #pragma unroll
  for(int i=0;i<4;i++){
    int idx=r0+rg*4+i;
    if(idx<n){
      #pragma unroll
      for(int cc=0;cc<4;cc++) Pt[(long)idx*SZ+cl+cc*64]=acc[i][cc];
    }
  }
}

// ------- iter-0 gate: ctxt==tile(we) -> pure elementwise from P0/Q ----------
__global__ void k_gate0(const float* __restrict__ we, const float* __restrict__ P0,
                        const float* __restrict__ Q, const float* __restrict__ lembuf,
                        const int* __restrict__ u2l, const unsigned int* __restrict__ flags,
                        const float* __restrict__ bg, float* __restrict__ out){
  long idx=(long)blockIdx.x*256+threadIdx.x;
  const long TOTAL4=(long)BB*NW*SZ/4;
  if(idx>=TOTAL4) return;
  long row=idx>>6; int k4=(int)(idx&63);
  int r32=(int)row;
  int b=r32/NW, w=r32-b*NW;
  int lem=u2l[w];
  long qb=((long)b*NLEM+lem)*SZ;
  unsigned int fl=flags[(long)b*NLEM+lem];
  float4 p =((const float4*)(P0+(long)w*SZ))[k4];
  float4 wv=((const float4*)(we+(long)w*SZ))[k4];
  float4 bgv=((const float4*)bg)[k4];
  float4 q, nw;
  if(fl){ q=((const float4*)(Q+qb))[k4]; nw=((const float4*)(lembuf+qb))[k4]; }
  else  { q=make_float4(0.f,0.f,0.f,0.f); nw=q; }
  float4 o;
  { float g=sigf(p.x+q.x+bgv.x); o.x=wv.x*g+(1.f-g)*nw.x; }
  { float g=sigf(p.y+q.y+bgv.y); o.y=wv.y*g+(1.f-g)*nw.y; }
  { float g=sigf(p.z+q.z+bgv.z); o.z=wv.z*g+(1.f-g)*nw.z; }
  { float g=sigf(p.w+q.w+bgv.w); o.w=wv.w*g+(1.f-g)*nw.w; }
  ((float4*)out)[idx]=o;
}

// ------- iter-1 gate, elementwise: P from Ptouch (touched0) or P1base -------
__global__ void k_gate1e(const float* __restrict__ P1base, const float* __restrict__ Pt,
                         const int* __restrict__ idxmap,
                         const float* __restrict__ Q, const float* __restrict__ lembuf,
                         const int* __restrict__ u2l, const unsigned int* __restrict__ flags,
                         const float* __restrict__ bg, float* __restrict__ out){
  long idx=(long)blockIdx.x*256+threadIdx.x;
  const long TOTAL4=(long)BB*NW*SZ/4;
  if(idx>=TOTAL4) return;
  long row=idx>>6; int k4=(int)(idx&63);
  int r32=(int)row;
  int b=r32/NW, w=r32-b*NW;
  int im=idxmap[r32];
  int lem=u2l[w];
  long qb=((long)b*NLEM+lem)*SZ;
  unsigned int fl=flags[(long)b*NLEM+lem];
  float4 p = (im>=0)? ((const float4*)(Pt+(long)im*SZ))[k4]
                    : ((const float4*)(P1base+(long)w*SZ))[k4];
  float4 cv=((const float4*)(out+(long)row*SZ))[k4];
  float4 bgv=((const float4*)bg)[k4];
  float4 q, nw;
  if(fl){ q=((const float4*)(Q+qb))[k4]; nw=((const float4*)(lembuf+qb))[k4]; }
  else  { q=make_float4(0.f,0.f,0.f,0.f); nw=q; }
  float4 o;
  { float g=sigf(p.x+q.x+bgv.x); o.x=cv.x*g+(1.f-g)*nw.x; }
  { float g=sigf(p.y+q.y+bgv.y); o.y=cv.y*g+(1.f-g)*nw.y; }
  { float g=sigf(p.z+q.z+bgv.z); o.z=cv.z*g+(1.f-g)*nw.z; }
  { float g=sigf(p.w+q.w+bgv.w); o.w=cv.w*g+(1.f-g)*nw.w; }
  ((float4*)out)[idx]=o;
}

// ------- legacy dense iter-1 gate (fallback if ws too small) ----------------
__global__ void k_gate1(const float* __restrict__ ctxt, const float* __restrict__ Wg,
                        const float* __restrict__ Q, const float* __restrict__ lembuf,
                        const int* __restrict__ u2l, const unsigned int* __restrict__ flags,
                        const float* __restrict__ bg, float* __restrict__ out){
  __shared__ __align__(16) float As[64][SZ];
  __shared__ __align__(16) float Ws[64][SZ];
  __shared__ int lem_s[64];
  int r0=blockIdx.x*64, tid=threadIdx.x;
  for(int i=tid;i<64*SZ;i+=256){int lr=i>>8,j=i&(SZ-1);
    As[lr][j]=ctxt[(long)(r0+lr)*SZ+j];}
  if(tid<64){int r=r0+tid; lem_s[tid]=u2l[r%NW];}
  int cl=tid&63, rg=tid>>6;
  float acc[16][4];
  #pragma unroll
  for(int i=0;i<16;i++){acc[i][0]=acc[i][1]=acc[i][2]=acc[i][3]=0.f;}
  for(int kb=0;kb<4;kb++){
    __syncthreads();
    for(int i=tid;i<64*SZ;i+=256){int lr=i>>8,j=i&(SZ-1);
      Ws[lr][j]=Wg[(long)(kb*64+lr)*SZ+j];}
    __syncthreads();
    for(int k=0;k<64;k+=4){
      float4 a4[16];
      #pragma unroll
      for(int i=0;i<16;i++) a4[i]=*(const float4*)&As[rg*16+i][kb*64+k];
      #pragma unroll
      for(int j=0;j<4;j++){
        float w0=Ws[k+j][cl],w1=Ws[k+j][cl+64],w2=Ws[k+j][cl+128],w3=Ws[k+j][cl+192];
        #pragma unroll
        for(int i=0;i<16;i++){
          float a=(j==0)?a4[i].x:(j==1)?a4[i].y:(j==2)?a4[i].z:a4[i].w;
          acc[i][0]=fmaf(a,w0,acc[i][0]);acc[i][1]=fmaf(a,w1,acc[i][1]);
          acc[i][2]=fmaf(a,w2,acc[i][2]);acc[i][3]=fmaf(a,w3,acc[i][3]);
        }
      }
    }
  }
  #pragma unroll
  for(int i=0;i<16;i++){
    int lr=rg*16+i, r=r0+lr, b=r/NW;
    long base=((long)b*NLEM+lem_s[lr])*SZ;
    unsigned int fl=flags[(long)b*NLEM+lem_s[lr]];
    #pragma unroll
    for(int cc=0;cc<4;cc++){
      int col=cl+cc*64;
      float qv=0.f, nw=0.f;
      if(fl){ qv=Q[base+col]; nw=lembuf[base+col]; }
      float g=sigf(acc[i][cc]+qv+bg[col]);
      out[(long)r*SZ+col]=As[lr][col]*g+(1.f-g)*nw;
    }
  }
}

extern "C" void kernel_launch(void* const* d_in, const int* in_sizes, int n_in,
                              void* d_out, int out_size, void* d_ws, size_t ws_size,
                              hipStream_t stream){
  const float* emb  =(const float*)d_in[0];
  const float* Wp   =(const float*)d_in[1];
  const float* bp   =(const float*)d_in[2];
  const float* Wi_f =(const float*)d_in[3];
  const float* Wh_f =(const float*)d_in[4];
  const float* b_f  =(const float*)d_in[5];
  const float* Wi_b =(const float*)d_in[6];
  const float* Wh_b =(const float*)d_in[7];
  const float* b_b  =(const float*)d_in[8];
  const float* Wenc =(const float*)d_in[9];
  const float* benc =(const float*)d_in[10];
  const float* Wg   =(const float*)d_in[11];
  const float* bg   =(const float*)d_in[12];
  const int*   seq0 =(const int*)d_in[13];
  const int*   seq1 =(const int*)d_in[14];
  const int*   len0 =(const int*)d_in[15];
  const int*   len1 =(const int*)d_in[16];
  const int*   u2l  =(const int*)d_in[17];

  float* ws    = (float*)d_ws;
  float* we    = ws;                       // 2,560,000
  float* xwi   = we    + 2560000;          // 4,194,304 floats (xq uses 8 MB as shorts)
  float* hglob = xwi   + 4194304;          // 1,048,576
  float* lembuf= hglob + 1048576;          // 12,288,000
  float* flags = lembuf+ 12288000;         // 48,000 (uint)
  float* Q     = flags + 48000;            // 12,288,000
  float* P0    = Q     + 12288000;         // 2,560,000 (becomes P1base)
  short* whb   = (short*)(P0 + 2560000);   // 524,288 shorts = 262,144 floats
  short* hx    = (short*)(P0 + 2560000 + 262144);  // 16,384 shorts = 8,192 floats
  int*   ctr   = (int*)(P0 + 2560000 + 262144 + 8192);  // 256 ints
  int*   idxmap= ctr + 256;                // 160,000
  int*   list  = idxmap + 160000;          // NCAPMAX
  int*   cnt   = list + NCAPMAX;           // 1 (+3 pad)
  float* Ptouch= (float*)(cnt + 4);        // up to NCAPMAX*256
  long base_floats = (long)(Ptouch - ws);
  long avail = ((long)(ws_size/4) - base_floats)/SZ;
  int ncap = (int)(avail > NCAPMAX ? NCAPMAX : (avail<0?0:avail));
  int sparse_ok = (ncap >= 16384);
  float* out   = (float*)d_out;

  k_we<<<NW/16,256,0,stream>>>(emb,Wp,bp,we);
  k_rowgemm<<<NW/16,256,0,stream>>>(we,Wg,P0,nullptr);            // P0 = we@Wg1
  k_prep<<<256,256,0,stream>>>(Wh_f,Wh_b,whb);

  const int* seqs[2]={seq0,seq1};
  const int* lens[2]={len0,len1};
  for(int i=0;i<2;i++){
    hipMemsetAsync(lembuf,0,(size_t)(12288000+48000)*4,stream);   // lembuf + flags
    hipMemsetAsync(ctr,0,256*4,stream);                           // step counters
    const float* src = (i==0)? we : out;
    long bstride     = (i==0)? 0L : (long)NW*SZ;
    dim3 gx(64,4);
    k_xwi<<<gx,256,0,stream>>>(seqs[i],lens[i],src,bstride,Wi_f,b_f,Wi_b,b_b,i,(short*)xwi);
    k_lstm_sync<<<8,256,0,stream>>>(whb,(const short*)xwi,hglob,hx,ctr);
    k_enc<<<BB*LL/16,256,0,stream>>>(seqs[i],lens[i],u2l,hglob,Wenc,benc,
                                     (unsigned int*)lembuf,(unsigned int*)flags);
    k_rowgemm<<<BB*NLEM/16,256,0,stream>>>(lembuf,Wg+(long)SZ*SZ,Q,
                                           (const unsigned int*)flags); // Q = nw@Wg2
    if(i==0){
      long nb=((long)BB*NW*SZ/4+255)/256;
      k_gate0<<<(int)nb,256,0,stream>>>(we,P0,Q,lembuf,u2l,
                                        (const unsigned int*)flags,bg,out);
      if(sparse_ok){
        hipMemsetAsync(cnt,0,4,stream);
        k_compact<<<(BB*NW+255)/256,256,0,stream>>>(u2l,(const unsigned int*)flags,
                                                    cnt,list,idxmap,ncap);
        k_ptouch<<<(ncap+15)/16,256,0,stream>>>(out,Wg,cnt,list,Ptouch);
        k_p1base<<<NW/16,256,0,stream>>>(we,P0,bg,Wg);   // P0 <- C0@Wg1
      }
    }else{
      if(sparse_ok){
        long nb=((long)BB*NW*SZ/4+255)/256;
        k_gate1e<<<(int)nb,256,0,stream>>>(P0,Ptouch,idxmap,Q,lembuf,u2l,
                                           (const unsigned int*)flags,bg,out);
      }else{
        k_gate1<<<BB*NW/64,256,0,stream>>>(out,Wg,Q,lembuf,u2l,
                                           (const unsigned int*)flags,bg,out);
      }
    }
  }
}

// Round 9
// 1513.618 us; speedup vs baseline: 5.1244x; 1.2638x over previous
//
#include <hip/hip_runtime.h>

#define NW    10000
#define INDIM 300
#define SZ    256
#define BB    16
#define LL    128
#define NLEM  3000
#define FH    1024   // 4*SZ
#define NCAPMAX 32768

typedef short  bf16x8 __attribute__((ext_vector_type(8)));
typedef float  f32x4  __attribute__((ext_vector_type(4)));

__device__ __forceinline__ float sigf(float x){
  return __builtin_amdgcn_rcpf(1.f+__builtin_amdgcn_exp2f(-1.442695041f*x));
}
__device__ __forceinline__ float tanhf_(float x){
  return fmaf(-2.f, __builtin_amdgcn_rcpf(1.f+__builtin_amdgcn_exp2f(2.885390082f*x)), 1.f);
}
__device__ __forceinline__ short f2b(float f){
  unsigned u=__float_as_uint(f); u += 0x7FFFu + ((u>>16)&1u); return (short)(u>>16);
}
#define B2F(s) __uint_as_float(((unsigned)(unsigned short)(s))<<16)

// ---------------- we = relu(emb @ Wp + bp) : [10000,300]@[300,256] ----------
__global__ void k_we(const float* __restrict__ emb, const float* __restrict__ Wp,
                     const float* __restrict__ bp, float* __restrict__ we){
  __shared__ __align__(16) float As[16][INDIM];
  int r0 = blockIdx.x*16, tid = threadIdx.x;
  for(int i=tid;i<16*INDIM;i+=256){int lr=i/INDIM,d=i-lr*INDIM;
    As[lr][d]=emb[(long)(r0+lr)*INDIM+d];}
  __syncthreads();
  int cl=tid&63, rg=tid>>6;
  float acc[4][4];
  #pragma unroll
  for(int i=0;i<4;i++){acc[i][0]=acc[i][1]=acc[i][2]=acc[i][3]=0.f;}
  for(int k=0;k<INDIM;k+=4){
    float4 a4[4];
    #pragma unroll
    for(int i=0;i<4;i++) a4[i]=*(const float4*)&As[rg*4+i][k];
    #pragma unroll
    for(int j=0;j<4;j++){
      const float* wr=Wp+(long)(k+j)*SZ+cl;
      float w0=wr[0],w1=wr[64],w2=wr[128],w3=wr[192];
      #pragma unroll
      for(int i=0;i<4;i++){
        float a=(j==0)?a4[i].x:(j==1)?a4[i].y:(j==2)?a4[i].z:a4[i].w;
        acc[i][0]=fmaf(a,w0,acc[i][0]);acc[i][1]=fmaf(a,w1,acc[i][1]);
        acc[i][2]=fmaf(a,w2,acc[i][2]);acc[i][3]=fmaf(a,w3,acc[i][3]);
      }
    }
  }
  #pragma unroll
  for(int i=0;i<4;i++){
    int r=r0+rg*4+i;
    #pragma unroll
    for(int cc=0;cc<4;cc++){int col=cl+cc*64;
      we[(long)r*SZ+col]=fmaxf(acc[i][cc]+bp[col],0.f);}
  }
}

// ---- xwi (bf16): sidx = (((dir*128+t)*8 + w)*64 + lane)*32 + s*16 + g*4 + r
//   col=g*256+unit ; unit=w*32+s*16+nl ; lane=(b>>2)*16+nl ; r=b&3
__global__ void k_xwi(const int* __restrict__ seq, const int* __restrict__ len,
                      const float* __restrict__ src, long bstride,
                      const float* __restrict__ Wi_f, const float* __restrict__ bvf,
                      const float* __restrict__ Wi_b, const float* __restrict__ bvb,
                      int iseq, short* __restrict__ xwo){
  __shared__ __align__(16) float As[64][SZ];
  __shared__ const float* rowp[64];
  int r0=blockIdx.x*64, cb=blockIdx.y, tid=threadIdx.x;
  int dir=r0>>11;
  if(tid<64){
    int grow=r0+tid;
    int t=(grow>>4)&(LL-1), b=grow&(BB-1);
    int lb=len[b];
    int tt=(dir==0)? t : ((t<lb)? (lb-1-t) : t);
    int tok=seq[b*LL+tt];
    rowp[tid]=src + (long)b*bstride + (long)tok*SZ;
  }
  __syncthreads();
  for(int i=tid;i<64*SZ;i+=256){int lr=i>>8,j=i&(SZ-1);As[lr][j]=rowp[lr][j];}
  __syncthreads();
  const float* __restrict__ Wi = dir? Wi_b : Wi_f;
  const float* __restrict__ bv = dir? bvb : bvf;
  int cl=tid&63, rg=tid>>6, c0=cb*256+cl;
  float acc[16][4];
  #pragma unroll
  for(int i=0;i<16;i++){acc[i][0]=acc[i][1]=acc[i][2]=acc[i][3]=0.f;}
  for(int k=0;k<SZ;k+=4){
    float4 a4[16];
    #pragma unroll
    for(int i=0;i<16;i++) a4[i]=*(const float4*)&As[rg*16+i][k];
    #pragma unroll
    for(int j=0;j<4;j++){
      const float* wr=Wi+(long)(k+j)*FH+c0;
      float w0=wr[0],w1=wr[64],w2=wr[128],w3=wr[192];
      #pragma unroll
      for(int i=0;i<16;i++){
        float a=(j==0)?a4[i].x:(j==1)?a4[i].y:(j==2)?a4[i].z:a4[i].w;
        acc[i][0]=fmaf(a,w0,acc[i][0]);acc[i][1]=fmaf(a,w1,acc[i][1]);
        acc[i][2]=fmaf(a,w2,acc[i][2]);acc[i][3]=fmaf(a,w3,acc[i][3]);
      }
    }
  }
  #pragma unroll
  for(int cc=0;cc<4;cc++){
    int cx=c0+cc*64;
    float be=Wi[(long)(SZ+iseq)*FH+cx]+bv[cx];
    int g=cx>>8, unit=cx&255, w2=unit>>5, s2=(unit>>4)&1, nl=unit&15;
    #pragma unroll
    for(int i=0;i<16;i++){
      int grow=r0+rg*16+i;
      int b=grow&15, t=(grow>>4)&127, d2=grow>>11;
      long sidx=((((long)d2*128+t)*8 + w2)*64 + (b>>2)*16+nl)*32 + s2*16 + g*4 + (b&3);
      xwo[sidx]=f2b(acc[i][cc]+be);
    }
  }
}

// ---- prep: Wh -> bf16 MFMA B-fragments, (dir,w,T2=s*4+g,ks,lane) tiling ----
__global__ void k_prep(const float* __restrict__ Wh_f, const float* __restrict__ Wh_b,
                       short* __restrict__ frag){
  int tid = blockIdx.x*256 + threadIdx.x;   // 65536 total
  int l=tid&63, f=(tid>>6)&63, w=(tid>>12)&7, dir=tid>>15;
  const float* Wh = dir? Wh_b : Wh_f;
  int ks=f&7, T2=f>>3, s2=T2>>2, g=T2&3;
  int col = g*256 + w*32 + s2*16 + (l&15);
  int k0  = ks*32 + (l>>4)*8;
  short v[8];
  #pragma unroll
  for(int j=0;j<8;j++) v[j]=f2b(Wh[(long)(k0+j)*FH + col]);
  *(bf16x8*)(frag + (long)tid*8) = *(bf16x8*)v;
}

// --------- single-CU-per-dir persistent LSTM: 512 thr, 8 waves, 2/SIMD ------
// Per wave: 32 units (8 col-tiles). Weights: 32 frags VGPR + 16 LDS + 16
// streamed from a 128KB L2-resident window each step. h via LDS + 1 barrier.
#define MFA(a,b,c) __builtin_amdgcn_mfma_f32_16x16x32_bf16(a,b,c,0,0,0)
#define LDFW(f)    (*(const bf16x8*)(fr + (long)(f)*512 + l*8))
#define LDLW(i2,ks) (*(const bf16x8*)(bl + ((i2)*8+(ks))*512 + l*8))
#define DECLWT(T) bf16x8 W##T##_0=LDFW((T)*8+0),W##T##_1=LDFW((T)*8+1),W##T##_2=LDFW((T)*8+2),W##T##_3=LDFW((T)*8+3),W##T##_4=LDFW((T)*8+4),W##T##_5=LDFW((T)*8+5),W##T##_6=LDFW((T)*8+6),W##T##_7=LDFW((T)*8+7);
#define MMRT(T,Cv) { Cv=MFA(A0,W##T##_0,Cv); Cv=MFA(A1,W##T##_1,Cv); Cv=MFA(A2,W##T##_2,Cv); Cv=MFA(A3,W##T##_3,Cv); Cv=MFA(A4,W##T##_4,Cv); Cv=MFA(A5,W##T##_5,Cv); Cv=MFA(A6,W##T##_6,Cv); Cv=MFA(A7,W##T##_7,Cv); }
#define MMLT(i2,Cv) { Cv=MFA(A0,LDLW(i2,0),Cv); Cv=MFA(A1,LDLW(i2,1),Cv); Cv=MFA(A2,LDLW(i2,2),Cv); Cv=MFA(A3,LDLW(i2,3),Cv); Cv=MFA(A4,LDLW(i2,4),Cv); Cv=MFA(A5,LDLW(i2,5),Cv); Cv=MFA(A6,LDLW(i2,6),Cv); Cv=MFA(A7,LDLW(i2,7),Cv); }
#define MMST(Cv) { Cv=MFA(A0,S0,Cv); Cv=MFA(A1,S1,Cv); Cv=MFA(A2,S2,Cv); Cv=MFA(A3,S3,Cv); Cv=MFA(A4,S4,Cv); Cv=MFA(A5,S5,Cv); Cv=MFA(A6,S6,Cv); Cv=MFA(A7,S7,Cv); }
#define LOADST(f0) S0=LDFW((f0)+0); S1=LDFW((f0)+1); S2=LDFW((f0)+2); S3=LDFW((f0)+3); S4=LDFW((f0)+4); S5=LDFW((f0)+5); S6=LDFW((f0)+6); S7=LDFW((f0)+7);
#define G1(s,r,CA,CB,CC,CD,XA,XB) { \
  float zi=CA[r]+B2F(XA[r]), zf=CB[r]+B2F(XA[4+(r)]), zg=CC[r]+B2F(XB[r]), zo=CD[r]+B2F(XB[4+(r)]); \
  cst_##s##_##r = sigf(zf)*cst_##s##_##r + sigf(zi)*tanhf_(zg); \
  float hv = sigf(zo)*tanhf_(cst_##s##_##r); \
  int b_=4*(l>>4)+(r); int u_=w*32+(s)*16+(l&15); \
  hbn[b_*264+u_]=f2b(hv); \
  hg[((long)t*16+b_)*256+u_]=hv; }
#define GP(s,CA,CB,CC,CD,XA,XB) \
  G1(s,0,CA,CB,CC,CD,XA,XB) G1(s,1,CA,CB,CC,CD,XA,XB) \
  G1(s,2,CA,CB,CC,CD,XA,XB) G1(s,3,CA,CB,CC,CD,XA,XB)

extern __shared__ char smem_raw[];

__global__ __launch_bounds__(512,2) void k_lstm_w8(
    const short* __restrict__ frag, const short* __restrict__ xq,
    float* __restrict__ hglob){
  const int dir=blockIdx.x, tid=threadIdx.x, w=tid>>6, l=tid&63;
  short* hb=(short*)smem_raw;                      // 2 x 16 x 264 shorts
  short* bl=(short*)(smem_raw+16896)+w*8192;       // per-wave LDS frags T2=4,5
  const short* fr = frag + (long)(dir*8+w)*32768;  // 64 frags * 512
  for(int i=tid;i<4224;i+=512) ((int*)smem_raw)[i]=0;
  #pragma unroll
  for(int c2=0;c2<16;c2++)
    *(f32x4*)(bl+c2*512+l*8) = *(const f32x4*)(fr+(long)(32+c2)*512+l*8);
  DECLWT(0) DECLWT(1) DECLWT(2) DECLWT(3)          // 32 resident frags
  float cst_0_0=0,cst_0_1=0,cst_0_2=0,cst_0_3=0,
        cst_1_0=0,cst_1_1=0,cst_1_2=0,cst_1_3=0;
  __syncthreads();
  const short* xwb = xq + ((long)dir*128*8 + w)*2048 + (long)l*32;
  float* hg = hglob + (long)dir*524288;
  bf16x8 S0,S1,S2,S3,S4,S5,S6,S7;
  for(int t=0;t<LL;t++){
    const int cur=t&1, nxt=cur^1;
    LOADST(48)                                     // stream T2=6 (early issue)
    const short* xp = xwb + (long)t*16384;
    bf16x8 X0=*(const bf16x8*)(xp+0), X1=*(const bf16x8*)(xp+8);
    const short* hr = hb + cur*4224 + (l&15)*264 + (l>>4)*8;
    bf16x8 A0=*(const bf16x8*)(hr+0),   A1=*(const bf16x8*)(hr+32),
           A2=*(const bf16x8*)(hr+64),  A3=*(const bf16x8*)(hr+96),
           A4=*(const bf16x8*)(hr+128), A5=*(const bf16x8*)(hr+160),
           A6=*(const bf16x8*)(hr+192), A7=*(const bf16x8*)(hr+224);
    f32x4 Z={0.f,0.f,0.f,0.f};
    f32x4 C00=Z,C01=Z,C02=Z,C03=Z,C10=Z,C11=Z,C12=Z,C13=Z;
    MMRT(0,C00) MMRT(1,C01) MMRT(2,C02) MMRT(3,C03)   // resident (32 MFMA)
    MMLT(0,C10) MMLT(1,C11)                           // LDS tiles (16 MFMA)
    MMST(C12)                                         // T2=6 streamed
    LOADST(56)                                        // stream T2=7 (issue)
    bf16x8 X2=*(const bf16x8*)(xp+16), X3=*(const bf16x8*)(xp+24);
    short* hbn = hb + nxt*4224;
    GP(0, C00,C01,C02,C03, X0,X1)                     // hides T2=7 latency
    MMST(C13)                                         // T2=7 streamed
    GP(1, C10,C11,C12,C13, X2,X3)
    __syncthreads();
  }
}

// ---- enc = [hf|hb] @ Wenc + benc, relu(max) scatter into lembuf + flags ----
__global__ void k_enc(const int* __restrict__ seq, const int* __restrict__ len,
                      const int* __restrict__ u2l, const float* __restrict__ hglob,
                      const float* __restrict__ Wenc, const float* __restrict__ benc,
                      unsigned int* __restrict__ lembuf, unsigned int* __restrict__ flags){
  __shared__ __align__(16) float As[16][2*SZ];
  __shared__ const float* pf16[16]; __shared__ const float* pb16[16];
  __shared__ int lem_s[16], val_s[16], b_s[16];
  int r0=blockIdx.x*16, tid=threadIdx.x;
  if(tid<16){
    int r=r0+tid, b=r>>7, t=r&127, lb=len[b];
    int v=(t<lb); val_s[tid]=v; b_s[tid]=b;
    int lem=u2l[seq[r]];
    lem_s[tid]=lem;
    pf16[tid]=hglob+((long)t*BB+b)*SZ;
    int tr=v? (lb-1-t) : t;
    pb16[tid]=hglob+((long)(LL+tr)*BB+b)*SZ;
    if(v) flags[(long)b*NLEM+lem]=1u;
  }
  __syncthreads();
  for(int i=tid;i<16*SZ;i+=256){int lr=i>>8,j=i&(SZ-1);
    As[lr][j]=pf16[lr][j]; As[lr][SZ+j]=pb16[lr][j];}
  __syncthreads();
  int cl=tid&63, rg=tid>>6;
  float acc[4][4];
  #pragma unroll
  for(int i=0;i<4;i++){acc[i][0]=acc[i][1]=acc[i][2]=acc[i][3]=0.f;}
  for(int k=0;k<2*SZ;k+=4){
    float4 a4[4];
    #pragma unroll
    for(int i=0;i<4;i++) a4[i]=*(const float4*)&As[rg*4+i][k];
    #pragma unroll
    for(int j=0;j<4;j++){
      const float* wr=Wenc+(long)(k+j)*SZ+cl;
      float w0=wr[0],w1=wr[64],w2=wr[128],w3=wr[192];
      #pragma unroll
      for(int i=0;i<4;i++){
        float a=(j==0)?a4[i].x:(j==1)?a4[i].y:(j==2)?a4[i].z:a4[i].w;
        acc[i][0]=fmaf(a,w0,acc[i][0]);acc[i][1]=fmaf(a,w1,acc[i][1]);
        acc[i][2]=fmaf(a,w2,acc[i][2]);acc[i][3]=fmaf(a,w3,acc[i][3]);
      }
    }
  }
  #pragma unroll
  for(int i=0;i<4;i++){
    int lr=rg*4+i;
    if(val_s[lr]){
      long base=((long)b_s[lr]*NLEM+lem_s[lr])*SZ;
      #pragma unroll
      for(int cc=0;cc<4;cc++){
        int col=cl+cc*64;
        float e=fmaxf(acc[i][cc]+benc[col],0.f);
        atomicMax(&lembuf[base+col], __float_as_uint(e));
      }
    }
  }
}

// ------------ generic C[r] = A[r] @ W  (K=256), optional touched-flags ------
__global__ void k_rowgemm(const float* __restrict__ A, const float* __restrict__ W,
                          float* __restrict__ C, const unsigned int* __restrict__ flags){
  __shared__ __align__(16) float As[16][SZ];
  __shared__ int any_s;
  int r0=blockIdx.x*16, tid=threadIdx.x;
  if(tid==0){
    int a = flags? 0 : 1;
    if(flags){ for(int i=0;i<16;i++) a |= (int)flags[r0+i]; }
    any_s=a;
  }
  __syncthreads();
  if(!any_s) return;
  for(int i=tid;i<16*SZ;i+=256){int lr=i>>8,j=i&(SZ-1);As[lr][j]=A[(long)(r0+lr)*SZ+j];}
  __syncthreads();
  int cl=tid&63, rg=tid>>6;
  float acc[4][4];
  #pragma unroll
  for(int i=0;i<4;i++){acc[i][0]=acc[i][1]=acc[i][2]=acc[i][3]=0.f;}
  for(int k=0;k<SZ;k+=4){
    float4 a4[4];
    #pragma unroll
    for(int i=0;i<4;i++) a4[i]=*(const float4*)&As[rg*4+i][k];
    #pragma unroll
    for(int j=0;j<4;j++){
      const float* wr=W+(long)(k+j)*SZ+cl;
      float w0=wr[0],w1=wr[64],w2=wr[128],w3=wr[192];
      #pragma unroll
      for(int i=0;i<4;i++){
        float a=(j==0)?a4[i].x:(j==1)?a4[i].y:(j==2)?a4[i].z:a4[i].w;
        acc[i][0]=fmaf(a,w0,acc[i][0]);acc[i][1]=fmaf(a,w1,acc[i][1]);
        acc[i][2]=fmaf(a,w2,acc[i][2]);acc[i][3]=fmaf(a,w3,acc[i][3]);
      }
    }
  }
  #pragma unroll
  for(int i=0;i<4;i++){
    int r=r0+rg*4+i;
    #pragma unroll
    for(int cc=0;cc<4;cc++) C[(long)r*SZ+cl+cc*64]=acc[i][cc];
  }
}

// ---- P1base: A=we*sig(P0+bg) staged on the fly; result overwrites P0 -------
__global__ void k_p1base(const float* __restrict__ we, float* __restrict__ P0,
                         const float* __restrict__ bg, const float* __restrict__ W){
  __shared__ __align__(16) float As[16][SZ];
  int r0=blockIdx.x*16, tid=threadIdx.x;
  for(int i=tid;i<16*SZ;i+=256){int lr=i>>8,j=i&(SZ-1);
    long off=(long)(r0+lr)*SZ+j;
    As[lr][j]=we[off]*sigf(P0[off]+bg[j]);}
  __syncthreads();
  int cl=tid&63, rg=tid>>6;
  float acc[4][4];
  #pragma unroll
  for(int i=0;i<4;i++){acc[i][0]=acc[i][1]=acc[i][2]=acc[i][3]=0.f;}
  for(int k=0;k<SZ;k+=4){
    float4 a4[4];
    #pragma unroll
    for(int i=0;i<4;i++) a4[i]=*(const float4*)&As[rg*4+i][k];
    #pragma unroll
    for(int j=0;j<4;j++){
      const float* wr=W+(long)(k+j)*SZ+cl;
      float w0=wr[0],w1=wr[64],w2=wr[128],w3=wr[192];
      #pragma unroll
      for(int i=0;i<4;i++){
        float a=(j==0)?a4[i].x:(j==1)?a4[i].y:(j==2)?a4[i].z:a4[i].w;
        acc[i][0]=fmaf(a,w0,acc[i][0]);acc[i][1]=fmaf(a,w1,acc[i][1]);
        acc[i][2]=fmaf(a,w2,acc[i][2]);acc[i][3]=fmaf(a,w3,acc[i][3]);
      }
    }
  }
  #pragma unroll
  for(int i=0;i<4;i++){
    int r=r0+rg*4+i;
    #pragma unroll
    for(int cc=0;cc<4;cc++) P0[(long)r*SZ+cl+cc*64]=acc[i][cc];
  }
}

// ---- compact list of rows whose lemma was touched in iter 0 ----------------
__global__ void k_compact(const int* __restrict__ u2l, const unsigned int* __restrict__ flags,
                          int* __restrict__ cnt, int* __restrict__ list,
                          int* __restrict__ idxmap, int ncap){
  int r = blockIdx.x*256+threadIdx.x;
  if(r>=BB*NW) return;
  int b=r/NW, w=r-b*NW;
  int im=-1;
  if(flags[(long)b*NLEM+u2l[w]]){
    int idx=atomicAdd(cnt,1);
    if(idx<ncap){ list[idx]=r; im=idx; }
  }
  idxmap[r]=im;
}

// ---- Ptouch[i] = out[list[i]] @ Wg1 over the compacted rows ----------------
__global__ void k_ptouch(const float* __restrict__ out, const float* __restrict__ W,
                         const int* __restrict__ cnt, const int* __restrict__ list,
                         float* __restrict__ Pt){
  __shared__ __align__(16) float As[16][SZ];
  __shared__ const float* rp[16];
  int n=*cnt;
  int r0=blockIdx.x*16, tid=threadIdx.x;
  if(r0>=n) return;
  if(tid<16){
    int idx=r0+tid;
    rp[tid]=(idx<n)? out+(long)list[idx]*SZ : nullptr;
  }
  __syncthreads();
  for(int i=tid;i<16*SZ;i+=256){int lr=i>>8,j=i&(SZ-1);
    As[lr][j]= rp[lr]? rp[lr][j] : 0.f;}
  __syncthreads();
  int cl=tid&63, rg=tid>>6;
  float acc[4][4];
  #pragma unroll
  for(int i=0;i<4;i++){acc[i][0]=acc[i][1]=acc[i][2]=acc[i][3]=0.f;}
  for(int k=0;k<SZ;k+=4){
    float4 a4[4];
    #pragma unroll
    for(int i=0;i<4;i++) a4[i]=*(const float4*)&As[rg*4+i][k];
    #pragma unroll
    for(int j=0;j<4;j++){
      const float* wr=W+(long)(k+j)*SZ+cl;
      float w0=wr[0],w1=wr[64],w2=wr[128],w3=wr[192];
      #pragma unroll
      for(int i=0;i<4;i++){
        float a=(j==0)?a4[i].x:(j==1)?a4[i].y:(j==2)?a4[i].z:a4[i].w;
        acc[i][0]=fmaf(a,w0,acc[i][0]);acc[i][1]=fmaf(a,w1,acc[i][1]);
        acc[i][2]=fmaf(a,w2,acc[i][2]);acc[i][3]=fmaf(a,w3,acc[i][3]);
      }
    }
  }
  #pragma unroll
  for(int i=0;i<4;i++){
    int idx=r0+rg*4+i;
    if(idx<n){
      #pragma unroll
      for(int cc=0;cc<4;cc++) Pt[(long)idx*SZ+cl+cc*64]=acc[i][cc];
    }
  }
}

// ------- iter-0 gate: ctxt==tile(we) -> pure elementwise from P0/Q ----------
__global__ void k_gate0(const float* __restrict__ we, const float* __restrict__ P0,
                        const float* __restrict__ Q, const float* __restrict__ lembuf,
                        const int* __restrict__ u2l, const unsigned int* __restrict__ flags,
                        const float* __restrict__ bg, float* __restrict__ out){
  long idx=(long)blockIdx.x*256+threadIdx.x;
  const long TOTAL4=(long)BB*NW*SZ/4;
  if(idx>=TOTAL4) return;
  long row=idx>>6; int k4=(int)(idx&63);
  int r32=(int)row;
  int b=r32/NW, w=r32-b*NW;
  int lem=u2l[w];
  long qb=((long)b*NLEM+lem)*SZ;
  unsigned int fl=flags[(long)b*NLEM+lem];
  float4 p =((const float4*)(P0+(long)w*SZ))[k4];
  float4 wv=((const float4*)(we+(long)w*SZ))[k4];
  float4 bgv=((const float4*)bg)[k4];
  float4 q, nw;
  if(fl){ q=((const float4*)(Q+qb))[k4]; nw=((const float4*)(lembuf+qb))[k4]; }
  else  { q=make_float4(0.f,0.f,0.f,0.f); nw=q; }
  float4 o;
  { float g=sigf(p.x+q.x+bgv.x); o.x=wv.x*g+(1.f-g)*nw.x; }
  { float g=sigf(p.y+q.y+bgv.y); o.y=wv.y*g+(1.f-g)*nw.y; }
  { float g=sigf(p.z+q.z+bgv.z); o.z=wv.z*g+(1.f-g)*nw.z; }
  { float g=sigf(p.w+q.w+bgv.w); o.w=wv.w*g+(1.f-g)*nw.w; }
  ((float4*)out)[idx]=o;
}

// ------- iter-1 gate, elementwise: P from Ptouch (touched0) or P1base -------
__global__ void k_gate1e(const float* __restrict__ P1base, const float* __restrict__ Pt,
                         const int* __restrict__ idxmap,
                         const float* __restrict__ Q, const float* __restrict__ lembuf,
                         const int* __restrict__ u2l, const unsigned int* __restrict__ flags,
                         const float* __restrict__ bg, float* __restrict__ out){
  long idx=(long)blockIdx.x*256+threadIdx.x;
  const long TOTAL4=(long)BB*NW*SZ/4;
  if(idx>=TOTAL4) return;
  long row=idx>>6; int k4=(int)(idx&63);
  int r32=(int)row;
  int b=r32/NW, w=r32-b*NW;
  int im=idxmap[r32];
  int lem=u2l[w];
  long qb=((long)b*NLEM+lem)*SZ;
  unsigned int fl=flags[(long)b*NLEM+lem];
  float4 p = (im>=0)? ((const float4*)(Pt+(long)im*SZ))[k4]
                    : ((const float4*)(P1base+(long)w*SZ))[k4];
  float4 cv=((const float4*)(out+(long)row*SZ))[k4];
  float4 bgv=((const float4*)bg)[k4];
  float4 q, nw;
  if(fl){ q=((const float4*)(Q+qb))[k4]; nw=((const float4*)(lembuf+qb))[k4]; }
  else  { q=make_float4(0.f,0.f,0.f,0.f); nw=q; }
  float4 o;
  { float g=sigf(p.x+q.x+bgv.x); o.x=cv.x*g+(1.f-g)*nw.x; }
  { float g=sigf(p.y+q.y+bgv.y); o.y=cv.y*g+(1.f-g)*nw.y; }
  { float g=sigf(p.z+q.z+bgv.z); o.z=cv.z*g+(1.f-g)*nw.z; }
  { float g=sigf(p.w+q.w+bgv.w); o.w=cv.w*g+(1.f-g)*nw.w; }
  ((float4*)out)[idx]=o;
}

// ------- legacy dense iter-1 gate (fallback if ws too small) ----------------
__global__ void k_gate1(const float* __restrict__ ctxt, const float* __restrict__ Wg,
                        const float* __restrict__ Q, const float* __restrict__ lembuf,
                        const int* __restrict__ u2l, const unsigned int* __restrict__ flags,
                        const float* __restrict__ bg, float* __restrict__ out){
  __shared__ __align__(16) float As[64][SZ];
  __shared__ __align__(16) float Ws[64][SZ];
  __shared__ int lem_s[64];
  int r0=blockIdx.x*64, tid=threadIdx.x;
  for(int i=tid;i<64*SZ;i+=256){int lr=i>>8,j=i&(SZ-1);
    As[lr][j]=ctxt[(long)(r0+lr)*SZ+j];}
  if(tid<64){int r=r0+tid; lem_s[tid]=u2l[r%NW];}
  int cl=tid&63, rg=tid>>6;
  float acc[16][4];
  #pragma unroll
  for(int i=0;i<16;i++){acc[i][0]=acc[i][1]=acc[i][2]=acc[i][3]=0.f;}
  for(int kb=0;kb<4;kb++){
    __syncthreads();
    for(int i=tid;i<64*SZ;i+=256){int lr=i>>8,j=i&(SZ-1);
      Ws[lr][j]=Wg[(long)(kb*64+lr)*SZ+j];}
    __syncthreads();
    for(int k=0;k<64;k+=4){
      float4 a4[16];
      #pragma unroll
      for(int i=0;i<16;i++) a4[i]=*(const float4*)&As[rg*16+i][kb*64+k];
      #pragma unroll
      for(int j=0;j<4;j++){
        float w0=Ws[k+j][cl],w1=Ws[k+j][cl+64],w2=Ws[k+j][cl+128],w3=Ws[k+j][cl+192];
        #pragma unroll
        for(int i=0;i<16;i++){
          float a=(j==0)?a4[i].x:(j==1)?a4[i].y:(j==2)?a4[i].z:a4[i].w;
          acc[i][0]=fmaf(a,w0,acc[i][0]);acc[i][1]=fmaf(a,w1,acc[i][1]);
          acc[i][2]=fmaf(a,w2,acc[i][2]);acc[i][3]=fmaf(a,w3,acc[i][3]);
        }
      }
    }
  }
  #pragma unroll
  for(int i=0;i<16;i++){
    int lr=rg*16+i, r=r0+lr, b=r/NW;
    long base=((long)b*NLEM+lem_s[lr])*SZ;
    unsigned int fl=flags[(long)b*NLEM+lem_s[lr]];
    #pragma unroll
    for(int cc=0;cc<4;cc++){
      int col=cl+cc*64;
      float qv=0.f, nw=0.f;
      if(fl){ qv=Q[base+col]; nw=lembuf[base+col]; }
      float g=sigf(acc[i][cc]+qv+bg[col]);
      out[(long)r*SZ+col]=As[lr][col]*g+(1.f-g)*nw;
    }
  }
}

extern "C" void kernel_launch(void* const* d_in, const int* in_sizes, int n_in,
                              void* d_out, int out_size, void* d_ws, size_t ws_size,
                              hipStream_t stream){
  const float* emb  =(const float*)d_in[0];
  const float* Wp   =(const float*)d_in[1];
  const float* bp   =(const float*)d_in[2];
  const float* Wi_f =(const float*)d_in[3];
  const float* Wh_f =(const float*)d_in[4];
  const float* b_f  =(const float*)d_in[5];
  const float* Wi_b =(const float*)d_in[6];
  const float* Wh_b =(const float*)d_in[7];
  const float* b_b  =(const float*)d_in[8];
  const float* Wenc =(const float*)d_in[9];
  const float* benc =(const float*)d_in[10];
  const float* Wg   =(const float*)d_in[11];
  const float* bg   =(const float*)d_in[12];
  const int*   seq0 =(const int*)d_in[13];
  const int*   seq1 =(const int*)d_in[14];
  const int*   len0 =(const int*)d_in[15];
  const int*   len1 =(const int*)d_in[16];
  const int*   u2l  =(const int*)d_in[17];

  float* ws    = (float*)d_ws;
  float* we    = ws;                       // 2,560,000
  float* xwi   = we    + 2560000;          // 4,194,304 floats (xq bf16, 8 MB)
  float* hglob = xwi   + 4194304;          // 1,048,576
  float* lembuf= hglob + 1048576;          // 12,288,000
  float* flags = lembuf+ 12288000;         // 48,000 (uint)
  float* Q     = flags + 48000;            // 12,288,000
  float* P0    = Q     + 12288000;         // 2,560,000 (becomes P1base)
  short* whb   = (short*)(P0 + 2560000);   // 524,288 shorts = 262,144 floats
  int*   idxmap= (int*)(P0 + 2560000 + 262144 + 8192 + 256);   // 160,000
  int*   list  = idxmap + 160000;          // NCAPMAX
  int*   cnt   = list + NCAPMAX;           // 1 (+3 pad)
  float* Ptouch= (float*)(cnt + 4);        // up to NCAPMAX*256
  long base_floats = (long)(Ptouch - ws);
  long avail = ((long)(ws_size/4) - base_floats)/SZ;
  int ncap = (int)(avail > NCAPMAX ? NCAPMAX : (avail<0?0:avail));
  int sparse_ok = (ncap >= 16384);
  float* out   = (float*)d_out;

  hipFuncSetAttribute((const void*)k_lstm_w8,
                      hipFuncAttributeMaxDynamicSharedMemorySize, 147968);

  k_we<<<NW/16,256,0,stream>>>(emb,Wp,bp,we);
  k_rowgemm<<<NW/16,256,0,stream>>>(we,Wg,P0,nullptr);            // P0 = we@Wg1
  k_prep<<<256,256,0,stream>>>(Wh_f,Wh_b,whb);

  const int* seqs[2]={seq0,seq1};
  const int* lens[2]={len0,len1};
  for(int i=0;i<2;i++){
    hipMemsetAsync(lembuf,0,(size_t)(12288000+48000)*4,stream);   // lembuf + flags
    const float* src = (i==0)? we : out;
    long bstride     = (i==0)? 0L : (long)NW*SZ;
    dim3 gx(64,4);
    k_xwi<<<gx,256,0,stream>>>(seqs[i],lens[i],src,bstride,Wi_f,b_f,Wi_b,b_b,i,(short*)xwi);
    k_lstm_w8<<<2,512,147968,stream>>>(whb,(const short*)xwi,hglob);
    k_enc<<<BB*LL/16,256,0,stream>>>(seqs[i],lens[i],u2l,hglob,Wenc,benc,
                                     (unsigned int*)lembuf,(unsigned int*)flags);
    k_rowgemm<<<BB*NLEM/16,256,0,stream>>>(lembuf,Wg+(long)SZ*SZ,Q,
                                           (const unsigned int*)flags); // Q = nw@Wg2
    if(i==0){
      long nb=((long)BB*NW*SZ/4+255)/256;
      k_gate0<<<(int)nb,256,0,stream>>>(we,P0,Q,lembuf,u2l,
                                        (const unsigned int*)flags,bg,out);
      if(sparse_ok){
        hipMemsetAsync(cnt,0,4,stream);
        k_compact<<<(BB*NW+255)/256,256,0,stream>>>(u2l,(const unsigned int*)flags,
                                                    cnt,list,idxmap,ncap);
        k_ptouch<<<(ncap+15)/16,256,0,stream>>>(out,Wg,cnt,list,Ptouch);
        k_p1base<<<NW/16,256,0,stream>>>(we,P0,bg,Wg);   // P0 <- C0@Wg1
      }
    }else{
      if(sparse_ok){
        long nb=((long)BB*NW*SZ/4+255)/256;
        k_gate1e<<<(int)nb,256,0,stream>>>(P0,Ptouch,idxmap,Q,lembuf,u2l,
                                           (const unsigned int*)flags,bg,out);
      }else{
        k_gate1<<<BB*NW/64,256,0,stream>>>(out,Wg,Q,lembuf,u2l,
                                           (const unsigned int*)flags,bg,out);
      }
    }
  }
}

// Round 10
// 1391.545 us; speedup vs baseline: 5.5740x; 1.0877x over previous
//
#include <hip/hip_runtime.h>

#define NW    10000
#define INDIM 300
#define SZ    256
#define BB    16
#define LL    128
#define NLEM  3000
#define FH    1024   // 4*SZ
#define NCAP  8192

typedef short  bf16x8 __attribute__((ext_vector_type(8)));
typedef float  f32x4  __attribute__((ext_vector_type(4)));

__device__ __forceinline__ float sigf(float x){
  return __builtin_amdgcn_rcpf(1.f+__builtin_amdgcn_exp2f(-1.442695041f*x));
}
__device__ __forceinline__ float tanhf_(float x){
  return fmaf(-2.f, __builtin_amdgcn_rcpf(1.f+__builtin_amdgcn_exp2f(2.885390082f*x)), 1.f);
}
__device__ __forceinline__ short f2b(float f){
  unsigned u=__float_as_uint(f); u += 0x7FFFu + ((u>>16)&1u); return (short)(u>>16);
}
#define B2F(s) __uint_as_float(((unsigned)(unsigned short)(s))<<16)

// ---------------- we = relu(emb @ Wp + bp) : [10000,300]@[300,256] ----------
__global__ void k_we(const float* __restrict__ emb, const float* __restrict__ Wp,
                     const float* __restrict__ bp, float* __restrict__ we){
  __shared__ __align__(16) float As[16][INDIM];
  int r0 = blockIdx.x*16, tid = threadIdx.x;
  for(int i=tid;i<16*INDIM;i+=256){int lr=i/INDIM,d=i-lr*INDIM;
    As[lr][d]=emb[(long)(r0+lr)*INDIM+d];}
  __syncthreads();
  int cl=tid&63, rg=tid>>6;
  float acc[4][4];
  #pragma unroll
  for(int i=0;i<4;i++){acc[i][0]=acc[i][1]=acc[i][2]=acc[i][3]=0.f;}
  for(int k=0;k<INDIM;k+=4){
    float4 a4[4];
    #pragma unroll
    for(int i=0;i<4;i++) a4[i]=*(const float4*)&As[rg*4+i][k];
    #pragma unroll
    for(int j=0;j<4;j++){
      const float* wr=Wp+(long)(k+j)*SZ+cl;
      float w0=wr[0],w1=wr[64],w2=wr[128],w3=wr[192];
      #pragma unroll
      for(int i=0;i<4;i++){
        float a=(j==0)?a4[i].x:(j==1)?a4[i].y:(j==2)?a4[i].z:a4[i].w;
        acc[i][0]=fmaf(a,w0,acc[i][0]);acc[i][1]=fmaf(a,w1,acc[i][1]);
        acc[i][2]=fmaf(a,w2,acc[i][2]);acc[i][3]=fmaf(a,w3,acc[i][3]);
      }
    }
  }
  #pragma unroll
  for(int i=0;i<4;i++){
    int r=r0+rg*4+i;
    #pragma unroll
    for(int cc=0;cc<4;cc++){int col=cl+cc*64;
      we[(long)r*SZ+col]=fmaxf(acc[i][cc]+bp[col],0.f);}
  }
}

// ---- xwi (bf16): sidx = (((dir*128+t)*8 + w)*64 + lane)*32 + s*16 + g*4 + r
__global__ void k_xwi(const int* __restrict__ seq, const int* __restrict__ len,
                      const float* __restrict__ srcw, long bstride,
                      const float* __restrict__ ctxtT, const int* __restrict__ idxmap,
                      const float* __restrict__ Wi_f, const float* __restrict__ bvf,
                      const float* __restrict__ Wi_b, const float* __restrict__ bvb,
                      int iseq, short* __restrict__ xwo){
  __shared__ __align__(16) float As[64][SZ];
  __shared__ const float* rowp[64];
  int r0=blockIdx.x*64, cb=blockIdx.y, tid=threadIdx.x;
  int dir=r0>>11;
  if(tid<64){
    int grow=r0+tid;
    int t=(grow>>4)&(LL-1), b=grow&(BB-1);
    int lb=len[b];
    int tt=(dir==0)? t : ((t<lb)? (lb-1-t) : t);
    int tok=seq[b*LL+tt];
    const float* rp;
    if(idxmap){
      int im=idxmap[b*NW+tok];
      rp = (im>=0)? ctxtT+(long)im*SZ : srcw+(long)tok*SZ;
    }else{
      rp = srcw + (long)b*bstride + (long)tok*SZ;
    }
    rowp[tid]=rp;
  }
  __syncthreads();
  for(int i=tid;i<64*SZ;i+=256){int lr=i>>8,j=i&(SZ-1);As[lr][j]=rowp[lr][j];}
  __syncthreads();
  const float* __restrict__ Wi = dir? Wi_b : Wi_f;
  const float* __restrict__ bv = dir? bvb : bvf;
  int cl=tid&63, rg=tid>>6, c0=cb*256+cl;
  float acc[16][4];
  #pragma unroll
  for(int i=0;i<16;i++){acc[i][0]=acc[i][1]=acc[i][2]=acc[i][3]=0.f;}
  for(int k=0;k<SZ;k+=4){
    float4 a4[16];
    #pragma unroll
    for(int i=0;i<16;i++) a4[i]=*(const float4*)&As[rg*16+i][k];
    #pragma unroll
    for(int j=0;j<4;j++){
      const float* wr=Wi+(long)(k+j)*FH+c0;
      float w0=wr[0],w1=wr[64],w2=wr[128],w3=wr[192];
      #pragma unroll
      for(int i=0;i<16;i++){
        float a=(j==0)?a4[i].x:(j==1)?a4[i].y:(j==2)?a4[i].z:a4[i].w;
        acc[i][0]=fmaf(a,w0,acc[i][0]);acc[i][1]=fmaf(a,w1,acc[i][1]);
        acc[i][2]=fmaf(a,w2,acc[i][2]);acc[i][3]=fmaf(a,w3,acc[i][3]);
      }
    }
  }
  #pragma unroll
  for(int cc=0;cc<4;cc++){
    int cx=c0+cc*64;
    float be=Wi[(long)(SZ+iseq)*FH+cx]+bv[cx];
    int g=cx>>8, unit=cx&255, w2=unit>>5, s2=(unit>>4)&1, nl=unit&15;
    #pragma unroll
    for(int i=0;i<16;i++){
      int grow=r0+rg*16+i;
      int b=grow&15, t=(grow>>4)&127, d2=grow>>11;
      long sidx=((((long)d2*128+t)*8 + w2)*64 + (b>>2)*16+nl)*32 + s2*16 + g*4 + (b&3);
      xwo[sidx]=f2b(acc[i][cc]+be);
    }
  }
}

// ---- prep: Wh -> bf16 MFMA B-fragments, (dir,w,T2=s*4+g,ks,lane) tiling ----
__global__ void k_prep(const float* __restrict__ Wh_f, const float* __restrict__ Wh_b,
                       short* __restrict__ frag){
  int tid = blockIdx.x*256 + threadIdx.x;   // 65536 total
  int l=tid&63, f=(tid>>6)&63, w=(tid>>12)&7, dir=tid>>15;
  const float* Wh = dir? Wh_b : Wh_f;
  int ks=f&7, T2=f>>3, s2=T2>>2, g=T2&3;
  int col = g*256 + w*32 + s2*16 + (l&15);
  int k0  = ks*32 + (l>>4)*8;
  short v[8];
  #pragma unroll
  for(int j=0;j<8;j++) v[j]=f2b(Wh[(long)(k0+j)*FH + col]);
  *(bf16x8*)(frag + (long)tid*8) = *(bf16x8*)v;
}

// --------- single-CU-per-dir persistent LSTM: 512 thr, 8 waves, 2/SIMD ------
#define MFA(a,b,c) __builtin_amdgcn_mfma_f32_16x16x32_bf16(a,b,c,0,0,0)
#define LDFW(f)    (*(const bf16x8*)(fr + (long)(f)*512 + l*8))
#define LDLW(i2,ks) (*(const bf16x8*)(bl + ((i2)*8+(ks))*512 + l*8))
#define DECLWT(T) bf16x8 W##T##_0=LDFW((T)*8+0),W##T##_1=LDFW((T)*8+1),W##T##_2=LDFW((T)*8+2),W##T##_3=LDFW((T)*8+3),W##T##_4=LDFW((T)*8+4),W##T##_5=LDFW((T)*8+5),W##T##_6=LDFW((T)*8+6),W##T##_7=LDFW((T)*8+7);
#define MMRT(T,Cv) { Cv=MFA(A0,W##T##_0,Cv); Cv=MFA(A1,W##T##_1,Cv); Cv=MFA(A2,W##T##_2,Cv); Cv=MFA(A3,W##T##_3,Cv); Cv=MFA(A4,W##T##_4,Cv); Cv=MFA(A5,W##T##_5,Cv); Cv=MFA(A6,W##T##_6,Cv); Cv=MFA(A7,W##T##_7,Cv); }
#define MMLT(i2,Cv) { Cv=MFA(A0,LDLW(i2,0),Cv); Cv=MFA(A1,LDLW(i2,1),Cv); Cv=MFA(A2,LDLW(i2,2),Cv); Cv=MFA(A3,LDLW(i2,3),Cv); Cv=MFA(A4,LDLW(i2,4),Cv); Cv=MFA(A5,LDLW(i2,5),Cv); Cv=MFA(A6,LDLW(i2,6),Cv); Cv=MFA(A7,LDLW(i2,7),Cv); }
#define MMST(Cv) { Cv=MFA(A0,S0,Cv); Cv=MFA(A1,S1,Cv); Cv=MFA(A2,S2,Cv); Cv=MFA(A3,S3,Cv); Cv=MFA(A4,S4,Cv); Cv=MFA(A5,S5,Cv); Cv=MFA(A6,S6,Cv); Cv=MFA(A7,S7,Cv); }
#define LOADST(f0) S0=LDFW((f0)+0); S1=LDFW((f0)+1); S2=LDFW((f0)+2); S3=LDFW((f0)+3); S4=LDFW((f0)+4); S5=LDFW((f0)+5); S6=LDFW((f0)+6); S7=LDFW((f0)+7);
#define G1(s,r,CA,CB,CC,CD,XA,XB) { \
  float zi=CA[r]+B2F(XA[r]), zf=CB[r]+B2F(XA[4+(r)]), zg=CC[r]+B2F(XB[r]), zo=CD[r]+B2F(XB[4+(r)]); \
  cst_##s##_##r = sigf(zf)*cst_##s##_##r + sigf(zi)*tanhf_(zg); \
  float hv = sigf(zo)*tanhf_(cst_##s##_##r); \
  int b_=4*(l>>4)+(r); int u_=w*32+(s)*16+(l&15); \
  hbn[b_*264+u_]=f2b(hv); }
#define GP(s,CA,CB,CC,CD,XA,XB) \
  G1(s,0,CA,CB,CC,CD,XA,XB) G1(s,1,CA,CB,CC,CD,XA,XB) \
  G1(s,2,CA,CB,CC,CD,XA,XB) G1(s,3,CA,CB,CC,CD,XA,XB)

extern __shared__ char smem_raw[];

__global__ __launch_bounds__(512,2) void k_lstm_w8(
    const short* __restrict__ frag, const short* __restrict__ xq,
    short* __restrict__ hgs){
  const int dir=blockIdx.x, tid=threadIdx.x, w=tid>>6, l=tid&63;
  short* hb=(short*)smem_raw;                      // 2 x 16 x 264 shorts
  short* bl=(short*)(smem_raw+16896)+w*8192;       // per-wave LDS frags T2=4,5
  const short* fr = frag + (long)(dir*8+w)*32768;  // 64 frags * 512
  for(int i=tid;i<4224;i+=512) ((int*)smem_raw)[i]=0;
  #pragma unroll
  for(int c2=0;c2<16;c2++)
    *(f32x4*)(bl+c2*512+l*8) = *(const f32x4*)(fr+(long)(32+c2)*512+l*8);
  DECLWT(0) DECLWT(1) DECLWT(2) DECLWT(3)          // 32 resident frags
  float cst_0_0=0,cst_0_1=0,cst_0_2=0,cst_0_3=0,
        cst_1_0=0,cst_1_1=0,cst_1_2=0,cst_1_3=0;
  __syncthreads();
  const short* xwb = xq + ((long)dir*128*8 + w)*2048 + (long)l*32;
  short* hgb = hgs + (long)dir*524288;             // bf16 h-out [t][16][256]
  const int db=tid>>5, du=(tid&31)*8;              // dump coords
  bf16x8 S0,S1,S2,S3,S4,S5,S6,S7;
  for(int t=0;t<LL;t++){
    const int cur=t&1, nxt=cur^1;
    LOADST(48)                                     // stream T2=6 (early issue)
    const short* xp = xwb + (long)t*16384;
    bf16x8 X0=*(const bf16x8*)(xp+0), X1=*(const bf16x8*)(xp+8);
    const short* hr = hb + cur*4224 + (l&15)*264 + (l>>4)*8;
    bf16x8 A0=*(const bf16x8*)(hr+0),   A1=*(const bf16x8*)(hr+32),
           A2=*(const bf16x8*)(hr+64),  A3=*(const bf16x8*)(hr+96),
           A4=*(const bf16x8*)(hr+128), A5=*(const bf16x8*)(hr+160),
           A6=*(const bf16x8*)(hr+192), A7=*(const bf16x8*)(hr+224);
    f32x4 Z={0.f,0.f,0.f,0.f};
    f32x4 C00=Z,C01=Z,C02=Z,C03=Z,C10=Z,C11=Z,C12=Z,C13=Z;
    MMRT(0,C00) MMRT(1,C01) MMRT(2,C02) MMRT(3,C03)   // resident (32 MFMA)
    MMLT(0,C10) MMLT(1,C11)                           // LDS tiles (16 MFMA)
    MMST(C12)                                         // T2=6 streamed
    LOADST(56)                                        // stream T2=7 (issue)
    bf16x8 X2=*(const bf16x8*)(xp+16), X3=*(const bf16x8*)(xp+24);
    short* hbn = hb + nxt*4224;
    GP(0, C00,C01,C02,C03, X0,X1)                     // hides T2=7 latency
    MMST(C13)                                         // T2=7 streamed
    GP(1, C10,C11,C12,C13, X2,X3)
    __syncthreads();
    // coalesced bf16 h dump; store retires during next step (no drain stall)
    f32x4 hv4 = *(const f32x4*)(hbn + db*264 + du);
    *(f32x4*)(hgb + ((long)t*16 + db)*256 + du) = hv4;
  }
}

// ---- enc = [hf|hb] @ Wenc + benc, relu(max) scatter into lembuf + flags ----
__global__ void k_enc(const int* __restrict__ seq, const int* __restrict__ len,
                      const int* __restrict__ u2l, const short* __restrict__ hgs,
                      const float* __restrict__ Wenc, const float* __restrict__ benc,
                      unsigned int* __restrict__ lembuf, unsigned int* __restrict__ flags){
  __shared__ __align__(16) float As[16][2*SZ];
  __shared__ const short* pf16[16]; __shared__ const short* pb16[16];
  __shared__ int lem_s[16], val_s[16], b_s[16];
  int r0=blockIdx.x*16, tid=threadIdx.x;
  if(tid<16){
    int r=r0+tid, b=r>>7, t=r&127, lb=len[b];
    int v=(t<lb); val_s[tid]=v; b_s[tid]=b;
    int lem=u2l[seq[r]];
    lem_s[tid]=lem;
    pf16[tid]=hgs+((long)t*BB+b)*SZ;
    int tr=v? (lb-1-t) : t;
    pb16[tid]=hgs+((long)(LL+tr)*BB+b)*SZ;
    if(v) flags[(long)b*NLEM+lem]=1u;
  }
  __syncthreads();
  for(int i=tid;i<16*SZ;i+=256){int lr=i>>8,j=i&(SZ-1);
    As[lr][j]=B2F(pf16[lr][j]); As[lr][SZ+j]=B2F(pb16[lr][j]);}
  __syncthreads();
  int cl=tid&63, rg=tid>>6;
  float acc[4][4];
  #pragma unroll
  for(int i=0;i<4;i++){acc[i][0]=acc[i][1]=acc[i][2]=acc[i][3]=0.f;}
  for(int k=0;k<2*SZ;k+=4){
    float4 a4[4];
    #pragma unroll
    for(int i=0;i<4;i++) a4[i]=*(const float4*)&As[rg*4+i][k];
    #pragma unroll
    for(int j=0;j<4;j++){
      const float* wr=Wenc+(long)(k+j)*SZ+cl;
      float w0=wr[0],w1=wr[64],w2=wr[128],w3=wr[192];
      #pragma unroll
      for(int i=0;i<4;i++){
        float a=(j==0)?a4[i].x:(j==1)?a4[i].y:(j==2)?a4[i].z:a4[i].w;
        acc[i][0]=fmaf(a,w0,acc[i][0]);acc[i][1]=fmaf(a,w1,acc[i][1]);
        acc[i][2]=fmaf(a,w2,acc[i][2]);acc[i][3]=fmaf(a,w3,acc[i][3]);
      }
    }
  }
  #pragma unroll
  for(int i=0;i<4;i++){
    int lr=rg*4+i;
    if(val_s[lr]){
      long base=((long)b_s[lr]*NLEM+lem_s[lr])*SZ;
      #pragma unroll
      for(int cc=0;cc<4;cc++){
        int col=cl+cc*64;
        float e=fmaxf(acc[i][cc]+benc[col],0.f);
        atomicMax(&lembuf[base+col], __float_as_uint(e));
      }
    }
  }
}

// ------------ generic C[r] = A[r] @ W  (K=256), optional touched-flags ------
__global__ void k_rowgemm(const float* __restrict__ A, const float* __restrict__ W,
                          float* __restrict__ C, const unsigned int* __restrict__ flags){
  __shared__ __align__(16) float As[16][SZ];
  __shared__ int any_s;
  int r0=blockIdx.x*16, tid=threadIdx.x;
  if(tid==0){
    int a = flags? 0 : 1;
    if(flags){ for(int i=0;i<16;i++) a |= (int)flags[r0+i]; }
    any_s=a;
  }
  __syncthreads();
  if(!any_s) return;
  for(int i=tid;i<16*SZ;i+=256){int lr=i>>8,j=i&(SZ-1);As[lr][j]=A[(long)(r0+lr)*SZ+j];}
  __syncthreads();
  int cl=tid&63, rg=tid>>6;
  float acc[4][4];
  #pragma unroll
  for(int i=0;i<4;i++){acc[i][0]=acc[i][1]=acc[i][2]=acc[i][3]=0.f;}
  for(int k=0;k<SZ;k+=4){
    float4 a4[4];
    #pragma unroll
    for(int i=0;i<4;i++) a4[i]=*(const float4*)&As[rg*4+i][k];
    #pragma unroll
    for(int j=0;j<4;j++){
      const float* wr=W+(long)(k+j)*SZ+cl;
      float w0=wr[0],w1=wr[64],w2=wr[128],w3=wr[192];
      #pragma unroll
      for(int i=0;i<4;i++){
        float a=(j==0)?a4[i].x:(j==1)?a4[i].y:(j==2)?a4[i].z:a4[i].w;
        acc[i][0]=fmaf(a,w0,acc[i][0]);acc[i][1]=fmaf(a,w1,acc[i][1]);
        acc[i][2]=fmaf(a,w2,acc[i][2]);acc[i][3]=fmaf(a,w3,acc[i][3]);
      }
    }
  }
  #pragma unroll
  for(int i=0;i<4;i++){
    int r=r0+rg*4+i;
    #pragma unroll
    for(int cc=0;cc<4;cc++) C[(long)r*SZ+cl+cc*64]=acc[i][cc];
  }
}

// ------------ rowgemm over *cnt rows (compacted): C[i] = A[i] @ W -----------
__global__ void k_rowgemm_n(const float* __restrict__ A, const float* __restrict__ W,
                            float* __restrict__ C, const int* __restrict__ cnt, int ncap){
  __shared__ __align__(16) float As[16][SZ];
  int n=*cnt; if(n>ncap)n=ncap;
  int r0=blockIdx.x*16, tid=threadIdx.x;
  if(r0>=n) return;
  for(int i=tid;i<16*SZ;i+=256){int lr=i>>8,j=i&(SZ-1);
    As[lr][j]= (r0+lr<n)? A[(long)(r0+lr)*SZ+j] : 0.f;}
  __syncthreads();
  int cl=tid&63, rg=tid>>6;
  float acc[4][4];
  #pragma unroll
  for(int i=0;i<4;i++){acc[i][0]=acc[i][1]=acc[i][2]=acc[i][3]=0.f;}
  for(int k=0;k<SZ;k+=4){
    float4 a4[4];
    #pragma unroll
    for(int i=0;i<4;i++) a4[i]=*(const float4*)&As[rg*4+i][k];
    #pragma unroll
    for(int j=0;j<4;j++){
      const float* wr=W+(long)(k+j)*SZ+cl;
      float w0=wr[0],w1=wr[64],w2=wr[128],w3=wr[192];
      #pragma unroll
      for(int i=0;i<4;i++){
        float a=(j==0)?a4[i].x:(j==1)?a4[i].y:(j==2)?a4[i].z:a4[i].w;
        acc[i][0]=fmaf(a,w0,acc[i][0]);acc[i][1]=fmaf(a,w1,acc[i][1]);
        acc[i][2]=fmaf(a,w2,acc[i][2]);acc[i][3]=fmaf(a,w3,acc[i][3]);
      }
    }
  }
  #pragma unroll
  for(int i=0;i<4;i++){
    int r=r0+rg*4+i;
    if(r<n){
      #pragma unroll
      for(int cc=0;cc<4;cc++) C[(long)r*SZ+cl+cc*64]=acc[i][cc];
    }
  }
}

// ---- compact list of rows whose lemma was touched in iter 0 ----------------
__global__ void k_compact(const int* __restrict__ u2l, const unsigned int* __restrict__ flags,
                          int* __restrict__ cnt, int* __restrict__ list,
                          int* __restrict__ idxmap, int ncap){
  int r = blockIdx.x*256+threadIdx.x;
  if(r>=BB*NW) return;
  int b=r/NW, w=r-b*NW;
  int im=-1;
  if(flags[(long)b*NLEM+u2l[w]]){
    int idx=atomicAdd(cnt,1);
    if(idx<ncap){ list[idx]=r; im=idx; }
  }
  idxmap[r]=im;
}

// ---- gate for touched-only rows -> compact ctxtT ---------------------------
__global__ void k_gate0c(const float* __restrict__ we, const float* __restrict__ P0,
                         const float* __restrict__ Q, const float* __restrict__ lembuf,
                         const int* __restrict__ u2l, const float* __restrict__ bg,
                         const int* __restrict__ cnt, const int* __restrict__ list,
                         float* __restrict__ ctxtT, int ncap){
  int n=*cnt; if(n>ncap)n=ncap;
  long idx=(long)blockIdx.x*256+threadIdx.x;
  long i=idx>>6; int k4=(int)(idx&63);
  if(i>=n) return;
  int r=list[i]; int b=r/NW, w=r-b*NW;
  int lem=u2l[w];
  long qb=((long)b*NLEM+lem)*SZ;
  float4 p =((const float4*)(P0+(long)w*SZ))[k4];
  float4 wv=((const float4*)(we+(long)w*SZ))[k4];
  float4 bgv=((const float4*)bg)[k4];
  float4 q =((const float4*)(Q+qb))[k4];
  float4 nw=((const float4*)(lembuf+qb))[k4];
  float4 o;
  { float g=sigf(p.x+q.x+bgv.x); o.x=wv.x*g+(1.f-g)*nw.x; }
  { float g=sigf(p.y+q.y+bgv.y); o.y=wv.y*g+(1.f-g)*nw.y; }
  { float g=sigf(p.z+q.z+bgv.z); o.z=wv.z*g+(1.f-g)*nw.z; }
  { float g=sigf(p.w+q.w+bgv.w); o.w=wv.w*g+(1.f-g)*nw.w; }
  ((float4*)ctxtT)[i*64+k4]=o;
}

// ---- we <- we*sig(P0+bg)  (base0 in place; run after gate0c) ---------------
__global__ void k_base0ip(float* __restrict__ we, const float* __restrict__ P0,
                          const float* __restrict__ bg){
  long idx=(long)blockIdx.x*256+threadIdx.x;
  if(idx>=(long)NW*SZ/4) return;
  int k4=(int)(idx&63);
  float4 wv=((float4*)we)[idx];
  float4 p =((const float4*)P0)[idx];
  float4 bgv=((const float4*)bg)[k4];
  wv.x*=sigf(p.x+bgv.x); wv.y*=sigf(p.y+bgv.y);
  wv.z*=sigf(p.z+bgv.z); wv.w*=sigf(p.w+bgv.w);
  ((float4*)we)[idx]=wv;
}

// ------- iter-0 gate DENSE (fallback): full out write -----------------------
__global__ void k_gate0(const float* __restrict__ we, const float* __restrict__ P0,
                        const float* __restrict__ Q, const float* __restrict__ lembuf,
                        const int* __restrict__ u2l, const unsigned int* __restrict__ flags,
                        const float* __restrict__ bg, float* __restrict__ out){
  long idx=(long)blockIdx.x*256+threadIdx.x;
  const long TOTAL4=(long)BB*NW*SZ/4;
  if(idx>=TOTAL4) return;
  long row=idx>>6; int k4=(int)(idx&63);
  int r32=(int)row;
  int b=r32/NW, w=r32-b*NW;
  int lem=u2l[w];
  long qb=((long)b*NLEM+lem)*SZ;
  unsigned int fl=flags[(long)b*NLEM+lem];
  float4 p =((const float4*)(P0+(long)w*SZ))[k4];
  float4 wv=((const float4*)(we+(long)w*SZ))[k4];
  float4 bgv=((const float4*)bg)[k4];
  float4 q, nw;
  if(fl){ q=((const float4*)(Q+qb))[k4]; nw=((const float4*)(lembuf+qb))[k4]; }
  else  { q=make_float4(0.f,0.f,0.f,0.f); nw=q; }
  float4 o;
  { float g=sigf(p.x+q.x+bgv.x); o.x=wv.x*g+(1.f-g)*nw.x; }
  { float g=sigf(p.y+q.y+bgv.y); o.y=wv.y*g+(1.f-g)*nw.y; }
  { float g=sigf(p.z+q.z+bgv.z); o.z=wv.z*g+(1.f-g)*nw.z; }
  { float g=sigf(p.w+q.w+bgv.w); o.w=wv.w*g+(1.f-g)*nw.w; }
  ((float4*)out)[idx]=o;
}

// ------- iter-1 gate: cv from base0/ctxtT, p from P1b/Pt, write final out ---
__global__ void k_gate1e(const float* __restrict__ base0, const float* __restrict__ ctxtT,
                         const float* __restrict__ P1b, const float* __restrict__ Pt,
                         const int* __restrict__ idxmap,
                         const float* __restrict__ Q, const float* __restrict__ lembuf,
                         const int* __restrict__ u2l, const unsigned int* __restrict__ flags,
                         const float* __restrict__ bg, float* __restrict__ out){
  long idx=(long)blockIdx.x*256+threadIdx.x;
  const long TOTAL4=(long)BB*NW*SZ/4;
  if(idx>=TOTAL4) return;
  long row=idx>>6; int k4=(int)(idx&63);
  int r32=(int)row;
  int b=r32/NW, w=r32-b*NW;
  int im=idxmap[r32];
  int lem=u2l[w];
  long qb=((long)b*NLEM+lem)*SZ;
  unsigned int fl=flags[(long)b*NLEM+lem];
  float4 p, cv;
  if(im>=0){ p=((const float4*)(Pt+(long)im*SZ))[k4]; cv=((const float4*)(ctxtT+(long)im*SZ))[k4]; }
  else     { p=((const float4*)(P1b+(long)w*SZ))[k4]; cv=((const float4*)(base0+(long)w*SZ))[k4]; }
  float4 bgv=((const float4*)bg)[k4];
  float4 q, nw;
  if(fl){ q=((const float4*)(Q+qb))[k4]; nw=((const float4*)(lembuf+qb))[k4]; }
  else  { q=make_float4(0.f,0.f,0.f,0.f); nw=q; }
  float4 o;
  { float g=sigf(p.x+q.x+bgv.x); o.x=cv.x*g+(1.f-g)*nw.x; }
  { float g=sigf(p.y+q.y+bgv.y); o.y=cv.y*g+(1.f-g)*nw.y; }
  { float g=sigf(p.z+q.z+bgv.z); o.z=cv.z*g+(1.f-g)*nw.z; }
  { float g=sigf(p.w+q.w+bgv.w); o.w=cv.w*g+(1.f-g)*nw.w; }
  ((float4*)out)[idx]=o;
}

// ------- legacy dense iter-1 gate (fallback if ws too small) ----------------
__global__ void k_gate1(const float* __restrict__ ctxt, const float* __restrict__ Wg,
                        const float* __restrict__ Q, const float* __restrict__ lembuf,
                        const int* __restrict__ u2l, const unsigned int* __restrict__ flags,
                        const float* __restrict__ bg, float* __restrict__ out){
  __shared__ __align__(16) float As[64][SZ];
  __shared__ __align__(16) float Ws[64][SZ];
  __shared__ int lem_s[64];
  int r0=blockIdx.x*64, tid=threadIdx.x;
  for(int i=tid;i<64*SZ;i+=256){int lr=i>>8,j=i&(SZ-1);
    As[lr][j]=ctxt[(long)(r0+lr)*SZ+j];}
  if(tid<64){int r=r0+tid; lem_s[tid]=u2l[r%NW];}
  int cl=tid&63, rg=tid>>6;
  float acc[16][4];
  #pragma unroll
  for(int i=0;i<16;i++){acc[i][0]=acc[i][1]=acc[i][2]=acc[i][3]=0.f;}
  for(int kb=0;kb<4;kb++){
    __syncthreads();
    for(int i=tid;i<64*SZ;i+=256){int lr=i>>8,j=i&(SZ-1);
      Ws[lr][j]=Wg[(long)(kb*64+lr)*SZ+j];}
    __syncthreads();
    for(int k=0;k<64;k+=4){
      float4 a4[16];
      #pragma unroll
      for(int i=0;i<16;i++) a4[i]=*(const float4*)&As[rg*16+i][kb*64+k];
      #pragma unroll
      for(int j=0;j<4;j++){
        float w0=Ws[k+j][cl],w1=Ws[k+j][cl+64],w2=Ws[k+j][cl+128],w3=Ws[k+j][cl+192];
        #pragma unroll
        for(int i=0;i<16;i++){
          float a=(j==0)?a4[i].x:(j==1)?a4[i].y:(j==2)?a4[i].z:a4[i].w;
          acc[i][0]=fmaf(a,w0,acc[i][0]);acc[i][1]=fmaf(a,w1,acc[i][1]);
          acc[i][2]=fmaf(a,w2,acc[i][2]);acc[i][3]=fmaf(a,w3,acc[i][3]);
        }
      }
    }
  }
  #pragma unroll
  for(int i=0;i<16;i++){
    int lr=rg*16+i, r=r0+lr, b=r/NW;
    long base=((long)b*NLEM+lem_s[lr])*SZ;
    unsigned int fl=flags[(long)b*NLEM+lem_s[lr]];
    #pragma unroll
    for(int cc=0;cc<4;cc++){
      int col=cl+cc*64;
      float qv=0.f, nw=0.f;
      if(fl){ qv=Q[base+col]; nw=lembuf[base+col]; }
      float g=sigf(acc[i][cc]+qv+bg[col]);
      out[(long)r*SZ+col]=As[lr][col]*g+(1.f-g)*nw;
    }
  }
}

extern "C" void kernel_launch(void* const* d_in, const int* in_sizes, int n_in,
                              void* d_out, int out_size, void* d_ws, size_t ws_size,
                              hipStream_t stream){
  const float* emb  =(const float*)d_in[0];
  const float* Wp   =(const float*)d_in[1];
  const float* bp   =(const float*)d_in[2];
  const float* Wi_f =(const float*)d_in[3];
  const float* Wh_f =(const float*)d_in[4];
  const float* b_f  =(const float*)d_in[5];
  const float* Wi_b =(const float*)d_in[6];
  const float* Wh_b =(const float*)d_in[7];
  const float* b_b  =(const float*)d_in[8];
  const float* Wenc =(const float*)d_in[9];
  const float* benc =(const float*)d_in[10];
  const float* Wg   =(const float*)d_in[11];
  const float* bg   =(const float*)d_in[12];
  const int*   seq0 =(const int*)d_in[13];
  const int*   seq1 =(const int*)d_in[14];
  const int*   len0 =(const int*)d_in[15];
  const int*   len1 =(const int*)d_in[16];
  const int*   u2l  =(const int*)d_in[17];

  float* ws    = (float*)d_ws;
  float* we    = ws;                       // 2,560,000 (becomes base0 after iter0)
  float* xwi   = we    + 2560000;          // region 4,194,304 floats:
  float* ctxtT = xwi   + 2097152;          //   xq bf16 uses first half; ctxtT second
  float* hglob = xwi   + 4194304;          // 1,048,576 (bf16 h uses half)
  float* lembuf= hglob + 1048576;          // 12,288,000
  float* flags = lembuf+ 12288000;         // 48,000 (uint)
  float* Q     = flags + 48000;            // 12,288,000
  float* P0    = Q     + 12288000;         // 2,560,000 (becomes P1b after iter0)
  short* whb   = (short*)(P0 + 2560000);   // 524,288 shorts = 262,144 floats
  int*   idxmap= (int*)(P0 + 2560000 + 262144);   // 160,000
  int*   list  = idxmap + 160000;          // NCAP
  int*   cnt   = list + NCAP;              // 1 (+3 pad)
  float* Ptouch= (float*)(cnt + 4);        // NCAP*256
  long base_floats = (long)(Ptouch - ws);
  long avail = ((long)(ws_size/4) - base_floats)/SZ;
  int sparse_ok = (avail >= NCAP);
  float* out   = (float*)d_out;

  hipFuncSetAttribute((const void*)k_lstm_w8,
                      hipFuncAttributeMaxDynamicSharedMemorySize, 147968);

  k_we<<<NW/16,256,0,stream>>>(emb,Wp,bp,we);
  k_rowgemm<<<NW/16,256,0,stream>>>(we,Wg,P0,nullptr);            // P0 = we@Wg1
  k_prep<<<256,256,0,stream>>>(Wh_f,Wh_b,whb);

  // ---------------- iteration 0 ----------------
  hipMemsetAsync(lembuf,0,(size_t)(12288000+48000)*4,stream);
  dim3 gx(64,4);
  k_xwi<<<gx,256,0,stream>>>(seq0,len0,we,0L,nullptr,nullptr,
                             Wi_f,b_f,Wi_b,b_b,0,(short*)xwi);
  k_lstm_w8<<<2,512,147968,stream>>>(whb,(const short*)xwi,(short*)hglob);
  k_enc<<<BB*LL/16,256,0,stream>>>(seq0,len0,u2l,(const short*)hglob,Wenc,benc,
                                   (unsigned int*)lembuf,(unsigned int*)flags);
  k_rowgemm<<<BB*NLEM/16,256,0,stream>>>(lembuf,Wg+(long)SZ*SZ,Q,
                                         (const unsigned int*)flags);  // Q = nw@Wg2
  if(sparse_ok){
    hipMemsetAsync(cnt,0,4,stream);
    k_compact<<<(BB*NW+255)/256,256,0,stream>>>(u2l,(const unsigned int*)flags,
                                                cnt,list,idxmap,NCAP);
    k_gate0c<<<NCAP*64/256,256,0,stream>>>(we,P0,Q,lembuf,u2l,bg,cnt,list,ctxtT,NCAP);
    k_rowgemm_n<<<NCAP/16,256,0,stream>>>(ctxtT,Wg,Ptouch,cnt,NCAP); // Pt=ctxtT@Wg1
    k_base0ip<<<(NW*SZ/4+255)/256,256,0,stream>>>(we,P0,bg);         // we <- base0
    k_rowgemm<<<NW/16,256,0,stream>>>(we,Wg,P0,nullptr);             // P0 <- base0@Wg1
  }else{
    long nb=((long)BB*NW*SZ/4+255)/256;
    k_gate0<<<(int)nb,256,0,stream>>>(we,P0,Q,lembuf,u2l,
                                      (const unsigned int*)flags,bg,out);
  }

  // ---------------- iteration 1 ----------------
  hipMemsetAsync(lembuf,0,(size_t)(12288000+48000)*4,stream);
  if(sparse_ok){
    k_xwi<<<gx,256,0,stream>>>(seq1,len1,we,0L,ctxtT,idxmap,
                               Wi_f,b_f,Wi_b,b_b,1,(short*)xwi);
  }else{
    k_xwi<<<gx,256,0,stream>>>(seq1,len1,out,(long)NW*SZ,nullptr,nullptr,
                               Wi_f,b_f,Wi_b,b_b,1,(short*)xwi);
  }
  k_lstm_w8<<<2,512,147968,stream>>>(whb,(const short*)xwi,(short*)hglob);
  k_enc<<<BB*LL/16,256,0,stream>>>(seq1,len1,u2l,(const short*)hglob,Wenc,benc,
                                   (unsigned int*)lembuf,(unsigned int*)flags);
  k_rowgemm<<<BB*NLEM/16,256,0,stream>>>(lembuf,Wg+(long)SZ*SZ,Q,
                                         (const unsigned int*)flags);  // Q = nw@Wg2
  if(sparse_ok){
    long nb=((long)BB*NW*SZ/4+255)/256;
    k_gate1e<<<(int)nb,256,0,stream>>>(we,ctxtT,P0,Ptouch,idxmap,Q,lembuf,u2l,
                                       (const unsigned int*)flags,bg,out);
  }else{
    k_gate1<<<BB*NW/64,256,0,stream>>>(out,Wg,Q,lembuf,u2l,
                                       (const unsigned int*)flags,bg,out);
  }
}